// Round 14
// baseline (1283.055 us; speedup 1.0000x reference)
//
#include <hip/hip_runtime.h>
#include <stdint.h>

typedef unsigned long long u64;
typedef unsigned int u32;

#define TPB 256
#define NJMAX 12
#define NSC 11

__device__ __forceinline__ int findJob(const int* cum, int nj, int v) {
  int j = 0;
  while (j + 1 < nj && v >= cum[j + 1]) ++j;
  return j;
}

// ---------------- resize weight tables (per scale, per output position) -----
// tW layout: TRANSPOSED [k][ox]: tW[wOff + k*nh + ox]  (coalesced lane reads)
struct MkP { int ns; int nw[NSC]; float invs[NSC], ks[NSC];
             int oxB[NSC], T[NSC], wOff[NSC]; };

__global__ void k_mkweights(int* __restrict__ tX0, int* __restrict__ tCNT,
                            float* __restrict__ tWT, float* __restrict__ tW, MkP P) {
  const int s = blockIdx.x;
  const int nw = P.nw[s];
  const float invs = P.invs[s], ks = P.ks[s];
  const int T = P.T[s];
  for (int ox = threadIdx.x; ox < nw; ox += TPB) {
    float sx = ((float)ox + 0.5f) * invs - 0.5f;
    int x0 = (int)ceilf(sx - ks); if (x0 < 0) x0 = 0;
    int x1 = (int)floorf(sx + ks); if (x1 > 767) x1 = 767;
    float wt = 0.f;
    float* wv = tW + P.wOff[s];
    for (int j = x0; j <= x1; ++j) {
      float w = fmaxf(0.f, 1.f - fabsf(sx - (float)j) / ks);
      wt += w;
      wv[(j - x0) * nw + ox] = w;
    }
    for (int k = x1 - x0 + 1; k < T; ++k) wv[k * nw + ox] = 0.f;
    int g = P.oxB[s] + ox;
    tX0[g] = x0; tCNT[g] = x1 - x0 + 1; tWT[g] = wt;
  }
}

// ---------------- descriptor builder (geometry-only, once per group) --------
struct DscP { int nj; int N[NJMAX]; int hOff[NJMAX], imgOff[NJMAX];
              int oxB[NJMAX], wOff[NJMAX];
              int cumW[NJMAX + 1], cumR[NJMAX + 1]; };

__global__ void k_mkdesc(int* __restrict__ hd, int* __restrict__ vd,
                         int hdcap, int vdcap, DscP P) {
  int gid = blockIdx.x * TPB + threadIdx.x;
  int totW = P.cumW[P.nj], totR = P.cumR[P.nj];
  if (gid < totW) {
    int j = findJob(P.cumW, P.nj, gid);
    int local = gid - P.cumW[j];
    int N = P.N[j];
    int ox = local % N, c = local / N;
    hd[gid]             = P.hOff[j] + c * 768 * N + ox;   // A
    hd[hdcap + gid]     = c * 769;                        // R (LDS row base)
    hd[2 * hdcap + gid] = N;                              // stride
    hd[3 * hdcap + gid] = P.oxB[j] + ox;                  // g
    hd[4 * hdcap + gid] = P.wOff[j] + ox;                 // W
  }
  if (gid < totR) {
    int j = findJob(P.cumR, P.nj, gid);
    int local = gid - P.cumR[j];
    int N = P.N[j];
    int oy = local % N, q = local / N;   // q = b*3+c in 0..23
    vd[gid]             = P.hOff[j] + q * 768 * N;        // S (src col base)
    vd[vdcap + gid]     = P.imgOff[j] + (q * N + oy) * N; // O (out row base)
    vd[2 * vdcap + gid] = P.oxB[j] + oy;                  // g
    vd[3 * vdcap + gid] = P.wOff[j] + oy;                 // W
    vd[4 * vdcap + gid] = N;                              // stride
  }
}

// ---------------- H pass: descriptor-driven, row-resident -------------------
__global__ void k_resizeH_d(const float* __restrict__ img, float* __restrict__ base,
                            const int* __restrict__ tX0, const int* __restrict__ tCNT,
                            const float* __restrict__ tWT, const float* __restrict__ tW,
                            const int* __restrict__ hd, int hdcap, int total) {
  __shared__ float row[3][769];
  const int y = blockIdx.x, b = blockIdx.y;
  const float* src = img + ((long)b * 768 + y) * 768 * 3;
  for (int t = threadIdx.x; t < 2304; t += TPB) {
    int x = t / 3, c = t - 3 * x;
    row[c][x] = src[t];
  }
  __syncthreads();
  const float* rowF = &row[0][0];
  const long yb = (long)y + 2304L * b;
  for (int t = threadIdx.x; t < total; t += TPB) {
    int A = hd[t];
    int R = hd[hdcap + t];
    int N = hd[2 * hdcap + t];
    int g = hd[3 * hdcap + t];
    int W = hd[4 * hdcap + t];
    int x0 = tX0[g], cnt = tCNT[g];
    float wt = tWT[g];
    const float* wv = tW + W;
    const float* rp = rowF + R + x0;
    const int N2 = N + N, N3 = N2 + N, N4 = N3 + N;
    float acc = 0.f;
    int k = 0;
    long o = 0;
    for (; k + 3 < cnt; k += 4) {
      float v0 = rp[k],     w0 = wv[o];
      float v1 = rp[k + 1], w1 = wv[o + N];
      float v2 = rp[k + 2], w2 = wv[o + N2];
      float v3 = rp[k + 3], w3 = wv[o + N3];
      acc += v0 * w0; acc += v1 * w1; acc += v2 * w2; acc += v3 * w3;
      o += N4;
    }
    for (; k < cnt; ++k) { acc += rp[k] * wv[o]; o += N; }
    base[(long)A + (long)N * yb] = acc / wt;
  }
}

// ---------------- V pass: one 64-lane wave per output row -------------------
__global__ void k_resizeV_row(const float* __restrict__ basep, float* __restrict__ img,
                              const int* __restrict__ tX0, const int* __restrict__ tCNT,
                              const float* __restrict__ tWT, const float* __restrict__ tW,
                              const int* __restrict__ vd, int vdcap, int nRows) {
  int row = blockIdx.x * 4 + (threadIdx.x >> 6);
  if (row >= nRows) return;
  int lane = threadIdx.x & 63;
  int S = vd[row];
  int O = vd[vdcap + row];
  int g = vd[2 * vdcap + row];
  int W = vd[3 * vdcap + row];
  int N = vd[4 * vdcap + row];
  int y0 = tX0[g], cnt = tCNT[g];
  float wt = tWT[g];
  const float* wv = tW + W;
  const float* col0 = basep + S + (long)y0 * N;
  const int N2 = N + N, N3 = N2 + N, N4 = N3 + N;
  for (int ox = lane; ox < N; ox += 64) {
    const float* col = col0 + ox;
    float acc = 0.f;
    int k = 0;
    long o = 0;
    for (; k + 3 < cnt; k += 4) {
      float v0 = col[o],      w0 = wv[o];
      float v1 = col[o + N],  w1 = wv[o + N];
      float v2 = col[o + N2], w2 = wv[o + N2];
      float v3 = col[o + N3], w3 = wv[o + N3];
      acc += v0 * w0; acc += v1 * w1; acc += v2 * w2; acc += v3 * w3;
      o += N4;
    }
    for (; k < cnt; ++k) { acc += col[o] * wv[o]; o += N; }
    img[(long)O + ox] = (acc / wt - 127.5f) * 0.0078125f;
  }
}

// ---------------- fused conv1 + PReLU + 2x2 ceil-maxpool (all 10 co) --------
__device__ __forceinline__ void conv1pool_body(
    const float* in, const float* w, const float* bias, const float* pr,
    float* out, int H, int W, int b, int px, int py) {
  const int h1 = H - 2, w1 = W - 2;
  const int PH = (h1 + 1) >> 1, PW = (w1 + 1) >> 1;
  if (px >= PW || py >= PH) return;
  const int x0 = px * 2, y0 = py * 2;
  float a00[10], a01[10], a10[10], a11[10];
#pragma unroll
  for (int co = 0; co < 10; ++co) { a00[co] = 0.f; a01[co] = 0.f; a10[co] = 0.f; a11[co] = 0.f; }
  const long HW = (long)H * W;
  const float* pp = in + ((long)b * 3 * H + y0) * W + x0;
  for (int ci = 0; ci < 3; ++ci, pp += HW) {
    const float* r = pp;
    float r00 = r[0], r01 = r[1], r02 = r[2], r03 = r[3]; r += W;
    float r10 = r[0], r11 = r[1], r12 = r[2], r13 = r[3]; r += W;
    float r20 = r[0], r21 = r[1], r22 = r[2], r23 = r[3]; r += W;
    float r30 = r[0], r31 = r[1], r32 = r[2], r33 = r[3];
#pragma unroll
    for (int co = 0; co < 10; ++co) {
      const float* wc = w + ((long)co * 3 + ci) * 9;
      float w0 = wc[0], w1_ = wc[1], w2 = wc[2];
      float w3 = wc[3], w4 = wc[4], w5 = wc[5];
      float w6 = wc[6], w7 = wc[7], w8 = wc[8];
      a00[co] += r00 * w0 + r01 * w1_ + r02 * w2;
      a00[co] += r10 * w3 + r11 * w4 + r12 * w5;
      a00[co] += r20 * w6 + r21 * w7 + r22 * w8;
      a01[co] += r01 * w0 + r02 * w1_ + r03 * w2;
      a01[co] += r11 * w3 + r12 * w4 + r13 * w5;
      a01[co] += r21 * w6 + r22 * w7 + r23 * w8;
      a10[co] += r10 * w0 + r11 * w1_ + r12 * w2;
      a10[co] += r20 * w3 + r21 * w4 + r22 * w5;
      a10[co] += r30 * w6 + r31 * w7 + r32 * w8;
      a11[co] += r11 * w0 + r12 * w1_ + r13 * w2;
      a11[co] += r21 * w3 + r22 * w4 + r23 * w5;
      a11[co] += r31 * w6 + r32 * w7 + r33 * w8;
    }
  }
  const bool vx = (x0 + 1 < w1), vy = (y0 + 1 < h1);
#pragma unroll
  for (int co = 0; co < 10; ++co) {
    const float bb = bias[co], al = pr[co];
    float v = a00[co] + bb; v = v > 0.f ? v : al * v;
    float m = v;
    if (vx) { v = a01[co] + bb; v = v > 0.f ? v : al * v; m = fmaxf(m, v); }
    if (vy) { v = a10[co] + bb; v = v > 0.f ? v : al * v; m = fmaxf(m, v); }
    if (vx && vy) { v = a11[co] + bb; v = v > 0.f ? v : al * v; m = fmaxf(m, v); }
    out[(((long)b * 10 + co) * PH + py) * PW + px] = m;
  }
}

struct C1P { int nj; int nh[NJMAX]; int imgOff[NJMAX], poolOff[NJMAX];
             int t1x[NJMAX]; int cumT[NJMAX + 1]; };

__global__ void k_conv1pool_job(const float* __restrict__ imgb, const float* __restrict__ w,
                                const float* __restrict__ bias, const float* __restrict__ pr,
                                float* __restrict__ poolb, C1P P) {
  int j = findJob(P.cumT, P.nj, blockIdx.x);
  int local = blockIdx.x - P.cumT[j];
  int t1x = P.t1x[j];
  int tX = local % t1x, tY = local / t1x;
  conv1pool_body(imgb + P.imgOff[j], w, bias, pr, poolb + P.poolOff[j],
                 P.nh[j], P.nh[j], blockIdx.z,
                 tX * 16 + (threadIdx.x & 15), tY * 16 + (threadIdx.x >> 4));
}

// ---------------- co-blocked (16) tiled 3x3 conv + PReLU --------------------
__device__ __forceinline__ void conv3x3c16_body(
    const float* in, const float* w, const float* bias, const float* pr,
    float* out, int Cin, int Cout, int H, int W, int cog, int b, int x0, int y) {
  const int OH = H - 2, OW = W - 2;
  if (y >= OH || x0 >= OW) return;
  float acc[16][4];
#pragma unroll
  for (int k = 0; k < 16; ++k) { acc[k][0] = 0.f; acc[k][1] = 0.f; acc[k][2] = 0.f; acc[k][3] = 0.f; }
  const float* wp = w + (long)cog * Cin * 9;
  const long HW = (long)H * W;
  const float* pp = in + ((long)b * Cin * H + y) * W + x0;
  for (int ci = 0; ci < Cin; ++ci, pp += HW) {
    const float* r = pp;
    float q00 = r[0], q01 = r[1], q02 = r[2], q03 = r[3], q04 = r[4], q05 = r[5]; r += W;
    float q10 = r[0], q11 = r[1], q12 = r[2], q13 = r[3], q14 = r[4], q15 = r[5]; r += W;
    float q20 = r[0], q21 = r[1], q22 = r[2], q23 = r[3], q24 = r[4], q25 = r[5];
#pragma unroll
    for (int k = 0; k < 16; ++k) {
      const float* wc = wp + ((long)k * Cin + ci) * 9;
      float w0 = wc[0], w1 = wc[1], w2 = wc[2];
      float w3 = wc[3], w4 = wc[4], w5 = wc[5];
      float w6 = wc[6], w7 = wc[7], w8 = wc[8];
      acc[k][0] += q00 * w0 + q01 * w1 + q02 * w2;
      acc[k][1] += q01 * w0 + q02 * w1 + q03 * w2;
      acc[k][2] += q02 * w0 + q03 * w1 + q04 * w2;
      acc[k][3] += q03 * w0 + q04 * w1 + q05 * w2;
      acc[k][0] += q10 * w3 + q11 * w4 + q12 * w5;
      acc[k][1] += q11 * w3 + q12 * w4 + q13 * w5;
      acc[k][2] += q12 * w3 + q13 * w4 + q14 * w5;
      acc[k][3] += q13 * w3 + q14 * w4 + q15 * w5;
      acc[k][0] += q20 * w6 + q21 * w7 + q22 * w8;
      acc[k][1] += q21 * w6 + q22 * w7 + q23 * w8;
      acc[k][2] += q22 * w6 + q23 * w7 + q24 * w8;
      acc[k][3] += q23 * w6 + q24 * w7 + q25 * w8;
    }
  }
  const int rem = OW - x0;
#pragma unroll
  for (int k = 0; k < 16; ++k) {
    const int co = cog + k;
    const float bb = bias[co], al = pr[co];
    float* op = out + (((long)b * Cout + co) * OH + y) * OW + x0;
    float v0 = acc[k][0] + bb; v0 = v0 > 0.f ? v0 : al * v0;
    op[0] = v0;
    if (rem > 1) { float v = acc[k][1] + bb; v = v > 0.f ? v : al * v; op[1] = v; }
    if (rem > 2) { float v = acc[k][2] + bb; v = v > 0.f ? v : al * v; op[2] = v; }
    if (rem > 3) { float v = acc[k][3] + bb; v = v > 0.f ? v : al * v; op[3] = v; }
  }
}

struct CvP { int nj; int H[NJMAX]; int inOff[NJMAX], outOff[NJMAX];
             int tx[NJMAX]; int cumT[NJMAX + 1]; };

__global__ void k_conv3x3c16_job(const float* __restrict__ inb, const float* __restrict__ w,
                                 const float* __restrict__ bias, const float* __restrict__ pr,
                                 float* __restrict__ outb, int Cin, int Cout, CvP P) {
  int j = findJob(P.cumT, P.nj, blockIdx.x);
  int local = blockIdx.x - P.cumT[j];
  int tx0 = P.tx[j];
  int tX = local % tx0, tY = local / tx0;
  conv3x3c16_body(inb + P.inOff[j], w, bias, pr, outb + P.outOff[j], Cin, Cout,
                  P.H[j], P.H[j], blockIdx.y * 16, blockIdx.z,
                  tX * 64 + (threadIdx.x & 15) * 4, tY * 16 + (threadIdx.x >> 4));
}

// ---------------- 1x1 heads -------------------------------------------------
__device__ __forceinline__ void head_body(const float* x3, const float* w41,
                                          const float* b41, const float* w42,
                                          const float* b42, float* reg, u64* keys,
                                          int plane, long idx) {
  int b = (int)(idx / plane); int rem = (int)(idx % plane);
  const float* p = x3 + (long)b * 32 * plane + rem;
  float l0 = 0.f, l1 = 0.f, r0 = 0.f, r1 = 0.f, r2 = 0.f, r3 = 0.f;
  for (int c = 0; c < 32; ++c) {
    float v = p[(long)c * plane];
    l0 += v * w41[c];      l1 += v * w41[32 + c];
    r0 += v * w42[c];      r1 += v * w42[32 + c];
    r2 += v * w42[64 + c]; r3 += v * w42[96 + c];
  }
  l0 += b41[0]; l1 += b41[1];
  r0 += b42[0]; r1 += b42[1]; r2 += b42[2]; r3 += b42[3];
  float mx = fmaxf(l0, l1);
  float e0 = expf(l0 - mx), e1 = expf(l1 - mx);
  float s = e1 / (e0 + e1);
  reg[idx * 4 + 0] = r0; reg[idx * 4 + 1] = r1;
  reg[idx * 4 + 2] = r2; reg[idx * 4 + 3] = r3;
  u32 ic = 0xFFFFFFFFu - (u32)idx;
  u64 k = (s >= 0.6f) ? ((((u64)__float_as_uint(s)) << 32) | ic) : (u64)ic;
  keys[idx] = k;
}

struct HdP { int nj; int h3[NJMAX]; int c3Off[NJMAX], kOff[NJMAX];
             int cumC[NJMAX + 1]; };

__global__ void k_head_job(const float* __restrict__ c3b, const float* __restrict__ w41,
                           const float* __restrict__ b41, const float* __restrict__ w42,
                           const float* __restrict__ b42, float* __restrict__ regb,
                           u64* __restrict__ keysb, HdP P) {
  int gid = blockIdx.x * TPB + threadIdx.x;
  if (gid >= P.cumC[P.nj]) return;
  int j = findJob(P.cumC, P.nj, gid);
  int idx = gid - P.cumC[j];
  head_body(c3b + P.c3Off[j], w41, b41, w42, b42,
            regb + 4L * P.kOff[j], keysb + P.kOff[j], P.h3[j] * P.h3[j], idx);
}

// ---------------- bitonic top-K ---------------------------------------------
__device__ __forceinline__ void bitonic2048(u64* s) {
  for (int k = 2; k <= 2048; k <<= 1) {
    for (int j = k >> 1; j > 0; j >>= 1) {
      for (int i = threadIdx.x; i < 2048; i += TPB) {
        int ixj = i ^ j;
        if (ixj > i) {
          u64 a = s[i], b = s[ixj];
          bool desc = ((i & k) == 0);
          if (desc ? (a < b) : (a > b)) { s[i] = b; s[ixj] = a; }
        }
      }
      __syncthreads();
    }
  }
}

__global__ void k_topk(const u64* __restrict__ in, int n, u64* __restrict__ out, int K) {
  __shared__ u64 s[2048];
  int base = blockIdx.x * 2048;
  for (int t = threadIdx.x; t < 2048; t += TPB) {
    int gi = base + t;
    s[t] = (gi < n) ? in[gi] : 0ULL;
  }
  __syncthreads();
  bitonic2048(s);
  for (int t = threadIdx.x; t < K; t += TPB)
    out[(long)blockIdx.x * K + t] = s[t];
}

struct TkP { int nj; int srcSel[NJMAX]; int srcOff[NJMAX]; int n[NJMAX];
             int dstOff[NJMAX]; int cumB[NJMAX + 1]; };

__global__ void k_topk_job(u64* __restrict__ A, u64* __restrict__ B, TkP P) {
  __shared__ u64 s[2048];
  int j = findJob(P.cumB, P.nj, blockIdx.x);
  int lb = blockIdx.x - P.cumB[j];
  const u64* src = (P.srcSel[j] ? B : A) + P.srcOff[j];
  u64* dst = (P.srcSel[j] ? A : B) + P.dstOff[j];
  int n = P.n[j];
  int base = lb * 2048;
  for (int t = threadIdx.x; t < 2048; t += TPB) {
    int gi = base + t;
    s[t] = (gi < n) ? src[gi] : 0ULL;
  }
  __syncthreads();
  bitonic2048(s);
  for (int t = threadIdx.x; t < 512; t += TPB)
    dst[(long)lb * 512 + t] = s[t];
}

struct TkFP { int nj; int srcSel[NJMAX]; int srcOff[NJMAX]; int n[NJMAX]; int sIdx[NJMAX]; };

__global__ void k_topk_fin(const u64* __restrict__ A, const u64* __restrict__ B,
                           u64* __restrict__ selk, TkFP P) {
  __shared__ u64 s[2048];
  int j = blockIdx.x;
  const u64* src = (P.srcSel[j] ? B : A) + P.srcOff[j];
  int n = P.n[j];
  for (int t = threadIdx.x; t < 2048; t += TPB)
    s[t] = (t < n) ? src[t] : 0ULL;
  __syncthreads();
  bitonic2048(s);
  for (int t = threadIdx.x; t < 512; t += TPB)
    selk[(long)P.sIdx[j] * 512 + t] = s[t];
}

// ---------------- gather box rows -------------------------------------------
__device__ __forceinline__ void gather_body(const u64* keys, const float* reg,
                                            float* boxes, int h, int w, float scalef,
                                            int i) {
  float* bx = boxes + (long)i * 12;
  u64 key = keys[i];
  if ((key >> 32) == 0ULL) {
    for (int q = 0; q < 12; ++q) bx[q] = 0.f;
    return;
  }
  u32 cell = 0xFFFFFFFFu - (u32)(key & 0xFFFFFFFFu);
  int x = (int)(cell % (u32)w); u32 t2 = cell / (u32)w;
  int y = (int)(t2 % (u32)h); int b = (int)(t2 / (u32)h);
  float fx = (float)x, fy = (float)y;
  bx[0] = floorf((2.f * fx + 1.f) / scalef);
  bx[1] = floorf((2.f * fy + 1.f) / scalef);
  bx[2] = floorf((2.f * fx + 12.f) / scalef);
  bx[3] = floorf((2.f * fy + 12.f) / scalef);
  bx[4] = __uint_as_float((u32)(key >> 32));
  bx[5] = reg[(long)cell * 4 + 0];
  bx[6] = reg[(long)cell * 4 + 1];
  bx[7] = reg[(long)cell * 4 + 2];
  bx[8] = reg[(long)cell * 4 + 3];
  bx[9] = (float)b;
  bx[10] = 1.f;
  bx[11] = 0.f;
}

struct GtP { int nj; int h3[NJMAX]; float scalef[NJMAX]; int kOff[NJMAX]; int sIdx[NJMAX]; };

__global__ void k_gather_job(const u64* __restrict__ selk, const float* __restrict__ regb,
                             float* __restrict__ boxes, GtP P) {
  int j = blockIdx.x >> 1;
  int i = ((blockIdx.x & 1) << 8) + threadIdx.x;
  gather_body(selk + (long)P.sIdx[j] * 512, regb + 4L * P.kOff[j],
              boxes + (long)P.sIdx[j] * 512 * 12, P.h3[j], P.h3[j], P.scalef[j], i);
}

// ---------------- greedy NMS (shared-memory form, proven) --------------------
__global__ void k_nms(float* __restrict__ boxes, int per, float thr) {
  __shared__ float sx1[1024], sy1[1024], sx2[1024], sy2[1024], sar[1024];
  __shared__ unsigned char kp[1024];
  __shared__ int snv;
  float* bs = boxes + (long)blockIdx.x * per * 12;
  int N = per;
  if (threadIdx.x == 0) snv = 0;
  __syncthreads();
  for (int i = threadIdx.x; i < N; i += blockDim.x) {
    const float* b = bs + (long)i * 12;
    float off = b[9] * 100000.0f;
    float a0 = b[0] + off, a1 = b[1] + off, a2 = b[2] + off, a3 = b[3] + off;
    sx1[i] = a0; sy1[i] = a1; sx2[i] = a2; sy2[i] = a3;
    sar[i] = fmaxf(a2 - a0, 0.f) * fmaxf(a3 - a1, 0.f);
    bool v = (b[10] != 0.f);
    kp[i] = v;
    if (v) atomicMax(&snv, i + 1);   // valid entries are a prefix (sorted desc)
  }
  __syncthreads();
  int nv = snv;
  for (int i = 0; i < nv; ++i) {
    if (kp[i]) {
      float xi1 = sx1[i], yi1 = sy1[i], xi2 = sx2[i], yi2 = sy2[i], ai = sar[i];
      for (int j = threadIdx.x; j < nv; j += blockDim.x) {
        if (j > i && kp[j]) {
          float iw = fmaxf(fminf(xi2, sx2[j]) - fmaxf(xi1, sx1[j]), 0.f);
          float ih = fmaxf(fminf(yi2, sy2[j]) - fmaxf(yi1, sy1[j]), 0.f);
          float inter = iw * ih;
          float iou = inter / (ai + sar[j] - inter + 1e-9f);
          if (iou > thr) kp[j] = 0;
        }
      }
    }
    __syncthreads();
  }
  for (int i = threadIdx.x; i < N; i += blockDim.x)
    bs[(long)i * 12 + 11] = kp[i] ? 1.f : 0.f;
}

// ---------------- final stage ------------------------------------------------
__global__ void k_finalkeys(const float* __restrict__ boxes, u64* __restrict__ keys,
                            int total, int padded) {
  int i = blockIdx.x * blockDim.x + threadIdx.x;
  if (i >= padded) return;
  u64 k = 0ULL;
  if (i < total) {
    const float* b = boxes + (long)i * 12;
    u32 ic = 0xFFFFFFFFu - (u32)i;
    k = (b[11] != 0.f) ? ((((u64)__float_as_uint(b[4])) << 32) | ic) : (u64)ic;
  }
  keys[i] = k;
}

__global__ void k_gatherfinal(const u64* __restrict__ keys, const float* __restrict__ boxes,
                              float* __restrict__ sel) {
  int i = blockIdx.x * blockDim.x + threadIdx.x;
  if (i >= 1024) return;
  u64 key = keys[i];
  float* o = sel + (long)i * 12;
  if ((key >> 32) == 0ULL) {
    for (int q = 0; q < 12; ++q) o[q] = 0.f;
    return;
  }
  u32 bi = 0xFFFFFFFFu - (u32)(key & 0xFFFFFFFFu);
  const float* b = boxes + (long)bi * 12;
  for (int q = 0; q < 12; ++q) o[q] = b[q];
  o[10] = 1.f;
  o[11] = 0.f;
}

__global__ void k_refine(const float* __restrict__ sel, float* __restrict__ out, int N) {
  int i = blockIdx.x * blockDim.x + threadIdx.x;
  if (i >= N) return;
  const float* b = sel + (long)i * 12;
  float keep = b[11];
  float x1 = b[0], y1 = b[1], x2 = b[2], y2 = b[3], sc = b[4];
  float rw = x2 - x1, rh = y2 - y1;
  float o0 = x1 + b[5] * rw;
  float o1 = y1 + b[6] * rh;
  float o2 = x2 + b[7] * rw;
  float o3 = y2 + b[8] * rh;
  float hh = o3 - o1, ww = o2 - o0;
  float l = fmaxf(hh, ww);
  float nx1 = o0 + ww * 0.5f - l * 0.5f;
  float ny1 = o1 + hh * 0.5f - l * 0.5f;
  out[(long)i * 5 + 0] = nx1 * keep;
  out[(long)i * 5 + 1] = ny1 * keep;
  out[(long)i * 5 + 2] = (nx1 + l) * keep;
  out[(long)i * 5 + 3] = (ny1 + l) * keep;
  out[(long)i * 5 + 4] = sc * keep;
}

extern "C" void kernel_launch(void* const* d_in, const int* in_sizes, int n_in,
                              void* d_out, int out_size, void* d_ws, size_t ws_size,
                              hipStream_t stream) {
  (void)in_sizes; (void)n_in; (void)out_size;
  const float* images = (const float*)d_in[0];
  const float* c1w = (const float*)d_in[1];
  const float* c1b = (const float*)d_in[2];
  const float* p1  = (const float*)d_in[3];
  const float* c2w = (const float*)d_in[4];
  const float* c2b = (const float*)d_in[5];
  const float* p2  = (const float*)d_in[6];
  const float* c3w = (const float*)d_in[7];
  const float* c3b = (const float*)d_in[8];
  const float* p3  = (const float*)d_in[9];
  const float* w41 = (const float*)d_in[10];
  const float* b41 = (const float*)d_in[11];
  const float* w42 = (const float*)d_in[12];
  const float* b42 = (const float*)d_in[13];
  float* ws = (float*)d_ws;

  double scl[16]; int nsc = 0;
  {
    double m = 12.0 / 20.0;
    double ml = 768.0 * m;
    double si = m;
    while (ml >= 12.0) { scl[nsc++] = si; si *= 0.709; ml *= 0.709; }
  }

  auto cdiv = [](long a, long b) { return (int)((a + b - 1) / b); };

  // per-scale dims + weight-table geometry
  int NH[NSC], PH_[NSC], H2[NSC], H3[NSC], OXB[NSC], TT[NSC], WOFF[NSC];
  float INV[NSC], KSF[NSC];
  {
    int oxb = 0, woff = 0;
    for (int s = 0; s < nsc; ++s) {
      int nh = (int)(768.0 * scl[s] + 1.0);
      NH[s] = nh;
      PH_[s] = ((nh - 2) + 1) / 2;
      H2[s] = PH_[s] - 2;
      H3[s] = H2[s] - 2;
      double inv = 1.0 / (((double)nh) / 768.0);
      INV[s] = (float)inv;
      KSF[s] = (float)(inv > 1.0 ? inv : 1.0);
      TT[s] = (int)(2.0f * KSF[s]) + 2;
      OXB[s] = oxb; oxb += nh;
      WOFF[s] = woff; woff += nh * TT[s];
    }
  }

  // candidate groupings
  static const int GA[11] = {0, 1, 2, 3, 4, 5, 6, 7, 8, 9, 10};
  static const int G1[7] = {0, 5, 6, 7, 8, 9, 10};
  static const int G2[4] = {1, 2, 3, 4};

  struct Layout {
    long HT, IMG, POOL, C2, REG, KEYS, SCR, SEL, BOX, FK, FS, SF, TBL, HD, VD, extent;
    int hdcap, vdcap;
  };

  auto calcLayout = [&](const int* const* gps, const int* gn, int ng,
                        int hdcap, int vdcap, Layout& L) {
    long htA = 0, c3A = 0, imgA = 0, poolA = 0, c2A = 0, cellsA = 0, scrA = 0;
    for (int g = 0; g < ng; ++g) {
      long ht = 0, c3 = 0, im = 0, pl = 0, c2s = 0, ck = 0, sc = 0;
      for (int q = 0; q < gn[g]; ++q) {
        int s = gps[g][q];
        ht += 24L * 768 * NH[s];
        im += 24L * NH[s] * NH[s];
        pl += 80L * PH_[s] * PH_[s];
        c2s += 128L * H2[s] * H2[s];
        c3 += 256L * H3[s] * H3[s];
        long cells = 8L * H3[s] * H3[s];
        ck += cells;
        sc += 512L * ((cells + 2047) / 2048);
      }
      if (ht > htA) htA = ht; if (c3 > c3A) c3A = c3; if (im > imgA) imgA = im;
      if (pl > poolA) poolA = pl; if (c2s > c2A) c2A = c2s;
      if (ck > cellsA) cellsA = ck; if (sc > scrA) scrA = sc;
    }
    long htR = htA > c3A ? htA : c3A;
    auto al = [](long v) { return (v + 15) & ~15L; };
    long off = 0;
    L.HT = off;   off += al(htR);
    L.IMG = off;  off += al(imgA);
    L.POOL = off; off += al(poolA);
    L.C2 = off;   off += al(c2A);
    L.REG = off;  off += al(4 * cellsA);
    L.KEYS = off; off += al(2 * cellsA);
    L.SCR = off;  off += al(2 * scrA + 16384);
    L.SEL = off;  off += al(11264);
    L.BOX = off;  off += al(67584);
    L.FK = off;   off += al(16384);
    L.FS = off;   off += al(2048);
    L.SF = off;   off += al(12288);
    L.TBL = off;  off += al(12288 + 24000);
    L.HD = off;   off += al((long)ng * 5 * hdcap);
    L.VD = off;   off += al((long)ng * 5 * vdcap);
    L.extent = off;
    L.hdcap = hdcap; L.vdcap = vdcap;
  };

  Layout LA, LB;
  {
    const int* gpsA[1] = {GA}; int gnA[1] = {11};
    calcLayout(gpsA, gnA, 1, 8192, 56320, LA);
    const int* gpsB[2] = {G1, G2}; int gnB[2] = {7, 4};
    calcLayout(gpsB, gnB, 2, 2560, 20480, LB);
  }
  bool big = (ws_size >= (size_t)LA.extent * 4);
  const Layout& L = big ? LA : LB;
  const int* GS[2]; int GN[2]; int ngroups;
  if (big) { GS[0] = GA; GN[0] = 11; ngroups = 1; }
  else { GS[0] = G1; GN[0] = 7; GS[1] = G2; GN[1] = 4; ngroups = 2; }

  u64* keys  = (u64*)(ws + L.KEYS);
  u64* scr   = (u64*)(ws + L.SCR);
  u64* selk  = (u64*)(ws + L.SEL);
  u64* fkeys = (u64*)(ws + L.FK);
  u64* fsel  = (u64*)(ws + L.FS);
  float* boxes = ws + L.BOX;
  float* self  = ws + L.SF;
  int*   tX0  = (int*)(ws + L.TBL);
  int*   tCNT = (int*)(ws + L.TBL + 4096);
  float* tWT  = ws + L.TBL + 8192;
  float* tW   = ws + L.TBL + 12288;

  // build resize weight tables (once per launch)
  {
    MkP P; P.ns = nsc;
    for (int s = 0; s < nsc; ++s) {
      P.nw[s] = NH[s]; P.invs[s] = INV[s]; P.ks[s] = KSF[s];
      P.oxB[s] = OXB[s]; P.T[s] = TT[s]; P.wOff[s] = WOFF[s];
    }
    k_mkweights<<<nsc, TPB, 0, stream>>>(tX0, tCNT, tWT, tW, P);
  }

  // per-group geometry
  int imgOff[2][NJMAX], poolOff[2][NJMAX], c2Off[2][NJMAX], c3Off[2][NJMAX],
      htOff[2][NJMAX], kOff[2][NJMAX], cells[2][NJMAX];
  int cumWtot[2], cumRtot[2];
  for (int g = 0; g < ngroups; ++g) {
    long ch = 0, ci = 0, cp = 0, c2 = 0, c3 = 0, ck = 0;
    int cw = 0, cr = 0;
    for (int q = 0; q < GN[g]; ++q) {
      int s = GS[g][q];
      htOff[g][q] = (int)ch;  ch += 24L * 768 * NH[s];
      imgOff[g][q] = (int)ci; ci += 24L * NH[s] * NH[s];
      poolOff[g][q] = (int)cp; cp += 80L * PH_[s] * PH_[s];
      c2Off[g][q] = (int)c2;  c2 += 128L * H2[s] * H2[s];
      c3Off[g][q] = (int)c3;  c3 += 256L * H3[s] * H3[s];
      kOff[g][q] = (int)ck;   cells[g][q] = 8 * H3[s] * H3[s]; ck += cells[g][q];
      cw += 3 * NH[s]; cr += 24 * NH[s];
    }
    cumWtot[g] = cw; cumRtot[g] = cr;
  }

  // build H/V descriptors (geometry-only)
  for (int g = 0; g < ngroups; ++g) {
    DscP P; P.nj = GN[g];
    int cw = 0, cr = 0;
    for (int q = 0; q < GN[g]; ++q) {
      int s = GS[g][q];
      P.N[q] = NH[s]; P.hOff[q] = htOff[g][q]; P.imgOff[q] = imgOff[g][q];
      P.oxB[q] = OXB[s]; P.wOff[q] = WOFF[s];
      P.cumW[q] = cw; cw += 3 * NH[s];
      P.cumR[q] = cr; cr += 24 * NH[s];
    }
    P.cumW[GN[g]] = cw; P.cumR[GN[g]] = cr;
    int* hd = (int*)(ws + L.HD) + (long)g * 5 * L.hdcap;
    int* vd = (int*)(ws + L.VD) + (long)g * 5 * L.vdcap;
    int tot = cw > cr ? cw : cr;
    k_mkdesc<<<cdiv(tot, TPB), TPB, 0, stream>>>(hd, vd, L.hdcap, L.vdcap, P);
  }

  // ---------------- unified job pipeline over groups ----------------
  for (int g = 0; g < ngroups; ++g) {
    const int* gs = GS[g];
    int nj = GN[g];
    int* hd = (int*)(ws + L.HD) + (long)g * 5 * L.hdcap;
    int* vd = (int*)(ws + L.VD) + (long)g * 5 * L.vdcap;
    // H pass (one image read for the whole group)
    {
      dim3 gh(768, 8, 1);
      k_resizeH_d<<<gh, TPB, 0, stream>>>(images, ws + L.HT, tX0, tCNT, tWT, tW,
                                          hd, L.hdcap, cumWtot[g]);
    }
    // V pass: one wave per output row
    k_resizeV_row<<<cdiv(cumRtot[g], 4), TPB, 0, stream>>>(
        ws + L.HT, ws + L.IMG, tX0, tCNT, tWT, tW, vd, L.vdcap, cumRtot[g]);
    // conv1+pool (all 10 co per block)
    {
      C1P P; P.nj = nj; int ct = 0;
      for (int q = 0; q < nj; ++q) {
        int s = gs[q];
        P.nh[q] = NH[s];
        P.imgOff[q] = imgOff[g][q]; P.poolOff[q] = poolOff[g][q];
        int t1x = cdiv(PH_[s], 16);
        P.t1x[q] = t1x;
        P.cumT[q] = ct; ct += t1x * t1x;
      }
      P.cumT[nj] = ct;
      dim3 gg(ct, 1, 8);
      k_conv1pool_job<<<gg, TPB, 0, stream>>>(ws + L.IMG, c1w, c1b, p1, ws + L.POOL, P);
    }
    // conv2 (16 co in one group)
    {
      CvP P; P.nj = nj; int ct = 0;
      for (int q = 0; q < nj; ++q) {
        int s = gs[q];
        P.H[q] = PH_[s];
        P.inOff[q] = poolOff[g][q]; P.outOff[q] = c2Off[g][q];
        int tx = cdiv(H2[s], 64), ty = cdiv(H2[s], 16);
        P.tx[q] = tx;
        P.cumT[q] = ct; ct += tx * ty;
      }
      P.cumT[nj] = ct;
      dim3 gg(ct, 1, 8);
      k_conv3x3c16_job<<<gg, TPB, 0, stream>>>(ws + L.POOL, c2w, c2b, p2, ws + L.C2,
                                               10, 16, P);
    }
    // conv3 (32 co in 2 groups of 16; writes into HT region)
    {
      CvP P; P.nj = nj; int ct = 0;
      for (int q = 0; q < nj; ++q) {
        int s = gs[q];
        P.H[q] = H2[s];
        P.inOff[q] = c2Off[g][q]; P.outOff[q] = c3Off[g][q];
        int tx = cdiv(H3[s], 64), ty = cdiv(H3[s], 16);
        P.tx[q] = tx;
        P.cumT[q] = ct; ct += tx * ty;
      }
      P.cumT[nj] = ct;
      dim3 gg(ct, 2, 8);
      k_conv3x3c16_job<<<gg, TPB, 0, stream>>>(ws + L.C2, c3w, c3b, p3, ws + L.HT,
                                               16, 32, P);
    }
    // heads
    {
      HdP P; P.nj = nj; int cc = 0;
      for (int q = 0; q < nj; ++q) {
        int s = gs[q];
        P.h3[q] = H3[s];
        P.c3Off[q] = c3Off[g][q]; P.kOff[q] = kOff[g][q];
        P.cumC[q] = cc; cc += cells[g][q];
      }
      P.cumC[nj] = cc;
      k_head_job<<<cdiv(cc, TPB), TPB, 0, stream>>>(ws + L.HT, w41, b41, w42, b42,
                                                    ws + L.REG, keys, P);
    }
    // batched top-512 tournament
    {
      int bOff[NJMAX];
      {
        int c = 0;
        for (int q = 0; q < nj; ++q) { bOff[q] = c; c += 512 * cdiv(cells[g][q], 2048); }
      }
      long nCur[NJMAX]; int par[NJMAX];
      for (int q = 0; q < nj; ++q) { nCur[q] = cells[g][q]; par[q] = 0; }
      while (true) {
        TkP P; P.nj = 0; int cum = 0; int act[NJMAX];
        for (int q = 0; q < nj; ++q) {
          if (nCur[q] > 2048) {
            int r = P.nj++;
            act[r] = q;
            int blocks = cdiv(nCur[q], 2048);
            P.srcSel[r] = par[q];
            P.srcOff[r] = par[q] ? bOff[q] : kOff[g][q];
            P.dstOff[r] = par[q] ? kOff[g][q] : bOff[q];
            P.n[r] = (int)nCur[q];
            P.cumB[r] = cum; cum += blocks;
          }
        }
        P.cumB[P.nj] = cum;
        if (P.nj == 0) break;
        k_topk_job<<<cum, TPB, 0, stream>>>(keys, scr, P);
        for (int r = 0; r < P.nj; ++r) {
          int q = act[r];
          nCur[q] = 512L * cdiv(nCur[q], 2048);
          par[q] ^= 1;
        }
      }
      TkFP F; F.nj = nj;
      for (int q = 0; q < nj; ++q) {
        F.srcSel[q] = par[q];
        F.srcOff[q] = par[q] ? bOff[q] : kOff[g][q];
        F.n[q] = (int)nCur[q];
        F.sIdx[q] = gs[q];
      }
      k_topk_fin<<<nj, TPB, 0, stream>>>(keys, scr, selk, F);
    }
    // gather
    {
      GtP P; P.nj = nj;
      for (int q = 0; q < nj; ++q) {
        int s = gs[q];
        P.h3[q] = H3[s]; P.scalef[q] = (float)scl[s]; P.kOff[q] = kOff[g][q];
        P.sIdx[q] = s;
      }
      k_gather_job<<<2 * nj, TPB, 0, stream>>>(selk, ws + L.REG, boxes, P);
    }
  }

  // ---------------- per-scale NMS + final stage ----------------
  k_nms<<<nsc, TPB, 0, stream>>>(boxes, 512, 0.5f);

  int total = nsc * 512;
  k_finalkeys<<<cdiv(8192, TPB), TPB, 0, stream>>>(boxes, fkeys, total, 8192);
  k_topk<<<4, TPB, 0, stream>>>(fkeys, 8192, scr, 1024);
  k_topk<<<2, TPB, 0, stream>>>(scr, 4096, keys, 1024);
  k_topk<<<1, TPB, 0, stream>>>(keys, 2048, fsel, 1024);
  k_gatherfinal<<<4, TPB, 0, stream>>>(fsel, boxes, self);
  k_nms<<<1, TPB, 0, stream>>>(self, 1024, 0.7f);
  k_refine<<<4, TPB, 0, stream>>>(self, (float*)d_out, 1024);
}

// Round 15
// 1152.285 us; speedup vs baseline: 1.1135x; 1.1135x over previous
//
#include <hip/hip_runtime.h>
#include <stdint.h>

typedef unsigned long long u64;
typedef unsigned int u32;

#define TPB 256
#define NJMAX 12
#define NSC 11

__device__ __forceinline__ int findJob(const int* cum, int nj, int v) {
  int j = 0;
  while (j + 1 < nj && v >= cum[j + 1]) ++j;
  return j;
}

// ---------------- resize weight tables (per scale, per output position) -----
// tW layout: TRANSPOSED [k][ox]: tW[wOff + k*nh + ox]  (coalesced lane reads)
struct MkP { int ns; int nw[NSC]; float invs[NSC], ks[NSC];
             int oxB[NSC], T[NSC], wOff[NSC]; };

__global__ void k_mkweights(int* __restrict__ tX0, int* __restrict__ tCNT,
                            float* __restrict__ tWT, float* __restrict__ tW, MkP P) {
  const int s = blockIdx.x;
  const int nw = P.nw[s];
  const float invs = P.invs[s], ks = P.ks[s];
  const int T = P.T[s];
  for (int ox = threadIdx.x; ox < nw; ox += TPB) {
    float sx = ((float)ox + 0.5f) * invs - 0.5f;
    int x0 = (int)ceilf(sx - ks); if (x0 < 0) x0 = 0;
    int x1 = (int)floorf(sx + ks); if (x1 > 767) x1 = 767;
    float wt = 0.f;
    float* wv = tW + P.wOff[s];
    for (int j = x0; j <= x1; ++j) {
      float w = fmaxf(0.f, 1.f - fabsf(sx - (float)j) / ks);
      wt += w;
      wv[(j - x0) * nw + ox] = w;
    }
    for (int k = x1 - x0 + 1; k < T; ++k) wv[k * nw + ox] = 0.f;
    int g = P.oxB[s] + ox;
    tX0[g] = x0; tCNT[g] = x1 - x0 + 1; tWT[g] = wt;
  }
}

// ---------------- descriptor builder (geometry-only, once per group) --------
struct DscP { int nj; int N[NJMAX]; int hOff[NJMAX], imgOff[NJMAX];
              int oxB[NJMAX], wOff[NJMAX];
              int cumW[NJMAX + 1], cumR[NJMAX + 1]; };

__global__ void k_mkdesc(int* __restrict__ hd, int* __restrict__ vd,
                         int hdcap, int vdcap, DscP P) {
  int gid = blockIdx.x * TPB + threadIdx.x;
  int totW = P.cumW[P.nj], totR = P.cumR[P.nj];
  if (gid < totW) {
    int j = findJob(P.cumW, P.nj, gid);
    int local = gid - P.cumW[j];
    int N = P.N[j];
    int ox = local % N, c = local / N;
    hd[gid]             = P.hOff[j] + c * 768 * N + ox;   // A
    hd[hdcap + gid]     = c * 769;                        // R (LDS row base)
    hd[2 * hdcap + gid] = N;                              // stride
    hd[3 * hdcap + gid] = P.oxB[j] + ox;                  // g
    hd[4 * hdcap + gid] = P.wOff[j] + ox;                 // W
  }
  if (gid < totR) {
    int j = findJob(P.cumR, P.nj, gid);
    int local = gid - P.cumR[j];
    int N = P.N[j];
    int oy = local % N, q = local / N;   // q = b*3+c in 0..23
    vd[gid]             = P.hOff[j] + q * 768 * N;        // S (src col base)
    vd[vdcap + gid]     = P.imgOff[j] + (q * N + oy) * N; // O (out row base)
    vd[2 * vdcap + gid] = P.oxB[j] + oy;                  // g
    vd[3 * vdcap + gid] = P.wOff[j] + oy;                 // W
    vd[4 * vdcap + gid] = N;                              // stride
  }
}

// ---------------- H pass: descriptor-driven, row-resident -------------------
__global__ void k_resizeH_d(const float* __restrict__ img, float* __restrict__ base,
                            const int* __restrict__ tX0, const int* __restrict__ tCNT,
                            const float* __restrict__ tWT, const float* __restrict__ tW,
                            const int* __restrict__ hd, int hdcap, int total) {
  __shared__ float row[3][769];
  const int y = blockIdx.x, b = blockIdx.y;
  const float* src = img + ((long)b * 768 + y) * 768 * 3;
  for (int t = threadIdx.x; t < 2304; t += TPB) {
    int x = t / 3, c = t - 3 * x;
    row[c][x] = src[t];
  }
  __syncthreads();
  const float* rowF = &row[0][0];
  const long yb = (long)y + 2304L * b;
  for (int t = threadIdx.x; t < total; t += TPB) {
    int A = hd[t];
    int R = hd[hdcap + t];
    int N = hd[2 * hdcap + t];
    int g = hd[3 * hdcap + t];
    int W = hd[4 * hdcap + t];
    int x0 = tX0[g], cnt = tCNT[g];
    float wt = tWT[g];
    const float* wv = tW + W;
    const float* rp = rowF + R + x0;
    const int N2 = N + N, N3 = N2 + N, N4 = N3 + N;
    float acc = 0.f;
    int k = 0;
    long o = 0;
    for (; k + 3 < cnt; k += 4) {
      float v0 = rp[k],     w0 = wv[o];
      float v1 = rp[k + 1], w1 = wv[o + N];
      float v2 = rp[k + 2], w2 = wv[o + N2];
      float v3 = rp[k + 3], w3 = wv[o + N3];
      acc += v0 * w0; acc += v1 * w1; acc += v2 * w2; acc += v3 * w3;
      o += N4;
    }
    for (; k < cnt; ++k) { acc += rp[k] * wv[o]; o += N; }
    base[(long)A + (long)N * yb] = acc / wt;
  }
}

// ---------------- V pass: one 64-lane wave per output row -------------------
__global__ void k_resizeV_row(const float* __restrict__ basep, float* __restrict__ img,
                              const int* __restrict__ tX0, const int* __restrict__ tCNT,
                              const float* __restrict__ tWT, const float* __restrict__ tW,
                              const int* __restrict__ vd, int vdcap, int nRows) {
  int row = blockIdx.x * 4 + (threadIdx.x >> 6);
  if (row >= nRows) return;
  int lane = threadIdx.x & 63;
  int S = vd[row];
  int O = vd[vdcap + row];
  int g = vd[2 * vdcap + row];
  int W = vd[3 * vdcap + row];
  int N = vd[4 * vdcap + row];
  int y0 = tX0[g], cnt = tCNT[g];
  float wt = tWT[g];
  const float* wv = tW + W;
  const float* col0 = basep + S + (long)y0 * N;
  const int N2 = N + N, N3 = N2 + N, N4 = N3 + N;
  for (int ox = lane; ox < N; ox += 64) {
    const float* col = col0 + ox;
    float acc = 0.f;
    int k = 0;
    long o = 0;
    for (; k + 3 < cnt; k += 4) {
      float v0 = col[o],      w0 = wv[o];
      float v1 = col[o + N],  w1 = wv[o + N];
      float v2 = col[o + N2], w2 = wv[o + N2];
      float v3 = col[o + N3], w3 = wv[o + N3];
      acc += v0 * w0; acc += v1 * w1; acc += v2 * w2; acc += v3 * w3;
      o += N4;
    }
    for (; k < cnt; ++k) { acc += col[o] * wv[o]; o += N; }
    img[(long)O + ox] = (acc / wt - 127.5f) * 0.0078125f;
  }
}

// ---------------- fused conv1 + PReLU + 2x2 ceil-maxpool (all 10 co) --------
__device__ __forceinline__ void conv1pool_body(
    const float* in, const float* w, const float* bias, const float* pr,
    float* out, int H, int W, int b, int px, int py) {
  const int h1 = H - 2, w1 = W - 2;
  const int PH = (h1 + 1) >> 1, PW = (w1 + 1) >> 1;
  if (px >= PW || py >= PH) return;
  const int x0 = px * 2, y0 = py * 2;
  float a00[10], a01[10], a10[10], a11[10];
#pragma unroll
  for (int co = 0; co < 10; ++co) { a00[co] = 0.f; a01[co] = 0.f; a10[co] = 0.f; a11[co] = 0.f; }
  const long HW = (long)H * W;
  const float* pp = in + ((long)b * 3 * H + y0) * W + x0;
  for (int ci = 0; ci < 3; ++ci, pp += HW) {
    const float* r = pp;
    float r00 = r[0], r01 = r[1], r02 = r[2], r03 = r[3]; r += W;
    float r10 = r[0], r11 = r[1], r12 = r[2], r13 = r[3]; r += W;
    float r20 = r[0], r21 = r[1], r22 = r[2], r23 = r[3]; r += W;
    float r30 = r[0], r31 = r[1], r32 = r[2], r33 = r[3];
#pragma unroll
    for (int co = 0; co < 10; ++co) {
      const float* wc = w + ((long)co * 3 + ci) * 9;
      float w0 = wc[0], w1_ = wc[1], w2 = wc[2];
      float w3 = wc[3], w4 = wc[4], w5 = wc[5];
      float w6 = wc[6], w7 = wc[7], w8 = wc[8];
      a00[co] += r00 * w0 + r01 * w1_ + r02 * w2;
      a00[co] += r10 * w3 + r11 * w4 + r12 * w5;
      a00[co] += r20 * w6 + r21 * w7 + r22 * w8;
      a01[co] += r01 * w0 + r02 * w1_ + r03 * w2;
      a01[co] += r11 * w3 + r12 * w4 + r13 * w5;
      a01[co] += r21 * w6 + r22 * w7 + r23 * w8;
      a10[co] += r10 * w0 + r11 * w1_ + r12 * w2;
      a10[co] += r20 * w3 + r21 * w4 + r22 * w5;
      a10[co] += r30 * w6 + r31 * w7 + r32 * w8;
      a11[co] += r11 * w0 + r12 * w1_ + r13 * w2;
      a11[co] += r21 * w3 + r22 * w4 + r23 * w5;
      a11[co] += r31 * w6 + r32 * w7 + r33 * w8;
    }
  }
  const bool vx = (x0 + 1 < w1), vy = (y0 + 1 < h1);
#pragma unroll
  for (int co = 0; co < 10; ++co) {
    const float bb = bias[co], al = pr[co];
    float v = a00[co] + bb; v = v > 0.f ? v : al * v;
    float m = v;
    if (vx) { v = a01[co] + bb; v = v > 0.f ? v : al * v; m = fmaxf(m, v); }
    if (vy) { v = a10[co] + bb; v = v > 0.f ? v : al * v; m = fmaxf(m, v); }
    if (vx && vy) { v = a11[co] + bb; v = v > 0.f ? v : al * v; m = fmaxf(m, v); }
    out[(((long)b * 10 + co) * PH + py) * PW + px] = m;
  }
}

struct C1P { int nj; int nh[NJMAX]; int imgOff[NJMAX], poolOff[NJMAX];
             int t1x[NJMAX]; int cumT[NJMAX + 1]; };

__global__ void k_conv1pool_job(const float* __restrict__ imgb, const float* __restrict__ w,
                                const float* __restrict__ bias, const float* __restrict__ pr,
                                float* __restrict__ poolb, C1P P) {
  int j = findJob(P.cumT, P.nj, blockIdx.x);
  int local = blockIdx.x - P.cumT[j];
  int t1x = P.t1x[j];
  int tX = local % t1x, tY = local / t1x;
  conv1pool_body(imgb + P.imgOff[j], w, bias, pr, poolb + P.poolOff[j],
                 P.nh[j], P.nh[j], blockIdx.z,
                 tX * 16 + (threadIdx.x & 15), tY * 16 + (threadIdx.x >> 4));
}

// ---------------- co-blocked (8) tiled 3x3 conv + PReLU ---------------------
__device__ __forceinline__ void conv3x3c8_body(
    const float* in, const float* w, const float* bias, const float* pr,
    float* out, int Cin, int Cout, int H, int W, int cog, int b, int x0, int y) {
  const int OH = H - 2, OW = W - 2;
  if (y >= OH || x0 >= OW) return;
  float acc[8][4];
#pragma unroll
  for (int k = 0; k < 8; ++k) { acc[k][0] = 0.f; acc[k][1] = 0.f; acc[k][2] = 0.f; acc[k][3] = 0.f; }
  const float* wp = w + (long)cog * Cin * 9;
  const long HW = (long)H * W;
  const float* pp = in + ((long)b * Cin * H + y) * W + x0;
  for (int ci = 0; ci < Cin; ++ci, pp += HW) {
    const float* r = pp;
    float q00 = r[0], q01 = r[1], q02 = r[2], q03 = r[3], q04 = r[4], q05 = r[5]; r += W;
    float q10 = r[0], q11 = r[1], q12 = r[2], q13 = r[3], q14 = r[4], q15 = r[5]; r += W;
    float q20 = r[0], q21 = r[1], q22 = r[2], q23 = r[3], q24 = r[4], q25 = r[5];
#pragma unroll
    for (int k = 0; k < 8; ++k) {
      const float* wc = wp + ((long)k * Cin + ci) * 9;
      float w0 = wc[0], w1 = wc[1], w2 = wc[2];
      float w3 = wc[3], w4 = wc[4], w5 = wc[5];
      float w6 = wc[6], w7 = wc[7], w8 = wc[8];
      acc[k][0] += q00 * w0 + q01 * w1 + q02 * w2;
      acc[k][1] += q01 * w0 + q02 * w1 + q03 * w2;
      acc[k][2] += q02 * w0 + q03 * w1 + q04 * w2;
      acc[k][3] += q03 * w0 + q04 * w1 + q05 * w2;
      acc[k][0] += q10 * w3 + q11 * w4 + q12 * w5;
      acc[k][1] += q11 * w3 + q12 * w4 + q13 * w5;
      acc[k][2] += q12 * w3 + q13 * w4 + q14 * w5;
      acc[k][3] += q13 * w3 + q14 * w4 + q15 * w5;
      acc[k][0] += q20 * w6 + q21 * w7 + q22 * w8;
      acc[k][1] += q21 * w6 + q22 * w7 + q23 * w8;
      acc[k][2] += q22 * w6 + q23 * w7 + q24 * w8;
      acc[k][3] += q23 * w6 + q24 * w7 + q25 * w8;
    }
  }
  const int rem = OW - x0;
#pragma unroll
  for (int k = 0; k < 8; ++k) {
    const int co = cog + k;
    const float bb = bias[co], al = pr[co];
    float* op = out + (((long)b * Cout + co) * OH + y) * OW + x0;
    float v0 = acc[k][0] + bb; v0 = v0 > 0.f ? v0 : al * v0;
    op[0] = v0;
    if (rem > 1) { float v = acc[k][1] + bb; v = v > 0.f ? v : al * v; op[1] = v; }
    if (rem > 2) { float v = acc[k][2] + bb; v = v > 0.f ? v : al * v; op[2] = v; }
    if (rem > 3) { float v = acc[k][3] + bb; v = v > 0.f ? v : al * v; op[3] = v; }
  }
}

struct CvP { int nj; int H[NJMAX]; int inOff[NJMAX], outOff[NJMAX];
             int tx[NJMAX]; int cumT[NJMAX + 1]; };

__global__ void k_conv3x3c8_job(const float* __restrict__ inb, const float* __restrict__ w,
                                const float* __restrict__ bias, const float* __restrict__ pr,
                                float* __restrict__ outb, int Cin, int Cout, CvP P) {
  int j = findJob(P.cumT, P.nj, blockIdx.x);
  int local = blockIdx.x - P.cumT[j];
  int tx0 = P.tx[j];
  int tX = local % tx0, tY = local / tx0;
  conv3x3c8_body(inb + P.inOff[j], w, bias, pr, outb + P.outOff[j], Cin, Cout,
                 P.H[j], P.H[j], blockIdx.y * 8, blockIdx.z,
                 tX * 64 + (threadIdx.x & 15) * 4, tY * 16 + (threadIdx.x >> 4));
}

// ---------------- 1x1 heads -------------------------------------------------
__device__ __forceinline__ void head_body(const float* x3, const float* w41,
                                          const float* b41, const float* w42,
                                          const float* b42, float* reg, u64* keys,
                                          int plane, long idx) {
  int b = (int)(idx / plane); int rem = (int)(idx % plane);
  const float* p = x3 + (long)b * 32 * plane + rem;
  float l0 = 0.f, l1 = 0.f, r0 = 0.f, r1 = 0.f, r2 = 0.f, r3 = 0.f;
  for (int c = 0; c < 32; ++c) {
    float v = p[(long)c * plane];
    l0 += v * w41[c];      l1 += v * w41[32 + c];
    r0 += v * w42[c];      r1 += v * w42[32 + c];
    r2 += v * w42[64 + c]; r3 += v * w42[96 + c];
  }
  l0 += b41[0]; l1 += b41[1];
  r0 += b42[0]; r1 += b42[1]; r2 += b42[2]; r3 += b42[3];
  float mx = fmaxf(l0, l1);
  float e0 = expf(l0 - mx), e1 = expf(l1 - mx);
  float s = e1 / (e0 + e1);
  reg[idx * 4 + 0] = r0; reg[idx * 4 + 1] = r1;
  reg[idx * 4 + 2] = r2; reg[idx * 4 + 3] = r3;
  u32 ic = 0xFFFFFFFFu - (u32)idx;
  u64 k = (s >= 0.6f) ? ((((u64)__float_as_uint(s)) << 32) | ic) : (u64)ic;
  keys[idx] = k;
}

struct HdP { int nj; int h3[NJMAX]; int c3Off[NJMAX], kOff[NJMAX];
             int cumC[NJMAX + 1]; };

__global__ void k_head_job(const float* __restrict__ c3b, const float* __restrict__ w41,
                           const float* __restrict__ b41, const float* __restrict__ w42,
                           const float* __restrict__ b42, float* __restrict__ regb,
                           u64* __restrict__ keysb, HdP P) {
  int gid = blockIdx.x * TPB + threadIdx.x;
  if (gid >= P.cumC[P.nj]) return;
  int j = findJob(P.cumC, P.nj, gid);
  int idx = gid - P.cumC[j];
  head_body(c3b + P.c3Off[j], w41, b41, w42, b42,
            regb + 4L * P.kOff[j], keysb + P.kOff[j], P.h3[j] * P.h3[j], idx);
}

// ---------------- bitonic top-K ---------------------------------------------
__device__ __forceinline__ void bitonic2048(u64* s) {
  for (int k = 2; k <= 2048; k <<= 1) {
    for (int j = k >> 1; j > 0; j >>= 1) {
      for (int i = threadIdx.x; i < 2048; i += TPB) {
        int ixj = i ^ j;
        if (ixj > i) {
          u64 a = s[i], b = s[ixj];
          bool desc = ((i & k) == 0);
          if (desc ? (a < b) : (a > b)) { s[i] = b; s[ixj] = a; }
        }
      }
      __syncthreads();
    }
  }
}

__global__ void k_topk(const u64* __restrict__ in, int n, u64* __restrict__ out, int K) {
  __shared__ u64 s[2048];
  int base = blockIdx.x * 2048;
  for (int t = threadIdx.x; t < 2048; t += TPB) {
    int gi = base + t;
    s[t] = (gi < n) ? in[gi] : 0ULL;
  }
  __syncthreads();
  bitonic2048(s);
  for (int t = threadIdx.x; t < K; t += TPB)
    out[(long)blockIdx.x * K + t] = s[t];
}

struct TkP { int nj; int srcSel[NJMAX]; int srcOff[NJMAX]; int n[NJMAX];
             int dstOff[NJMAX]; int cumB[NJMAX + 1]; };

__global__ void k_topk_job(u64* __restrict__ A, u64* __restrict__ B, TkP P) {
  __shared__ u64 s[2048];
  int j = findJob(P.cumB, P.nj, blockIdx.x);
  int lb = blockIdx.x - P.cumB[j];
  const u64* src = (P.srcSel[j] ? B : A) + P.srcOff[j];
  u64* dst = (P.srcSel[j] ? A : B) + P.dstOff[j];
  int n = P.n[j];
  int base = lb * 2048;
  for (int t = threadIdx.x; t < 2048; t += TPB) {
    int gi = base + t;
    s[t] = (gi < n) ? src[gi] : 0ULL;
  }
  __syncthreads();
  bitonic2048(s);
  for (int t = threadIdx.x; t < 512; t += TPB)
    dst[(long)lb * 512 + t] = s[t];
}

struct TkFP { int nj; int srcSel[NJMAX]; int srcOff[NJMAX]; int n[NJMAX]; int sIdx[NJMAX]; };

__global__ void k_topk_fin(const u64* __restrict__ A, const u64* __restrict__ B,
                           u64* __restrict__ selk, TkFP P) {
  __shared__ u64 s[2048];
  int j = blockIdx.x;
  const u64* src = (P.srcSel[j] ? B : A) + P.srcOff[j];
  int n = P.n[j];
  for (int t = threadIdx.x; t < 2048; t += TPB)
    s[t] = (t < n) ? src[t] : 0ULL;
  __syncthreads();
  bitonic2048(s);
  for (int t = threadIdx.x; t < 512; t += TPB)
    selk[(long)P.sIdx[j] * 512 + t] = s[t];
}

// ---------------- gather box rows -------------------------------------------
__device__ __forceinline__ void gather_body(const u64* keys, const float* reg,
                                            float* boxes, int h, int w, float scalef,
                                            int i) {
  float* bx = boxes + (long)i * 12;
  u64 key = keys[i];
  if ((key >> 32) == 0ULL) {
    for (int q = 0; q < 12; ++q) bx[q] = 0.f;
    return;
  }
  u32 cell = 0xFFFFFFFFu - (u32)(key & 0xFFFFFFFFu);
  int x = (int)(cell % (u32)w); u32 t2 = cell / (u32)w;
  int y = (int)(t2 % (u32)h); int b = (int)(t2 / (u32)h);
  float fx = (float)x, fy = (float)y;
  bx[0] = floorf((2.f * fx + 1.f) / scalef);
  bx[1] = floorf((2.f * fy + 1.f) / scalef);
  bx[2] = floorf((2.f * fx + 12.f) / scalef);
  bx[3] = floorf((2.f * fy + 12.f) / scalef);
  bx[4] = __uint_as_float((u32)(key >> 32));
  bx[5] = reg[(long)cell * 4 + 0];
  bx[6] = reg[(long)cell * 4 + 1];
  bx[7] = reg[(long)cell * 4 + 2];
  bx[8] = reg[(long)cell * 4 + 3];
  bx[9] = (float)b;
  bx[10] = 1.f;
  bx[11] = 0.f;
}

struct GtP { int nj; int h3[NJMAX]; float scalef[NJMAX]; int kOff[NJMAX]; int sIdx[NJMAX]; };

__global__ void k_gather_job(const u64* __restrict__ selk, const float* __restrict__ regb,
                             float* __restrict__ boxes, GtP P) {
  int j = blockIdx.x >> 1;
  int i = ((blockIdx.x & 1) << 8) + threadIdx.x;
  gather_body(selk + (long)P.sIdx[j] * 512, regb + 4L * P.kOff[j],
              boxes + (long)P.sIdx[j] * 512 * 12, P.h3[j], P.h3[j], P.scalef[j], i);
}

// ---------------- greedy NMS (shared-memory form, proven) --------------------
__global__ void k_nms(float* __restrict__ boxes, int per, float thr) {
  __shared__ float sx1[1024], sy1[1024], sx2[1024], sy2[1024], sar[1024];
  __shared__ unsigned char kp[1024];
  __shared__ int snv;
  float* bs = boxes + (long)blockIdx.x * per * 12;
  int N = per;
  if (threadIdx.x == 0) snv = 0;
  __syncthreads();
  for (int i = threadIdx.x; i < N; i += blockDim.x) {
    const float* b = bs + (long)i * 12;
    float off = b[9] * 100000.0f;
    float a0 = b[0] + off, a1 = b[1] + off, a2 = b[2] + off, a3 = b[3] + off;
    sx1[i] = a0; sy1[i] = a1; sx2[i] = a2; sy2[i] = a3;
    sar[i] = fmaxf(a2 - a0, 0.f) * fmaxf(a3 - a1, 0.f);
    bool v = (b[10] != 0.f);
    kp[i] = v;
    if (v) atomicMax(&snv, i + 1);   // valid entries are a prefix (sorted desc)
  }
  __syncthreads();
  int nv = snv;
  for (int i = 0; i < nv; ++i) {
    if (kp[i]) {
      float xi1 = sx1[i], yi1 = sy1[i], xi2 = sx2[i], yi2 = sy2[i], ai = sar[i];
      for (int j = threadIdx.x; j < nv; j += blockDim.x) {
        if (j > i && kp[j]) {
          float iw = fmaxf(fminf(xi2, sx2[j]) - fmaxf(xi1, sx1[j]), 0.f);
          float ih = fmaxf(fminf(yi2, sy2[j]) - fmaxf(yi1, sy1[j]), 0.f);
          float inter = iw * ih;
          float iou = inter / (ai + sar[j] - inter + 1e-9f);
          if (iou > thr) kp[j] = 0;
        }
      }
    }
    __syncthreads();
  }
  for (int i = threadIdx.x; i < N; i += blockDim.x)
    bs[(long)i * 12 + 11] = kp[i] ? 1.f : 0.f;
}

// ---------------- final stage ------------------------------------------------
__global__ void k_finalkeys(const float* __restrict__ boxes, u64* __restrict__ keys,
                            int total, int padded) {
  int i = blockIdx.x * blockDim.x + threadIdx.x;
  if (i >= padded) return;
  u64 k = 0ULL;
  if (i < total) {
    const float* b = boxes + (long)i * 12;
    u32 ic = 0xFFFFFFFFu - (u32)i;
    k = (b[11] != 0.f) ? ((((u64)__float_as_uint(b[4])) << 32) | ic) : (u64)ic;
  }
  keys[i] = k;
}

__global__ void k_gatherfinal(const u64* __restrict__ keys, const float* __restrict__ boxes,
                              float* __restrict__ sel) {
  int i = blockIdx.x * blockDim.x + threadIdx.x;
  if (i >= 1024) return;
  u64 key = keys[i];
  float* o = sel + (long)i * 12;
  if ((key >> 32) == 0ULL) {
    for (int q = 0; q < 12; ++q) o[q] = 0.f;
    return;
  }
  u32 bi = 0xFFFFFFFFu - (u32)(key & 0xFFFFFFFFu);
  const float* b = boxes + (long)bi * 12;
  for (int q = 0; q < 12; ++q) o[q] = b[q];
  o[10] = 1.f;
  o[11] = 0.f;
}

__global__ void k_refine(const float* __restrict__ sel, float* __restrict__ out, int N) {
  int i = blockIdx.x * blockDim.x + threadIdx.x;
  if (i >= N) return;
  const float* b = sel + (long)i * 12;
  float keep = b[11];
  float x1 = b[0], y1 = b[1], x2 = b[2], y2 = b[3], sc = b[4];
  float rw = x2 - x1, rh = y2 - y1;
  float o0 = x1 + b[5] * rw;
  float o1 = y1 + b[6] * rh;
  float o2 = x2 + b[7] * rw;
  float o3 = y2 + b[8] * rh;
  float hh = o3 - o1, ww = o2 - o0;
  float l = fmaxf(hh, ww);
  float nx1 = o0 + ww * 0.5f - l * 0.5f;
  float ny1 = o1 + hh * 0.5f - l * 0.5f;
  out[(long)i * 5 + 0] = nx1 * keep;
  out[(long)i * 5 + 1] = ny1 * keep;
  out[(long)i * 5 + 2] = (nx1 + l) * keep;
  out[(long)i * 5 + 3] = (ny1 + l) * keep;
  out[(long)i * 5 + 4] = sc * keep;
}

extern "C" void kernel_launch(void* const* d_in, const int* in_sizes, int n_in,
                              void* d_out, int out_size, void* d_ws, size_t ws_size,
                              hipStream_t stream) {
  (void)in_sizes; (void)n_in; (void)out_size;
  const float* images = (const float*)d_in[0];
  const float* c1w = (const float*)d_in[1];
  const float* c1b = (const float*)d_in[2];
  const float* p1  = (const float*)d_in[3];
  const float* c2w = (const float*)d_in[4];
  const float* c2b = (const float*)d_in[5];
  const float* p2  = (const float*)d_in[6];
  const float* c3w = (const float*)d_in[7];
  const float* c3b = (const float*)d_in[8];
  const float* p3  = (const float*)d_in[9];
  const float* w41 = (const float*)d_in[10];
  const float* b41 = (const float*)d_in[11];
  const float* w42 = (const float*)d_in[12];
  const float* b42 = (const float*)d_in[13];
  float* ws = (float*)d_ws;

  double scl[16]; int nsc = 0;
  {
    double m = 12.0 / 20.0;
    double ml = 768.0 * m;
    double si = m;
    while (ml >= 12.0) { scl[nsc++] = si; si *= 0.709; ml *= 0.709; }
  }

  auto cdiv = [](long a, long b) { return (int)((a + b - 1) / b); };

  // per-scale dims + weight-table geometry
  int NH[NSC], PH_[NSC], H2[NSC], H3[NSC], OXB[NSC], TT[NSC], WOFF[NSC];
  float INV[NSC], KSF[NSC];
  {
    int oxb = 0, woff = 0;
    for (int s = 0; s < nsc; ++s) {
      int nh = (int)(768.0 * scl[s] + 1.0);
      NH[s] = nh;
      PH_[s] = ((nh - 2) + 1) / 2;
      H2[s] = PH_[s] - 2;
      H3[s] = H2[s] - 2;
      double inv = 1.0 / (((double)nh) / 768.0);
      INV[s] = (float)inv;
      KSF[s] = (float)(inv > 1.0 ? inv : 1.0);
      TT[s] = (int)(2.0f * KSF[s]) + 2;
      OXB[s] = oxb; oxb += nh;
      WOFF[s] = woff; woff += nh * TT[s];
    }
  }

  // candidate groupings
  static const int GA[11] = {0, 1, 2, 3, 4, 5, 6, 7, 8, 9, 10};
  static const int G1[7] = {0, 5, 6, 7, 8, 9, 10};
  static const int G2[4] = {1, 2, 3, 4};

  struct Layout {
    long HT, IMG, POOL, C2, REG, KEYS, SCR, SEL, BOX, FK, FS, SF, TBL, HD, VD, extent;
    int hdcap, vdcap;
  };

  auto calcLayout = [&](const int* const* gps, const int* gn, int ng,
                        int hdcap, int vdcap, Layout& L) {
    long htA = 0, c3A = 0, imgA = 0, poolA = 0, c2A = 0, cellsA = 0, scrA = 0;
    for (int g = 0; g < ng; ++g) {
      long ht = 0, c3 = 0, im = 0, pl = 0, c2s = 0, ck = 0, sc = 0;
      for (int q = 0; q < gn[g]; ++q) {
        int s = gps[g][q];
        ht += 24L * 768 * NH[s];
        im += 24L * NH[s] * NH[s];
        pl += 80L * PH_[s] * PH_[s];
        c2s += 128L * H2[s] * H2[s];
        c3 += 256L * H3[s] * H3[s];
        long cells = 8L * H3[s] * H3[s];
        ck += cells;
        sc += 512L * ((cells + 2047) / 2048);
      }
      if (ht > htA) htA = ht; if (c3 > c3A) c3A = c3; if (im > imgA) imgA = im;
      if (pl > poolA) poolA = pl; if (c2s > c2A) c2A = c2s;
      if (ck > cellsA) cellsA = ck; if (sc > scrA) scrA = sc;
    }
    long htR = htA > c3A ? htA : c3A;
    auto al = [](long v) { return (v + 15) & ~15L; };
    long off = 0;
    L.HT = off;   off += al(htR);
    L.IMG = off;  off += al(imgA);
    L.POOL = off; off += al(poolA);
    L.C2 = off;   off += al(c2A);
    L.REG = off;  off += al(4 * cellsA);
    L.KEYS = off; off += al(2 * cellsA);
    L.SCR = off;  off += al(2 * scrA + 16384);
    L.SEL = off;  off += al(11264);
    L.BOX = off;  off += al(67584);
    L.FK = off;   off += al(16384);
    L.FS = off;   off += al(2048);
    L.SF = off;   off += al(12288);
    L.TBL = off;  off += al(12288 + 24000);
    L.HD = off;   off += al((long)ng * 5 * hdcap);
    L.VD = off;   off += al((long)ng * 5 * vdcap);
    L.extent = off;
    L.hdcap = hdcap; L.vdcap = vdcap;
  };

  Layout LA, LB;
  {
    const int* gpsA[1] = {GA}; int gnA[1] = {11};
    calcLayout(gpsA, gnA, 1, 8192, 56320, LA);
    const int* gpsB[2] = {G1, G2}; int gnB[2] = {7, 4};
    calcLayout(gpsB, gnB, 2, 2560, 20480, LB);
  }
  bool big = (ws_size >= (size_t)LA.extent * 4);
  const Layout& L = big ? LA : LB;
  const int* GS[2]; int GN[2]; int ngroups;
  if (big) { GS[0] = GA; GN[0] = 11; ngroups = 1; }
  else { GS[0] = G1; GN[0] = 7; GS[1] = G2; GN[1] = 4; ngroups = 2; }

  u64* keys  = (u64*)(ws + L.KEYS);
  u64* scr   = (u64*)(ws + L.SCR);
  u64* selk  = (u64*)(ws + L.SEL);
  u64* fkeys = (u64*)(ws + L.FK);
  u64* fsel  = (u64*)(ws + L.FS);
  float* boxes = ws + L.BOX;
  float* self  = ws + L.SF;
  int*   tX0  = (int*)(ws + L.TBL);
  int*   tCNT = (int*)(ws + L.TBL + 4096);
  float* tWT  = ws + L.TBL + 8192;
  float* tW   = ws + L.TBL + 12288;

  // build resize weight tables (once per launch)
  {
    MkP P; P.ns = nsc;
    for (int s = 0; s < nsc; ++s) {
      P.nw[s] = NH[s]; P.invs[s] = INV[s]; P.ks[s] = KSF[s];
      P.oxB[s] = OXB[s]; P.T[s] = TT[s]; P.wOff[s] = WOFF[s];
    }
    k_mkweights<<<nsc, TPB, 0, stream>>>(tX0, tCNT, tWT, tW, P);
  }

  // per-group geometry
  int imgOff[2][NJMAX], poolOff[2][NJMAX], c2Off[2][NJMAX], c3Off[2][NJMAX],
      htOff[2][NJMAX], kOff[2][NJMAX], cells[2][NJMAX];
  int cumWtot[2], cumRtot[2];
  for (int g = 0; g < ngroups; ++g) {
    long ch = 0, ci = 0, cp = 0, c2 = 0, c3 = 0, ck = 0;
    int cw = 0, cr = 0;
    for (int q = 0; q < GN[g]; ++q) {
      int s = GS[g][q];
      htOff[g][q] = (int)ch;  ch += 24L * 768 * NH[s];
      imgOff[g][q] = (int)ci; ci += 24L * NH[s] * NH[s];
      poolOff[g][q] = (int)cp; cp += 80L * PH_[s] * PH_[s];
      c2Off[g][q] = (int)c2;  c2 += 128L * H2[s] * H2[s];
      c3Off[g][q] = (int)c3;  c3 += 256L * H3[s] * H3[s];
      kOff[g][q] = (int)ck;   cells[g][q] = 8 * H3[s] * H3[s]; ck += cells[g][q];
      cw += 3 * NH[s]; cr += 24 * NH[s];
    }
    cumWtot[g] = cw; cumRtot[g] = cr;
  }

  // build H/V descriptors (geometry-only)
  for (int g = 0; g < ngroups; ++g) {
    DscP P; P.nj = GN[g];
    int cw = 0, cr = 0;
    for (int q = 0; q < GN[g]; ++q) {
      int s = GS[g][q];
      P.N[q] = NH[s]; P.hOff[q] = htOff[g][q]; P.imgOff[q] = imgOff[g][q];
      P.oxB[q] = OXB[s]; P.wOff[q] = WOFF[s];
      P.cumW[q] = cw; cw += 3 * NH[s];
      P.cumR[q] = cr; cr += 24 * NH[s];
    }
    P.cumW[GN[g]] = cw; P.cumR[GN[g]] = cr;
    int* hd = (int*)(ws + L.HD) + (long)g * 5 * L.hdcap;
    int* vd = (int*)(ws + L.VD) + (long)g * 5 * L.vdcap;
    int tot = cw > cr ? cw : cr;
    k_mkdesc<<<cdiv(tot, TPB), TPB, 0, stream>>>(hd, vd, L.hdcap, L.vdcap, P);
  }

  // ---------------- unified job pipeline over groups ----------------
  for (int g = 0; g < ngroups; ++g) {
    const int* gs = GS[g];
    int nj = GN[g];
    int* hd = (int*)(ws + L.HD) + (long)g * 5 * L.hdcap;
    int* vd = (int*)(ws + L.VD) + (long)g * 5 * L.vdcap;
    // H pass (one image read for the whole group)
    {
      dim3 gh(768, 8, 1);
      k_resizeH_d<<<gh, TPB, 0, stream>>>(images, ws + L.HT, tX0, tCNT, tWT, tW,
                                          hd, L.hdcap, cumWtot[g]);
    }
    // V pass: one wave per output row
    k_resizeV_row<<<cdiv(cumRtot[g], 4), TPB, 0, stream>>>(
        ws + L.HT, ws + L.IMG, tX0, tCNT, tWT, tW, vd, L.vdcap, cumRtot[g]);
    // conv1+pool (all 10 co per block)
    {
      C1P P; P.nj = nj; int ct = 0;
      for (int q = 0; q < nj; ++q) {
        int s = gs[q];
        P.nh[q] = NH[s];
        P.imgOff[q] = imgOff[g][q]; P.poolOff[q] = poolOff[g][q];
        int t1x = cdiv(PH_[s], 16);
        P.t1x[q] = t1x;
        P.cumT[q] = ct; ct += t1x * t1x;
      }
      P.cumT[nj] = ct;
      dim3 gg(ct, 1, 8);
      k_conv1pool_job<<<gg, TPB, 0, stream>>>(ws + L.IMG, c1w, c1b, p1, ws + L.POOL, P);
    }
    // conv2 (16 co in 2 groups of 8)
    {
      CvP P; P.nj = nj; int ct = 0;
      for (int q = 0; q < nj; ++q) {
        int s = gs[q];
        P.H[q] = PH_[s];
        P.inOff[q] = poolOff[g][q]; P.outOff[q] = c2Off[g][q];
        int tx = cdiv(H2[s], 64), ty = cdiv(H2[s], 16);
        P.tx[q] = tx;
        P.cumT[q] = ct; ct += tx * ty;
      }
      P.cumT[nj] = ct;
      dim3 gg(ct, 2, 8);
      k_conv3x3c8_job<<<gg, TPB, 0, stream>>>(ws + L.POOL, c2w, c2b, p2, ws + L.C2,
                                              10, 16, P);
    }
    // conv3 (32 co in 4 groups of 8; writes into HT region)
    {
      CvP P; P.nj = nj; int ct = 0;
      for (int q = 0; q < nj; ++q) {
        int s = gs[q];
        P.H[q] = H2[s];
        P.inOff[q] = c2Off[g][q]; P.outOff[q] = c3Off[g][q];
        int tx = cdiv(H3[s], 64), ty = cdiv(H3[s], 16);
        P.tx[q] = tx;
        P.cumT[q] = ct; ct += tx * ty;
      }
      P.cumT[nj] = ct;
      dim3 gg(ct, 4, 8);
      k_conv3x3c8_job<<<gg, TPB, 0, stream>>>(ws + L.C2, c3w, c3b, p3, ws + L.HT,
                                              16, 32, P);
    }
    // heads
    {
      HdP P; P.nj = nj; int cc = 0;
      for (int q = 0; q < nj; ++q) {
        int s = gs[q];
        P.h3[q] = H3[s];
        P.c3Off[q] = c3Off[g][q]; P.kOff[q] = kOff[g][q];
        P.cumC[q] = cc; cc += cells[g][q];
      }
      P.cumC[nj] = cc;
      k_head_job<<<cdiv(cc, TPB), TPB, 0, stream>>>(ws + L.HT, w41, b41, w42, b42,
                                                    ws + L.REG, keys, P);
    }
    // batched top-512 tournament
    {
      int bOff[NJMAX];
      {
        int c = 0;
        for (int q = 0; q < nj; ++q) { bOff[q] = c; c += 512 * cdiv(cells[g][q], 2048); }
      }
      long nCur[NJMAX]; int par[NJMAX];
      for (int q = 0; q < nj; ++q) { nCur[q] = cells[g][q]; par[q] = 0; }
      while (true) {
        TkP P; P.nj = 0; int cum = 0; int act[NJMAX];
        for (int q = 0; q < nj; ++q) {
          if (nCur[q] > 2048) {
            int r = P.nj++;
            act[r] = q;
            int blocks = cdiv(nCur[q], 2048);
            P.srcSel[r] = par[q];
            P.srcOff[r] = par[q] ? bOff[q] : kOff[g][q];
            P.dstOff[r] = par[q] ? kOff[g][q] : bOff[q];
            P.n[r] = (int)nCur[q];
            P.cumB[r] = cum; cum += blocks;
          }
        }
        P.cumB[P.nj] = cum;
        if (P.nj == 0) break;
        k_topk_job<<<cum, TPB, 0, stream>>>(keys, scr, P);
        for (int r = 0; r < P.nj; ++r) {
          int q = act[r];
          nCur[q] = 512L * cdiv(nCur[q], 2048);
          par[q] ^= 1;
        }
      }
      TkFP F; F.nj = nj;
      for (int q = 0; q < nj; ++q) {
        F.srcSel[q] = par[q];
        F.srcOff[q] = par[q] ? bOff[q] : kOff[g][q];
        F.n[q] = (int)nCur[q];
        F.sIdx[q] = gs[q];
      }
      k_topk_fin<<<nj, TPB, 0, stream>>>(keys, scr, selk, F);
    }
    // gather
    {
      GtP P; P.nj = nj;
      for (int q = 0; q < nj; ++q) {
        int s = gs[q];
        P.h3[q] = H3[s]; P.scalef[q] = (float)scl[s]; P.kOff[q] = kOff[g][q];
        P.sIdx[q] = s;
      }
      k_gather_job<<<2 * nj, TPB, 0, stream>>>(selk, ws + L.REG, boxes, P);
    }
  }

  // ---------------- per-scale NMS + final stage ----------------
  k_nms<<<nsc, TPB, 0, stream>>>(boxes, 512, 0.5f);

  int total = nsc * 512;
  k_finalkeys<<<cdiv(8192, TPB), TPB, 0, stream>>>(boxes, fkeys, total, 8192);
  k_topk<<<4, TPB, 0, stream>>>(fkeys, 8192, scr, 1024);
  k_topk<<<2, TPB, 0, stream>>>(scr, 4096, keys, 1024);
  k_topk<<<1, TPB, 0, stream>>>(keys, 2048, fsel, 1024);
  k_gatherfinal<<<4, TPB, 0, stream>>>(fsel, boxes, self);
  k_nms<<<1, TPB, 0, stream>>>(self, 1024, 0.7f);
  k_refine<<<4, TPB, 0, stream>>>(self, (float*)d_out, 1024);
}

// Round 16
// 1114.268 us; speedup vs baseline: 1.1515x; 1.0341x over previous
//
#include <hip/hip_runtime.h>
#include <stdint.h>

typedef unsigned long long u64;
typedef unsigned int u32;

#define TPB 256
#define NJMAX 12
#define NSC 11

__device__ __forceinline__ int findJob(const int* cum, int nj, int v) {
  int j = 0;
  while (j + 1 < nj && v >= cum[j + 1]) ++j;
  return j;
}

// ---------------- resize weight tables (per scale, per output position) -----
// tW layout: TRANSPOSED [k][ox]: tW[wOff + k*nh + ox]  (coalesced lane reads)
struct MkP { int ns; int nw[NSC]; float invs[NSC], ks[NSC];
             int oxB[NSC], T[NSC], wOff[NSC]; };

__global__ void k_mkweights(int* __restrict__ tX0, int* __restrict__ tCNT,
                            float* __restrict__ tWT, float* __restrict__ tW, MkP P) {
  const int s = blockIdx.x;
  const int nw = P.nw[s];
  const float invs = P.invs[s], ks = P.ks[s];
  const int T = P.T[s];
  for (int ox = threadIdx.x; ox < nw; ox += TPB) {
    float sx = ((float)ox + 0.5f) * invs - 0.5f;
    int x0 = (int)ceilf(sx - ks); if (x0 < 0) x0 = 0;
    int x1 = (int)floorf(sx + ks); if (x1 > 767) x1 = 767;
    float wt = 0.f;
    float* wv = tW + P.wOff[s];
    for (int j = x0; j <= x1; ++j) {
      float w = fmaxf(0.f, 1.f - fabsf(sx - (float)j) / ks);
      wt += w;
      wv[(j - x0) * nw + ox] = w;
    }
    for (int k = x1 - x0 + 1; k < T; ++k) wv[k * nw + ox] = 0.f;
    int g = P.oxB[s] + ox;
    tX0[g] = x0; tCNT[g] = x1 - x0 + 1; tWT[g] = wt;
  }
}

// ---------------- descriptor builder (geometry-only, once per group) --------
struct DscP { int nj; int N[NJMAX]; int hOff[NJMAX], imgOff[NJMAX];
              int oxB[NJMAX], wOff[NJMAX];
              int cumW[NJMAX + 1], cumR[NJMAX + 1]; };

__global__ void k_mkdesc(int* __restrict__ hd, int* __restrict__ vd,
                         int hdcap, int vdcap, DscP P) {
  int gid = blockIdx.x * TPB + threadIdx.x;
  int totW = P.cumW[P.nj], totR = P.cumR[P.nj];
  if (gid < totW) {
    int j = findJob(P.cumW, P.nj, gid);
    int local = gid - P.cumW[j];
    int N = P.N[j];
    int ox = local % N, c = local / N;
    hd[gid]             = P.hOff[j] + c * 768 * N + ox;   // A
    hd[hdcap + gid]     = c * 769;                        // R (LDS row base)
    hd[2 * hdcap + gid] = N;                              // stride
    hd[3 * hdcap + gid] = P.oxB[j] + ox;                  // g
    hd[4 * hdcap + gid] = P.wOff[j] + ox;                 // W
  }
  if (gid < totR) {
    int j = findJob(P.cumR, P.nj, gid);
    int local = gid - P.cumR[j];
    int N = P.N[j];
    int oy = local % N, q = local / N;   // q = b*3+c in 0..23
    vd[gid]             = P.hOff[j] + q * 768 * N;        // S (src col base)
    vd[vdcap + gid]     = P.imgOff[j] + (q * N + oy) * N; // O (out row base)
    vd[2 * vdcap + gid] = P.oxB[j] + oy;                  // g
    vd[3 * vdcap + gid] = P.wOff[j] + oy;                 // W
    vd[4 * vdcap + gid] = N;                              // stride
  }
}

// ---------------- H pass: descriptor-driven, row-resident -------------------
__global__ void k_resizeH_d(const float* __restrict__ img, float* __restrict__ base,
                            const int* __restrict__ tX0, const int* __restrict__ tCNT,
                            const float* __restrict__ tWT, const float* __restrict__ tW,
                            const int* __restrict__ hd, int hdcap, int total) {
  __shared__ float row[3][769];
  const int y = blockIdx.x, b = blockIdx.y;
  const float* src = img + ((long)b * 768 + y) * 768 * 3;
  for (int t = threadIdx.x; t < 2304; t += TPB) {
    int x = t / 3, c = t - 3 * x;
    row[c][x] = src[t];
  }
  __syncthreads();
  const float* rowF = &row[0][0];
  const long yb = (long)y + 2304L * b;
  for (int t = threadIdx.x; t < total; t += TPB) {
    int A = hd[t];
    int R = hd[hdcap + t];
    int N = hd[2 * hdcap + t];
    int g = hd[3 * hdcap + t];
    int W = hd[4 * hdcap + t];
    int x0 = tX0[g], cnt = tCNT[g];
    float wt = tWT[g];
    const float* wv = tW + W;
    const float* rp = rowF + R + x0;
    float acc = 0.f;
    int k = 0;
    for (; k + 3 < cnt; k += 4) {
      float v0 = rp[k],     w0 = wv[(long)k * N];
      float v1 = rp[k + 1], w1 = wv[(long)(k + 1) * N];
      float v2 = rp[k + 2], w2 = wv[(long)(k + 2) * N];
      float v3 = rp[k + 3], w3 = wv[(long)(k + 3) * N];
      acc += v0 * w0; acc += v1 * w1; acc += v2 * w2; acc += v3 * w3;
    }
    for (; k < cnt; ++k) acc += rp[k] * wv[(long)k * N];
    base[(long)A + (long)N * yb] = acc / wt;
  }
}

// ---------------- V pass: one 64-lane wave per output row -------------------
__global__ void k_resizeV_row(const float* __restrict__ basep, float* __restrict__ img,
                              const int* __restrict__ tX0, const int* __restrict__ tCNT,
                              const float* __restrict__ tWT, const float* __restrict__ tW,
                              const int* __restrict__ vd, int vdcap, int nRows) {
  int row = blockIdx.x * 4 + (threadIdx.x >> 6);
  if (row >= nRows) return;
  int lane = threadIdx.x & 63;
  int S = vd[row];
  int O = vd[vdcap + row];
  int g = vd[2 * vdcap + row];
  int W = vd[3 * vdcap + row];
  int N = vd[4 * vdcap + row];
  int y0 = tX0[g], cnt = tCNT[g];
  float wt = tWT[g];
  const float* wv = tW + W;
  const float* col0 = basep + S + (long)y0 * N;
  for (int ox = lane; ox < N; ox += 64) {
    const float* col = col0 + ox;
    float acc = 0.f;
    int k = 0;
    for (; k + 3 < cnt; k += 4) {
      float v0 = col[(long)k * N],       w0 = wv[(long)k * N];
      float v1 = col[(long)(k + 1) * N], w1 = wv[(long)(k + 1) * N];
      float v2 = col[(long)(k + 2) * N], w2 = wv[(long)(k + 2) * N];
      float v3 = col[(long)(k + 3) * N], w3 = wv[(long)(k + 3) * N];
      acc += v0 * w0; acc += v1 * w1; acc += v2 * w2; acc += v3 * w3;
    }
    for (; k < cnt; ++k) acc += col[(long)k * N] * wv[(long)k * N];
    img[(long)O + ox] = (acc / wt - 127.5f) * 0.0078125f;
  }
}

// ---------------- fused conv1 + PReLU + 2x2 ceil-maxpool (all 10 co) --------
__device__ __forceinline__ void conv1pool_body(
    const float* in, const float* w, const float* bias, const float* pr,
    float* out, int H, int W, int b, int px, int py) {
  const int h1 = H - 2, w1 = W - 2;
  const int PH = (h1 + 1) >> 1, PW = (w1 + 1) >> 1;
  if (px >= PW || py >= PH) return;
  const int x0 = px * 2, y0 = py * 2;
  float a00[10], a01[10], a10[10], a11[10];
#pragma unroll
  for (int co = 0; co < 10; ++co) { a00[co] = 0.f; a01[co] = 0.f; a10[co] = 0.f; a11[co] = 0.f; }
  const long HW = (long)H * W;
  const float* pp = in + ((long)b * 3 * H + y0) * W + x0;
  for (int ci = 0; ci < 3; ++ci, pp += HW) {
    const float* r = pp;
    float r00 = r[0], r01 = r[1], r02 = r[2], r03 = r[3]; r += W;
    float r10 = r[0], r11 = r[1], r12 = r[2], r13 = r[3]; r += W;
    float r20 = r[0], r21 = r[1], r22 = r[2], r23 = r[3]; r += W;
    float r30 = r[0], r31 = r[1], r32 = r[2], r33 = r[3];
#pragma unroll
    for (int co = 0; co < 10; ++co) {
      const float* wc = w + ((long)co * 3 + ci) * 9;
      float w0 = wc[0], w1_ = wc[1], w2 = wc[2];
      float w3 = wc[3], w4 = wc[4], w5 = wc[5];
      float w6 = wc[6], w7 = wc[7], w8 = wc[8];
      a00[co] += r00 * w0 + r01 * w1_ + r02 * w2;
      a00[co] += r10 * w3 + r11 * w4 + r12 * w5;
      a00[co] += r20 * w6 + r21 * w7 + r22 * w8;
      a01[co] += r01 * w0 + r02 * w1_ + r03 * w2;
      a01[co] += r11 * w3 + r12 * w4 + r13 * w5;
      a01[co] += r21 * w6 + r22 * w7 + r23 * w8;
      a10[co] += r10 * w0 + r11 * w1_ + r12 * w2;
      a10[co] += r20 * w3 + r21 * w4 + r22 * w5;
      a10[co] += r30 * w6 + r31 * w7 + r32 * w8;
      a11[co] += r11 * w0 + r12 * w1_ + r13 * w2;
      a11[co] += r21 * w3 + r22 * w4 + r23 * w5;
      a11[co] += r31 * w6 + r32 * w7 + r33 * w8;
    }
  }
  const bool vx = (x0 + 1 < w1), vy = (y0 + 1 < h1);
#pragma unroll
  for (int co = 0; co < 10; ++co) {
    const float bb = bias[co], al = pr[co];
    float v = a00[co] + bb; v = v > 0.f ? v : al * v;
    float m = v;
    if (vx) { v = a01[co] + bb; v = v > 0.f ? v : al * v; m = fmaxf(m, v); }
    if (vy) { v = a10[co] + bb; v = v > 0.f ? v : al * v; m = fmaxf(m, v); }
    if (vx && vy) { v = a11[co] + bb; v = v > 0.f ? v : al * v; m = fmaxf(m, v); }
    out[(((long)b * 10 + co) * PH + py) * PW + px] = m;
  }
}

struct C1P { int nj; int nh[NJMAX]; int imgOff[NJMAX], poolOff[NJMAX];
             int t1x[NJMAX]; int cumT[NJMAX + 1]; };

__global__ void k_conv1pool_job(const float* __restrict__ imgb, const float* __restrict__ w,
                                const float* __restrict__ bias, const float* __restrict__ pr,
                                float* __restrict__ poolb, C1P P) {
  int j = findJob(P.cumT, P.nj, blockIdx.x);
  int local = blockIdx.x - P.cumT[j];
  int t1x = P.t1x[j];
  int tX = local % t1x, tY = local / t1x;
  conv1pool_body(imgb + P.imgOff[j], w, bias, pr, poolb + P.poolOff[j],
                 P.nh[j], P.nh[j], blockIdx.z,
                 tX * 16 + (threadIdx.x & 15), tY * 16 + (threadIdx.x >> 4));
}

// ---------------- co-blocked (8) tiled 3x3 conv + PReLU ---------------------
__device__ __forceinline__ void conv3x3c8_body(
    const float* in, const float* w, const float* bias, const float* pr,
    float* out, int Cin, int Cout, int H, int W, int cog, int b, int x0, int y) {
  const int OH = H - 2, OW = W - 2;
  if (y >= OH || x0 >= OW) return;
  float acc[8][4];
#pragma unroll
  for (int k = 0; k < 8; ++k) { acc[k][0] = 0.f; acc[k][1] = 0.f; acc[k][2] = 0.f; acc[k][3] = 0.f; }
  const float* wp = w + (long)cog * Cin * 9;
  const long HW = (long)H * W;
  const float* pp = in + ((long)b * Cin * H + y) * W + x0;
  for (int ci = 0; ci < Cin; ++ci, pp += HW) {
    const float* r = pp;
    float q00 = r[0], q01 = r[1], q02 = r[2], q03 = r[3], q04 = r[4], q05 = r[5]; r += W;
    float q10 = r[0], q11 = r[1], q12 = r[2], q13 = r[3], q14 = r[4], q15 = r[5]; r += W;
    float q20 = r[0], q21 = r[1], q22 = r[2], q23 = r[3], q24 = r[4], q25 = r[5];
#pragma unroll
    for (int k = 0; k < 8; ++k) {
      const float* wc = wp + ((long)k * Cin + ci) * 9;
      float w0 = wc[0], w1 = wc[1], w2 = wc[2];
      float w3 = wc[3], w4 = wc[4], w5 = wc[5];
      float w6 = wc[6], w7 = wc[7], w8 = wc[8];
      acc[k][0] += q00 * w0 + q01 * w1 + q02 * w2;
      acc[k][1] += q01 * w0 + q02 * w1 + q03 * w2;
      acc[k][2] += q02 * w0 + q03 * w1 + q04 * w2;
      acc[k][3] += q03 * w0 + q04 * w1 + q05 * w2;
      acc[k][0] += q10 * w3 + q11 * w4 + q12 * w5;
      acc[k][1] += q11 * w3 + q12 * w4 + q13 * w5;
      acc[k][2] += q12 * w3 + q13 * w4 + q14 * w5;
      acc[k][3] += q13 * w3 + q14 * w4 + q15 * w5;
      acc[k][0] += q20 * w6 + q21 * w7 + q22 * w8;
      acc[k][1] += q21 * w6 + q22 * w7 + q23 * w8;
      acc[k][2] += q22 * w6 + q23 * w7 + q24 * w8;
      acc[k][3] += q23 * w6 + q24 * w7 + q25 * w8;
    }
  }
  const int rem = OW - x0;
#pragma unroll
  for (int k = 0; k < 8; ++k) {
    const int co = cog + k;
    const float bb = bias[co], al = pr[co];
    float* op = out + (((long)b * Cout + co) * OH + y) * OW + x0;
    float v0 = acc[k][0] + bb; v0 = v0 > 0.f ? v0 : al * v0;
    op[0] = v0;
    if (rem > 1) { float v = acc[k][1] + bb; v = v > 0.f ? v : al * v; op[1] = v; }
    if (rem > 2) { float v = acc[k][2] + bb; v = v > 0.f ? v : al * v; op[2] = v; }
    if (rem > 3) { float v = acc[k][3] + bb; v = v > 0.f ? v : al * v; op[3] = v; }
  }
}

struct CvP { int nj; int H[NJMAX]; int inOff[NJMAX], outOff[NJMAX];
             int tx[NJMAX]; int cumT[NJMAX + 1]; };

__global__ void k_conv3x3c8_job(const float* __restrict__ inb, const float* __restrict__ w,
                                const float* __restrict__ bias, const float* __restrict__ pr,
                                float* __restrict__ outb, int Cin, int Cout, CvP P) {
  int j = findJob(P.cumT, P.nj, blockIdx.x);
  int local = blockIdx.x - P.cumT[j];
  int tx0 = P.tx[j];
  int tX = local % tx0, tY = local / tx0;
  conv3x3c8_body(inb + P.inOff[j], w, bias, pr, outb + P.outOff[j], Cin, Cout,
                 P.H[j], P.H[j], blockIdx.y * 8, blockIdx.z,
                 tX * 64 + (threadIdx.x & 15) * 4, tY * 16 + (threadIdx.x >> 4));
}

// ---------------- 1x1 heads -------------------------------------------------
__device__ __forceinline__ void head_body(const float* x3, const float* w41,
                                          const float* b41, const float* w42,
                                          const float* b42, float* reg, u64* keys,
                                          int plane, long idx) {
  int b = (int)(idx / plane); int rem = (int)(idx % plane);
  const float* p = x3 + (long)b * 32 * plane + rem;
  float l0 = 0.f, l1 = 0.f, r0 = 0.f, r1 = 0.f, r2 = 0.f, r3 = 0.f;
  for (int c = 0; c < 32; ++c) {
    float v = p[(long)c * plane];
    l0 += v * w41[c];      l1 += v * w41[32 + c];
    r0 += v * w42[c];      r1 += v * w42[32 + c];
    r2 += v * w42[64 + c]; r3 += v * w42[96 + c];
  }
  l0 += b41[0]; l1 += b41[1];
  r0 += b42[0]; r1 += b42[1]; r2 += b42[2]; r3 += b42[3];
  float mx = fmaxf(l0, l1);
  float e0 = expf(l0 - mx), e1 = expf(l1 - mx);
  float s = e1 / (e0 + e1);
  reg[idx * 4 + 0] = r0; reg[idx * 4 + 1] = r1;
  reg[idx * 4 + 2] = r2; reg[idx * 4 + 3] = r3;
  u32 ic = 0xFFFFFFFFu - (u32)idx;
  u64 k = (s >= 0.6f) ? ((((u64)__float_as_uint(s)) << 32) | ic) : (u64)ic;
  keys[idx] = k;
}

struct HdP { int nj; int h3[NJMAX]; int c3Off[NJMAX], kOff[NJMAX];
             int cumC[NJMAX + 1]; };

__global__ void k_head_job(const float* __restrict__ c3b, const float* __restrict__ w41,
                           const float* __restrict__ b41, const float* __restrict__ w42,
                           const float* __restrict__ b42, float* __restrict__ regb,
                           u64* __restrict__ keysb, HdP P) {
  int gid = blockIdx.x * TPB + threadIdx.x;
  if (gid >= P.cumC[P.nj]) return;
  int j = findJob(P.cumC, P.nj, gid);
  int idx = gid - P.cumC[j];
  head_body(c3b + P.c3Off[j], w41, b41, w42, b42,
            regb + 4L * P.kOff[j], keysb + P.kOff[j], P.h3[j] * P.h3[j], idx);
}

// ---------------- bitonic top-K ---------------------------------------------
__device__ __forceinline__ void bitonic2048(u64* s) {
  for (int k = 2; k <= 2048; k <<= 1) {
    for (int j = k >> 1; j > 0; j >>= 1) {
      for (int i = threadIdx.x; i < 2048; i += TPB) {
        int ixj = i ^ j;
        if (ixj > i) {
          u64 a = s[i], b = s[ixj];
          bool desc = ((i & k) == 0);
          if (desc ? (a < b) : (a > b)) { s[i] = b; s[ixj] = a; }
        }
      }
      __syncthreads();
    }
  }
}

__global__ void k_topk(const u64* __restrict__ in, int n, u64* __restrict__ out, int K) {
  __shared__ u64 s[2048];
  int base = blockIdx.x * 2048;
  for (int t = threadIdx.x; t < 2048; t += TPB) {
    int gi = base + t;
    s[t] = (gi < n) ? in[gi] : 0ULL;
  }
  __syncthreads();
  bitonic2048(s);
  for (int t = threadIdx.x; t < K; t += TPB)
    out[(long)blockIdx.x * K + t] = s[t];
}

struct TkP { int nj; int srcSel[NJMAX]; int srcOff[NJMAX]; int n[NJMAX];
             int dstOff[NJMAX]; int cumB[NJMAX + 1]; };

__global__ void k_topk_job(u64* __restrict__ A, u64* __restrict__ B, TkP P) {
  __shared__ u64 s[2048];
  int j = findJob(P.cumB, P.nj, blockIdx.x);
  int lb = blockIdx.x - P.cumB[j];
  const u64* src = (P.srcSel[j] ? B : A) + P.srcOff[j];
  u64* dst = (P.srcSel[j] ? A : B) + P.dstOff[j];
  int n = P.n[j];
  int base = lb * 2048;
  for (int t = threadIdx.x; t < 2048; t += TPB) {
    int gi = base + t;
    s[t] = (gi < n) ? src[gi] : 0ULL;
  }
  __syncthreads();
  bitonic2048(s);
  for (int t = threadIdx.x; t < 512; t += TPB)
    dst[(long)lb * 512 + t] = s[t];
}

struct TkFP { int nj; int srcSel[NJMAX]; int srcOff[NJMAX]; int n[NJMAX]; int sIdx[NJMAX]; };

__global__ void k_topk_fin(const u64* __restrict__ A, const u64* __restrict__ B,
                           u64* __restrict__ selk, TkFP P) {
  __shared__ u64 s[2048];
  int j = blockIdx.x;
  const u64* src = (P.srcSel[j] ? B : A) + P.srcOff[j];
  int n = P.n[j];
  for (int t = threadIdx.x; t < 2048; t += TPB)
    s[t] = (t < n) ? src[t] : 0ULL;
  __syncthreads();
  bitonic2048(s);
  for (int t = threadIdx.x; t < 512; t += TPB)
    selk[(long)P.sIdx[j] * 512 + t] = s[t];
}

// ---------------- gather box rows -------------------------------------------
__device__ __forceinline__ void gather_body(const u64* keys, const float* reg,
                                            float* boxes, int h, int w, float scalef,
                                            int i) {
  float* bx = boxes + (long)i * 12;
  u64 key = keys[i];
  if ((key >> 32) == 0ULL) {
    for (int q = 0; q < 12; ++q) bx[q] = 0.f;
    return;
  }
  u32 cell = 0xFFFFFFFFu - (u32)(key & 0xFFFFFFFFu);
  int x = (int)(cell % (u32)w); u32 t2 = cell / (u32)w;
  int y = (int)(t2 % (u32)h); int b = (int)(t2 / (u32)h);
  float fx = (float)x, fy = (float)y;
  bx[0] = floorf((2.f * fx + 1.f) / scalef);
  bx[1] = floorf((2.f * fy + 1.f) / scalef);
  bx[2] = floorf((2.f * fx + 12.f) / scalef);
  bx[3] = floorf((2.f * fy + 12.f) / scalef);
  bx[4] = __uint_as_float((u32)(key >> 32));
  bx[5] = reg[(long)cell * 4 + 0];
  bx[6] = reg[(long)cell * 4 + 1];
  bx[7] = reg[(long)cell * 4 + 2];
  bx[8] = reg[(long)cell * 4 + 3];
  bx[9] = (float)b;
  bx[10] = 1.f;
  bx[11] = 0.f;
}

struct GtP { int nj; int h3[NJMAX]; float scalef[NJMAX]; int kOff[NJMAX]; int sIdx[NJMAX]; };

__global__ void k_gather_job(const u64* __restrict__ selk, const float* __restrict__ regb,
                             float* __restrict__ boxes, GtP P) {
  int j = blockIdx.x >> 1;
  int i = ((blockIdx.x & 1) << 8) + threadIdx.x;
  gather_body(selk + (long)P.sIdx[j] * 512, regb + 4L * P.kOff[j],
              boxes + (long)P.sIdx[j] * 512 * 12, P.h3[j], P.h3[j], P.scalef[j], i);
}

// ---------------- greedy NMS (shared-memory form, proven) --------------------
__global__ void k_nms(float* __restrict__ boxes, int per, float thr) {
  __shared__ float sx1[1024], sy1[1024], sx2[1024], sy2[1024], sar[1024];
  __shared__ unsigned char kp[1024];
  __shared__ int snv;
  float* bs = boxes + (long)blockIdx.x * per * 12;
  int N = per;
  if (threadIdx.x == 0) snv = 0;
  __syncthreads();
  for (int i = threadIdx.x; i < N; i += blockDim.x) {
    const float* b = bs + (long)i * 12;
    float off = b[9] * 100000.0f;
    float a0 = b[0] + off, a1 = b[1] + off, a2 = b[2] + off, a3 = b[3] + off;
    sx1[i] = a0; sy1[i] = a1; sx2[i] = a2; sy2[i] = a3;
    sar[i] = fmaxf(a2 - a0, 0.f) * fmaxf(a3 - a1, 0.f);
    bool v = (b[10] != 0.f);
    kp[i] = v;
    if (v) atomicMax(&snv, i + 1);   // valid entries are a prefix (sorted desc)
  }
  __syncthreads();
  int nv = snv;
  for (int i = 0; i < nv; ++i) {
    if (kp[i]) {
      float xi1 = sx1[i], yi1 = sy1[i], xi2 = sx2[i], yi2 = sy2[i], ai = sar[i];
      for (int j = threadIdx.x; j < nv; j += blockDim.x) {
        if (j > i && kp[j]) {
          float iw = fmaxf(fminf(xi2, sx2[j]) - fmaxf(xi1, sx1[j]), 0.f);
          float ih = fmaxf(fminf(yi2, sy2[j]) - fmaxf(yi1, sy1[j]), 0.f);
          float inter = iw * ih;
          float iou = inter / (ai + sar[j] - inter + 1e-9f);
          if (iou > thr) kp[j] = 0;
        }
      }
    }
    __syncthreads();
  }
  for (int i = threadIdx.x; i < N; i += blockDim.x)
    bs[(long)i * 12 + 11] = kp[i] ? 1.f : 0.f;
}

// ---------------- final stage ------------------------------------------------
__global__ void k_finalkeys(const float* __restrict__ boxes, u64* __restrict__ keys,
                            int total, int padded) {
  int i = blockIdx.x * blockDim.x + threadIdx.x;
  if (i >= padded) return;
  u64 k = 0ULL;
  if (i < total) {
    const float* b = boxes + (long)i * 12;
    u32 ic = 0xFFFFFFFFu - (u32)i;
    k = (b[11] != 0.f) ? ((((u64)__float_as_uint(b[4])) << 32) | ic) : (u64)ic;
  }
  keys[i] = k;
}

__global__ void k_gatherfinal(const u64* __restrict__ keys, const float* __restrict__ boxes,
                              float* __restrict__ sel) {
  int i = blockIdx.x * blockDim.x + threadIdx.x;
  if (i >= 1024) return;
  u64 key = keys[i];
  float* o = sel + (long)i * 12;
  if ((key >> 32) == 0ULL) {
    for (int q = 0; q < 12; ++q) o[q] = 0.f;
    return;
  }
  u32 bi = 0xFFFFFFFFu - (u32)(key & 0xFFFFFFFFu);
  const float* b = boxes + (long)bi * 12;
  for (int q = 0; q < 12; ++q) o[q] = b[q];
  o[10] = 1.f;
  o[11] = 0.f;
}

__global__ void k_refine(const float* __restrict__ sel, float* __restrict__ out, int N) {
  int i = blockIdx.x * blockDim.x + threadIdx.x;
  if (i >= N) return;
  const float* b = sel + (long)i * 12;
  float keep = b[11];
  float x1 = b[0], y1 = b[1], x2 = b[2], y2 = b[3], sc = b[4];
  float rw = x2 - x1, rh = y2 - y1;
  float o0 = x1 + b[5] * rw;
  float o1 = y1 + b[6] * rh;
  float o2 = x2 + b[7] * rw;
  float o3 = y2 + b[8] * rh;
  float hh = o3 - o1, ww = o2 - o0;
  float l = fmaxf(hh, ww);
  float nx1 = o0 + ww * 0.5f - l * 0.5f;
  float ny1 = o1 + hh * 0.5f - l * 0.5f;
  out[(long)i * 5 + 0] = nx1 * keep;
  out[(long)i * 5 + 1] = ny1 * keep;
  out[(long)i * 5 + 2] = (nx1 + l) * keep;
  out[(long)i * 5 + 3] = (ny1 + l) * keep;
  out[(long)i * 5 + 4] = sc * keep;
}

extern "C" void kernel_launch(void* const* d_in, const int* in_sizes, int n_in,
                              void* d_out, int out_size, void* d_ws, size_t ws_size,
                              hipStream_t stream) {
  (void)in_sizes; (void)n_in; (void)out_size;
  const float* images = (const float*)d_in[0];
  const float* c1w = (const float*)d_in[1];
  const float* c1b = (const float*)d_in[2];
  const float* p1  = (const float*)d_in[3];
  const float* c2w = (const float*)d_in[4];
  const float* c2b = (const float*)d_in[5];
  const float* p2  = (const float*)d_in[6];
  const float* c3w = (const float*)d_in[7];
  const float* c3b = (const float*)d_in[8];
  const float* p3  = (const float*)d_in[9];
  const float* w41 = (const float*)d_in[10];
  const float* b41 = (const float*)d_in[11];
  const float* w42 = (const float*)d_in[12];
  const float* b42 = (const float*)d_in[13];
  float* ws = (float*)d_ws;

  double scl[16]; int nsc = 0;
  {
    double m = 12.0 / 20.0;
    double ml = 768.0 * m;
    double si = m;
    while (ml >= 12.0) { scl[nsc++] = si; si *= 0.709; ml *= 0.709; }
  }

  auto cdiv = [](long a, long b) { return (int)((a + b - 1) / b); };

  // per-scale dims + weight-table geometry
  int NH[NSC], PH_[NSC], H2[NSC], H3[NSC], OXB[NSC], TT[NSC], WOFF[NSC];
  float INV[NSC], KSF[NSC];
  {
    int oxb = 0, woff = 0;
    for (int s = 0; s < nsc; ++s) {
      int nh = (int)(768.0 * scl[s] + 1.0);
      NH[s] = nh;
      PH_[s] = ((nh - 2) + 1) / 2;
      H2[s] = PH_[s] - 2;
      H3[s] = H2[s] - 2;
      double inv = 1.0 / (((double)nh) / 768.0);
      INV[s] = (float)inv;
      KSF[s] = (float)(inv > 1.0 ? inv : 1.0);
      TT[s] = (int)(2.0f * KSF[s]) + 2;
      OXB[s] = oxb; oxb += nh;
      WOFF[s] = woff; woff += nh * TT[s];
    }
  }

  // candidate groupings
  static const int GA[11] = {0, 1, 2, 3, 4, 5, 6, 7, 8, 9, 10};
  static const int G1[7] = {0, 5, 6, 7, 8, 9, 10};
  static const int G2[4] = {1, 2, 3, 4};

  struct Layout {
    long HT, IMG, POOL, C2, REG, KEYS, SCR, SEL, BOX, FK, FS, SF, TBL, HD, VD, extent;
    int hdcap, vdcap;
  };

  auto calcLayout = [&](const int* const* gps, const int* gn, int ng,
                        int hdcap, int vdcap, Layout& L) {
    long htA = 0, c3A = 0, imgA = 0, poolA = 0, c2A = 0, cellsA = 0, scrA = 0;
    for (int g = 0; g < ng; ++g) {
      long ht = 0, c3 = 0, im = 0, pl = 0, c2s = 0, ck = 0, sc = 0;
      for (int q = 0; q < gn[g]; ++q) {
        int s = gps[g][q];
        ht += 24L * 768 * NH[s];
        im += 24L * NH[s] * NH[s];
        pl += 80L * PH_[s] * PH_[s];
        c2s += 128L * H2[s] * H2[s];
        c3 += 256L * H3[s] * H3[s];
        long cells = 8L * H3[s] * H3[s];
        ck += cells;
        sc += 512L * ((cells + 2047) / 2048);
      }
      if (ht > htA) htA = ht; if (c3 > c3A) c3A = c3; if (im > imgA) imgA = im;
      if (pl > poolA) poolA = pl; if (c2s > c2A) c2A = c2s;
      if (ck > cellsA) cellsA = ck; if (sc > scrA) scrA = sc;
    }
    long htR = htA > c3A ? htA : c3A;
    auto al = [](long v) { return (v + 15) & ~15L; };
    long off = 0;
    L.HT = off;   off += al(htR);
    L.IMG = off;  off += al(imgA);
    L.POOL = off; off += al(poolA);
    L.C2 = off;   off += al(c2A);
    L.REG = off;  off += al(4 * cellsA);
    L.KEYS = off; off += al(2 * cellsA);
    L.SCR = off;  off += al(2 * scrA + 16384);
    L.SEL = off;  off += al(11264);
    L.BOX = off;  off += al(67584);
    L.FK = off;   off += al(16384);
    L.FS = off;   off += al(2048);
    L.SF = off;   off += al(12288);
    L.TBL = off;  off += al(12288 + 24000);
    L.HD = off;   off += al((long)ng * 5 * hdcap);
    L.VD = off;   off += al((long)ng * 5 * vdcap);
    L.extent = off;
    L.hdcap = hdcap; L.vdcap = vdcap;
  };

  Layout LA, LB;
  {
    const int* gpsA[1] = {GA}; int gnA[1] = {11};
    calcLayout(gpsA, gnA, 1, 8192, 56320, LA);
    const int* gpsB[2] = {G1, G2}; int gnB[2] = {7, 4};
    calcLayout(gpsB, gnB, 2, 2560, 20480, LB);
  }
  bool big = (ws_size >= (size_t)LA.extent * 4);
  const Layout& L = big ? LA : LB;
  const int* GS[2]; int GN[2]; int ngroups;
  if (big) { GS[0] = GA; GN[0] = 11; ngroups = 1; }
  else { GS[0] = G1; GN[0] = 7; GS[1] = G2; GN[1] = 4; ngroups = 2; }

  u64* keys  = (u64*)(ws + L.KEYS);
  u64* scr   = (u64*)(ws + L.SCR);
  u64* selk  = (u64*)(ws + L.SEL);
  u64* fkeys = (u64*)(ws + L.FK);
  u64* fsel  = (u64*)(ws + L.FS);
  float* boxes = ws + L.BOX;
  float* self  = ws + L.SF;
  int*   tX0  = (int*)(ws + L.TBL);
  int*   tCNT = (int*)(ws + L.TBL + 4096);
  float* tWT  = ws + L.TBL + 8192;
  float* tW   = ws + L.TBL + 12288;

  // build resize weight tables (once per launch)
  {
    MkP P; P.ns = nsc;
    for (int s = 0; s < nsc; ++s) {
      P.nw[s] = NH[s]; P.invs[s] = INV[s]; P.ks[s] = KSF[s];
      P.oxB[s] = OXB[s]; P.T[s] = TT[s]; P.wOff[s] = WOFF[s];
    }
    k_mkweights<<<nsc, TPB, 0, stream>>>(tX0, tCNT, tWT, tW, P);
  }

  // per-group geometry
  int imgOff[2][NJMAX], poolOff[2][NJMAX], c2Off[2][NJMAX], c3Off[2][NJMAX],
      htOff[2][NJMAX], kOff[2][NJMAX], cells[2][NJMAX];
  int cumWtot[2], cumRtot[2];
  for (int g = 0; g < ngroups; ++g) {
    long ch = 0, ci = 0, cp = 0, c2 = 0, c3 = 0, ck = 0;
    int cw = 0, cr = 0;
    for (int q = 0; q < GN[g]; ++q) {
      int s = GS[g][q];
      htOff[g][q] = (int)ch;  ch += 24L * 768 * NH[s];
      imgOff[g][q] = (int)ci; ci += 24L * NH[s] * NH[s];
      poolOff[g][q] = (int)cp; cp += 80L * PH_[s] * PH_[s];
      c2Off[g][q] = (int)c2;  c2 += 128L * H2[s] * H2[s];
      c3Off[g][q] = (int)c3;  c3 += 256L * H3[s] * H3[s];
      kOff[g][q] = (int)ck;   cells[g][q] = 8 * H3[s] * H3[s]; ck += cells[g][q];
      cw += 3 * NH[s]; cr += 24 * NH[s];
    }
    cumWtot[g] = cw; cumRtot[g] = cr;
  }

  // build H/V descriptors (geometry-only)
  for (int g = 0; g < ngroups; ++g) {
    DscP P; P.nj = GN[g];
    int cw = 0, cr = 0;
    for (int q = 0; q < GN[g]; ++q) {
      int s = GS[g][q];
      P.N[q] = NH[s]; P.hOff[q] = htOff[g][q]; P.imgOff[q] = imgOff[g][q];
      P.oxB[q] = OXB[s]; P.wOff[q] = WOFF[s];
      P.cumW[q] = cw; cw += 3 * NH[s];
      P.cumR[q] = cr; cr += 24 * NH[s];
    }
    P.cumW[GN[g]] = cw; P.cumR[GN[g]] = cr;
    int* hd = (int*)(ws + L.HD) + (long)g * 5 * L.hdcap;
    int* vd = (int*)(ws + L.VD) + (long)g * 5 * L.vdcap;
    int tot = cw > cr ? cw : cr;
    k_mkdesc<<<cdiv(tot, TPB), TPB, 0, stream>>>(hd, vd, L.hdcap, L.vdcap, P);
  }

  // ---------------- unified job pipeline over groups ----------------
  for (int g = 0; g < ngroups; ++g) {
    const int* gs = GS[g];
    int nj = GN[g];
    int* hd = (int*)(ws + L.HD) + (long)g * 5 * L.hdcap;
    int* vd = (int*)(ws + L.VD) + (long)g * 5 * L.vdcap;
    // H pass (one image read for the whole group)
    {
      dim3 gh(768, 8, 1);
      k_resizeH_d<<<gh, TPB, 0, stream>>>(images, ws + L.HT, tX0, tCNT, tWT, tW,
                                          hd, L.hdcap, cumWtot[g]);
    }
    // V pass: one wave per output row
    k_resizeV_row<<<cdiv(cumRtot[g], 4), TPB, 0, stream>>>(
        ws + L.HT, ws + L.IMG, tX0, tCNT, tWT, tW, vd, L.vdcap, cumRtot[g]);
    // conv1+pool (all 10 co per block)
    {
      C1P P; P.nj = nj; int ct = 0;
      for (int q = 0; q < nj; ++q) {
        int s = gs[q];
        P.nh[q] = NH[s];
        P.imgOff[q] = imgOff[g][q]; P.poolOff[q] = poolOff[g][q];
        int t1x = cdiv(PH_[s], 16);
        P.t1x[q] = t1x;
        P.cumT[q] = ct; ct += t1x * t1x;
      }
      P.cumT[nj] = ct;
      dim3 gg(ct, 1, 8);
      k_conv1pool_job<<<gg, TPB, 0, stream>>>(ws + L.IMG, c1w, c1b, p1, ws + L.POOL, P);
    }
    // conv2 (16 co in 2 groups of 8)
    {
      CvP P; P.nj = nj; int ct = 0;
      for (int q = 0; q < nj; ++q) {
        int s = gs[q];
        P.H[q] = PH_[s];
        P.inOff[q] = poolOff[g][q]; P.outOff[q] = c2Off[g][q];
        int tx = cdiv(H2[s], 64), ty = cdiv(H2[s], 16);
        P.tx[q] = tx;
        P.cumT[q] = ct; ct += tx * ty;
      }
      P.cumT[nj] = ct;
      dim3 gg(ct, 2, 8);
      k_conv3x3c8_job<<<gg, TPB, 0, stream>>>(ws + L.POOL, c2w, c2b, p2, ws + L.C2,
                                              10, 16, P);
    }
    // conv3 (32 co in 4 groups of 8; writes into HT region)
    {
      CvP P; P.nj = nj; int ct = 0;
      for (int q = 0; q < nj; ++q) {
        int s = gs[q];
        P.H[q] = H2[s];
        P.inOff[q] = c2Off[g][q]; P.outOff[q] = c3Off[g][q];
        int tx = cdiv(H3[s], 64), ty = cdiv(H3[s], 16);
        P.tx[q] = tx;
        P.cumT[q] = ct; ct += tx * ty;
      }
      P.cumT[nj] = ct;
      dim3 gg(ct, 4, 8);
      k_conv3x3c8_job<<<gg, TPB, 0, stream>>>(ws + L.C2, c3w, c3b, p3, ws + L.HT,
                                              16, 32, P);
    }
    // heads
    {
      HdP P; P.nj = nj; int cc = 0;
      for (int q = 0; q < nj; ++q) {
        int s = gs[q];
        P.h3[q] = H3[s];
        P.c3Off[q] = c3Off[g][q]; P.kOff[q] = kOff[g][q];
        P.cumC[q] = cc; cc += cells[g][q];
      }
      P.cumC[nj] = cc;
      k_head_job<<<cdiv(cc, TPB), TPB, 0, stream>>>(ws + L.HT, w41, b41, w42, b42,
                                                    ws + L.REG, keys, P);
    }
    // batched top-512 tournament
    {
      int bOff[NJMAX];
      {
        int c = 0;
        for (int q = 0; q < nj; ++q) { bOff[q] = c; c += 512 * cdiv(cells[g][q], 2048); }
      }
      long nCur[NJMAX]; int par[NJMAX];
      for (int q = 0; q < nj; ++q) { nCur[q] = cells[g][q]; par[q] = 0; }
      while (true) {
        TkP P; P.nj = 0; int cum = 0; int act[NJMAX];
        for (int q = 0; q < nj; ++q) {
          if (nCur[q] > 2048) {
            int r = P.nj++;
            act[r] = q;
            int blocks = cdiv(nCur[q], 2048);
            P.srcSel[r] = par[q];
            P.srcOff[r] = par[q] ? bOff[q] : kOff[g][q];
            P.dstOff[r] = par[q] ? kOff[g][q] : bOff[q];
            P.n[r] = (int)nCur[q];
            P.cumB[r] = cum; cum += blocks;
          }
        }
        P.cumB[P.nj] = cum;
        if (P.nj == 0) break;
        k_topk_job<<<cum, TPB, 0, stream>>>(keys, scr, P);
        for (int r = 0; r < P.nj; ++r) {
          int q = act[r];
          nCur[q] = 512L * cdiv(nCur[q], 2048);
          par[q] ^= 1;
        }
      }
      TkFP F; F.nj = nj;
      for (int q = 0; q < nj; ++q) {
        F.srcSel[q] = par[q];
        F.srcOff[q] = par[q] ? bOff[q] : kOff[g][q];
        F.n[q] = (int)nCur[q];
        F.sIdx[q] = gs[q];
      }
      k_topk_fin<<<nj, TPB, 0, stream>>>(keys, scr, selk, F);
    }
    // gather
    {
      GtP P; P.nj = nj;
      for (int q = 0; q < nj; ++q) {
        int s = gs[q];
        P.h3[q] = H3[s]; P.scalef[q] = (float)scl[s]; P.kOff[q] = kOff[g][q];
        P.sIdx[q] = s;
      }
      k_gather_job<<<2 * nj, TPB, 0, stream>>>(selk, ws + L.REG, boxes, P);
    }
  }

  // ---------------- per-scale NMS + final stage ----------------
  k_nms<<<nsc, TPB, 0, stream>>>(boxes, 512, 0.5f);

  int total = nsc * 512;
  k_finalkeys<<<cdiv(8192, TPB), TPB, 0, stream>>>(boxes, fkeys, total, 8192);
  k_topk<<<4, TPB, 0, stream>>>(fkeys, 8192, scr, 1024);
  k_topk<<<2, TPB, 0, stream>>>(scr, 4096, keys, 1024);
  k_topk<<<1, TPB, 0, stream>>>(keys, 2048, fsel, 1024);
  k_gatherfinal<<<4, TPB, 0, stream>>>(fsel, boxes, self);
  k_nms<<<1, TPB, 0, stream>>>(self, 1024, 0.7f);
  k_refine<<<4, TPB, 0, stream>>>(self, (float*)d_out, 1024);
}

// Round 17
// 1114.062 us; speedup vs baseline: 1.1517x; 1.0002x over previous
//
#include <hip/hip_runtime.h>
#include <stdint.h>

typedef unsigned long long u64;
typedef unsigned int u32;

#define TPB 256
#define NJMAX 12
#define NSC 11

__device__ __forceinline__ int findJob(const int* cum, int nj, int v) {
  int j = 0;
  while (j + 1 < nj && v >= cum[j + 1]) ++j;
  return j;
}

// ---------------- resize weight tables (per scale, per output position) -----
// tW layout: TRANSPOSED [k][ox]: tW[wOff + k*nh + ox]  (coalesced lane reads)
struct MkP { int ns; int nw[NSC]; float invs[NSC], ks[NSC];
             int oxB[NSC], T[NSC], wOff[NSC]; };

__global__ void k_mkweights(int* __restrict__ tX0, int* __restrict__ tCNT,
                            float* __restrict__ tWT, float* __restrict__ tW, MkP P) {
  const int s = blockIdx.x;
  const int nw = P.nw[s];
  const float invs = P.invs[s], ks = P.ks[s];
  const int T = P.T[s];
  for (int ox = threadIdx.x; ox < nw; ox += TPB) {
    float sx = ((float)ox + 0.5f) * invs - 0.5f;
    int x0 = (int)ceilf(sx - ks); if (x0 < 0) x0 = 0;
    int x1 = (int)floorf(sx + ks); if (x1 > 767) x1 = 767;
    float wt = 0.f;
    float* wv = tW + P.wOff[s];
    for (int j = x0; j <= x1; ++j) {
      float w = fmaxf(0.f, 1.f - fabsf(sx - (float)j) / ks);
      wt += w;
      wv[(j - x0) * nw + ox] = w;
    }
    for (int k = x1 - x0 + 1; k < T; ++k) wv[k * nw + ox] = 0.f;
    int g = P.oxB[s] + ox;
    tX0[g] = x0; tCNT[g] = x1 - x0 + 1; tWT[g] = wt;
  }
}

// ---------------- descriptor builder (geometry-only, once per group) --------
struct DscP { int nj; int N[NJMAX]; int hOff[NJMAX], imgOff[NJMAX];
              int oxB[NJMAX], wOff[NJMAX];
              int cumW[NJMAX + 1], cumR[NJMAX + 1]; };

__global__ void k_mkdesc(int* __restrict__ hd, int* __restrict__ vd,
                         int hdcap, int vdcap, DscP P) {
  int gid = blockIdx.x * TPB + threadIdx.x;
  int totW = P.cumW[P.nj], totR = P.cumR[P.nj];
  if (gid < totW) {
    int j = findJob(P.cumW, P.nj, gid);
    int local = gid - P.cumW[j];
    int N = P.N[j];
    int ox = local % N, c = local / N;
    hd[gid]             = P.hOff[j] + c * 768 * N + ox;   // A
    hd[hdcap + gid]     = c * 769;                        // R (LDS row base)
    hd[2 * hdcap + gid] = N;                              // stride
    hd[3 * hdcap + gid] = P.oxB[j] + ox;                  // g
    hd[4 * hdcap + gid] = P.wOff[j] + ox;                 // W
  }
  if (gid < totR) {
    int j = findJob(P.cumR, P.nj, gid);
    int local = gid - P.cumR[j];
    int N = P.N[j];
    int oy = local % N, q = local / N;   // q = b*3+c in 0..23
    vd[gid]             = P.hOff[j] + q * 768 * N;        // S (src col base)
    vd[vdcap + gid]     = P.imgOff[j] + (q * N + oy) * N; // O (out row base)
    vd[2 * vdcap + gid] = P.oxB[j] + oy;                  // g
    vd[3 * vdcap + gid] = P.wOff[j] + oy;                 // W
    vd[4 * vdcap + gid] = N;                              // stride
  }
}

// ---------------- H pass: descriptor-driven, row-resident -------------------
__global__ void k_resizeH_d(const float* __restrict__ img, float* __restrict__ base,
                            const int* __restrict__ tX0, const int* __restrict__ tCNT,
                            const float* __restrict__ tWT, const float* __restrict__ tW,
                            const int* __restrict__ hd, int hdcap, int total) {
  __shared__ float row[3][769];
  const int y = blockIdx.x, b = blockIdx.y;
  const float* src = img + ((long)b * 768 + y) * 768 * 3;
  for (int t = threadIdx.x; t < 2304; t += TPB) {
    int x = t / 3, c = t - 3 * x;
    row[c][x] = src[t];
  }
  __syncthreads();
  const float* rowF = &row[0][0];
  const long yb = (long)y + 2304L * b;
  for (int t = threadIdx.x; t < total; t += TPB) {
    int A = hd[t];
    int R = hd[hdcap + t];
    int N = hd[2 * hdcap + t];
    int g = hd[3 * hdcap + t];
    int W = hd[4 * hdcap + t];
    int x0 = tX0[g], cnt = tCNT[g];
    float wt = tWT[g];
    const float* wv = tW + W;
    const float* rp = rowF + R + x0;
    float acc = 0.f;
    int k = 0;
    for (; k + 3 < cnt; k += 4) {
      float v0 = rp[k],     w0 = wv[(long)k * N];
      float v1 = rp[k + 1], w1 = wv[(long)(k + 1) * N];
      float v2 = rp[k + 2], w2 = wv[(long)(k + 2) * N];
      float v3 = rp[k + 3], w3 = wv[(long)(k + 3) * N];
      acc += v0 * w0; acc += v1 * w1; acc += v2 * w2; acc += v3 * w3;
    }
    for (; k < cnt; ++k) acc += rp[k] * wv[(long)k * N];
    base[(long)A + (long)N * yb] = acc / wt;
  }
}

// ---------------- V pass: one 64-lane wave per output row -------------------
__global__ void k_resizeV_row(const float* __restrict__ basep, float* __restrict__ img,
                              const int* __restrict__ tX0, const int* __restrict__ tCNT,
                              const float* __restrict__ tWT, const float* __restrict__ tW,
                              const int* __restrict__ vd, int vdcap, int nRows) {
  int row = blockIdx.x * 4 + (threadIdx.x >> 6);
  if (row >= nRows) return;
  int lane = threadIdx.x & 63;
  int S = vd[row];
  int O = vd[vdcap + row];
  int g = vd[2 * vdcap + row];
  int W = vd[3 * vdcap + row];
  int N = vd[4 * vdcap + row];
  int y0 = tX0[g], cnt = tCNT[g];
  float wt = tWT[g];
  const float* wv = tW + W;
  const float* col0 = basep + S + (long)y0 * N;
  for (int ox = lane; ox < N; ox += 64) {
    const float* col = col0 + ox;
    float acc = 0.f;
    int k = 0;
    for (; k + 3 < cnt; k += 4) {
      float v0 = col[(long)k * N],       w0 = wv[(long)k * N];
      float v1 = col[(long)(k + 1) * N], w1 = wv[(long)(k + 1) * N];
      float v2 = col[(long)(k + 2) * N], w2 = wv[(long)(k + 2) * N];
      float v3 = col[(long)(k + 3) * N], w3 = wv[(long)(k + 3) * N];
      acc += v0 * w0; acc += v1 * w1; acc += v2 * w2; acc += v3 * w3;
    }
    for (; k < cnt; ++k) acc += col[(long)k * N] * wv[(long)k * N];
    img[(long)O + ox] = (acc / wt - 127.5f) * 0.0078125f;
  }
}

// ---------------- fused conv1 + PReLU + 2x2 ceil-maxpool (all 10 co) --------
__device__ __forceinline__ void conv1pool_body(
    const float* in, const float* w, const float* bias, const float* pr,
    float* out, int H, int W, int b, int px, int py) {
  const int h1 = H - 2, w1 = W - 2;
  const int PH = (h1 + 1) >> 1, PW = (w1 + 1) >> 1;
  if (px >= PW || py >= PH) return;
  const int x0 = px * 2, y0 = py * 2;
  float a00[10], a01[10], a10[10], a11[10];
#pragma unroll
  for (int co = 0; co < 10; ++co) { a00[co] = 0.f; a01[co] = 0.f; a10[co] = 0.f; a11[co] = 0.f; }
  const long HW = (long)H * W;
  const float* pp = in + ((long)b * 3 * H + y0) * W + x0;
  for (int ci = 0; ci < 3; ++ci, pp += HW) {
    const float* r = pp;
    float r00 = r[0], r01 = r[1], r02 = r[2], r03 = r[3]; r += W;
    float r10 = r[0], r11 = r[1], r12 = r[2], r13 = r[3]; r += W;
    float r20 = r[0], r21 = r[1], r22 = r[2], r23 = r[3]; r += W;
    float r30 = r[0], r31 = r[1], r32 = r[2], r33 = r[3];
#pragma unroll
    for (int co = 0; co < 10; ++co) {
      const float* wc = w + ((long)co * 3 + ci) * 9;
      float w0 = wc[0], w1_ = wc[1], w2 = wc[2];
      float w3 = wc[3], w4 = wc[4], w5 = wc[5];
      float w6 = wc[6], w7 = wc[7], w8 = wc[8];
      a00[co] += r00 * w0 + r01 * w1_ + r02 * w2;
      a00[co] += r10 * w3 + r11 * w4 + r12 * w5;
      a00[co] += r20 * w6 + r21 * w7 + r22 * w8;
      a01[co] += r01 * w0 + r02 * w1_ + r03 * w2;
      a01[co] += r11 * w3 + r12 * w4 + r13 * w5;
      a01[co] += r21 * w6 + r22 * w7 + r23 * w8;
      a10[co] += r10 * w0 + r11 * w1_ + r12 * w2;
      a10[co] += r20 * w3 + r21 * w4 + r22 * w5;
      a10[co] += r30 * w6 + r31 * w7 + r32 * w8;
      a11[co] += r11 * w0 + r12 * w1_ + r13 * w2;
      a11[co] += r21 * w3 + r22 * w4 + r23 * w5;
      a11[co] += r31 * w6 + r32 * w7 + r33 * w8;
    }
  }
  const bool vx = (x0 + 1 < w1), vy = (y0 + 1 < h1);
#pragma unroll
  for (int co = 0; co < 10; ++co) {
    const float bb = bias[co], al = pr[co];
    float v = a00[co] + bb; v = v > 0.f ? v : al * v;
    float m = v;
    if (vx) { v = a01[co] + bb; v = v > 0.f ? v : al * v; m = fmaxf(m, v); }
    if (vy) { v = a10[co] + bb; v = v > 0.f ? v : al * v; m = fmaxf(m, v); }
    if (vx && vy) { v = a11[co] + bb; v = v > 0.f ? v : al * v; m = fmaxf(m, v); }
    out[(((long)b * 10 + co) * PH + py) * PW + px] = m;
  }
}

struct C1P { int nj; int nh[NJMAX]; int imgOff[NJMAX], poolOff[NJMAX];
             int t1x[NJMAX]; int cumT[NJMAX + 1]; };

__global__ void k_conv1pool_job(const float* __restrict__ imgb, const float* __restrict__ w,
                                const float* __restrict__ bias, const float* __restrict__ pr,
                                float* __restrict__ poolb, C1P P) {
  int j = findJob(P.cumT, P.nj, blockIdx.x);
  int local = blockIdx.x - P.cumT[j];
  int t1x = P.t1x[j];
  int tX = local % t1x, tY = local / t1x;
  conv1pool_body(imgb + P.imgOff[j], w, bias, pr, poolb + P.poolOff[j],
                 P.nh[j], P.nh[j], blockIdx.z,
                 tX * 16 + (threadIdx.x & 15), tY * 16 + (threadIdx.x >> 4));
}

// ---------------- co-blocked (8) tiled 3x3 conv + PReLU ---------------------
__device__ __forceinline__ void conv3x3c8_body(
    const float* in, const float* w, const float* bias, const float* pr,
    float* out, int Cin, int Cout, int H, int W, int cog, int b, int x0, int y) {
  const int OH = H - 2, OW = W - 2;
  if (y >= OH || x0 >= OW) return;
  float acc[8][4];
#pragma unroll
  for (int k = 0; k < 8; ++k) { acc[k][0] = 0.f; acc[k][1] = 0.f; acc[k][2] = 0.f; acc[k][3] = 0.f; }
  const float* wp = w + (long)cog * Cin * 9;
  const long HW = (long)H * W;
  const float* pp = in + ((long)b * Cin * H + y) * W + x0;
  for (int ci = 0; ci < Cin; ++ci, pp += HW) {
    const float* r = pp;
    float q00 = r[0], q01 = r[1], q02 = r[2], q03 = r[3], q04 = r[4], q05 = r[5]; r += W;
    float q10 = r[0], q11 = r[1], q12 = r[2], q13 = r[3], q14 = r[4], q15 = r[5]; r += W;
    float q20 = r[0], q21 = r[1], q22 = r[2], q23 = r[3], q24 = r[4], q25 = r[5];
#pragma unroll
    for (int k = 0; k < 8; ++k) {
      const float* wc = wp + ((long)k * Cin + ci) * 9;
      float w0 = wc[0], w1 = wc[1], w2 = wc[2];
      float w3 = wc[3], w4 = wc[4], w5 = wc[5];
      float w6 = wc[6], w7 = wc[7], w8 = wc[8];
      acc[k][0] += q00 * w0 + q01 * w1 + q02 * w2;
      acc[k][1] += q01 * w0 + q02 * w1 + q03 * w2;
      acc[k][2] += q02 * w0 + q03 * w1 + q04 * w2;
      acc[k][3] += q03 * w0 + q04 * w1 + q05 * w2;
      acc[k][0] += q10 * w3 + q11 * w4 + q12 * w5;
      acc[k][1] += q11 * w3 + q12 * w4 + q13 * w5;
      acc[k][2] += q12 * w3 + q13 * w4 + q14 * w5;
      acc[k][3] += q13 * w3 + q14 * w4 + q15 * w5;
      acc[k][0] += q20 * w6 + q21 * w7 + q22 * w8;
      acc[k][1] += q21 * w6 + q22 * w7 + q23 * w8;
      acc[k][2] += q22 * w6 + q23 * w7 + q24 * w8;
      acc[k][3] += q23 * w6 + q24 * w7 + q25 * w8;
    }
  }
  const int rem = OW - x0;
#pragma unroll
  for (int k = 0; k < 8; ++k) {
    const int co = cog + k;
    const float bb = bias[co], al = pr[co];
    float* op = out + (((long)b * Cout + co) * OH + y) * OW + x0;
    float v0 = acc[k][0] + bb; v0 = v0 > 0.f ? v0 : al * v0;
    op[0] = v0;
    if (rem > 1) { float v = acc[k][1] + bb; v = v > 0.f ? v : al * v; op[1] = v; }
    if (rem > 2) { float v = acc[k][2] + bb; v = v > 0.f ? v : al * v; op[2] = v; }
    if (rem > 3) { float v = acc[k][3] + bb; v = v > 0.f ? v : al * v; op[3] = v; }
  }
}

struct CvP { int nj; int H[NJMAX]; int inOff[NJMAX], outOff[NJMAX];
             int tx[NJMAX]; int cumT[NJMAX + 1]; };

__global__ void k_conv3x3c8_job(const float* __restrict__ inb, const float* __restrict__ w,
                                const float* __restrict__ bias, const float* __restrict__ pr,
                                float* __restrict__ outb, int Cin, int Cout, CvP P) {
  int j = findJob(P.cumT, P.nj, blockIdx.x);
  int local = blockIdx.x - P.cumT[j];
  int tx0 = P.tx[j];
  int tX = local % tx0, tY = local / tx0;
  conv3x3c8_body(inb + P.inOff[j], w, bias, pr, outb + P.outOff[j], Cin, Cout,
                 P.H[j], P.H[j], blockIdx.y * 8, blockIdx.z,
                 tX * 64 + (threadIdx.x & 15) * 4, tY * 16 + (threadIdx.x >> 4));
}

// ---------------- 1x1 heads -------------------------------------------------
__device__ __forceinline__ void head_body(const float* x3, const float* w41,
                                          const float* b41, const float* w42,
                                          const float* b42, float* reg, u64* keys,
                                          int plane, long idx) {
  int b = (int)(idx / plane); int rem = (int)(idx % plane);
  const float* p = x3 + (long)b * 32 * plane + rem;
  float l0 = 0.f, l1 = 0.f, r0 = 0.f, r1 = 0.f, r2 = 0.f, r3 = 0.f;
  for (int c = 0; c < 32; ++c) {
    float v = p[(long)c * plane];
    l0 += v * w41[c];      l1 += v * w41[32 + c];
    r0 += v * w42[c];      r1 += v * w42[32 + c];
    r2 += v * w42[64 + c]; r3 += v * w42[96 + c];
  }
  l0 += b41[0]; l1 += b41[1];
  r0 += b42[0]; r1 += b42[1]; r2 += b42[2]; r3 += b42[3];
  float mx = fmaxf(l0, l1);
  float e0 = expf(l0 - mx), e1 = expf(l1 - mx);
  float s = e1 / (e0 + e1);
  reg[idx * 4 + 0] = r0; reg[idx * 4 + 1] = r1;
  reg[idx * 4 + 2] = r2; reg[idx * 4 + 3] = r3;
  u32 ic = 0xFFFFFFFFu - (u32)idx;
  u64 k = (s >= 0.6f) ? ((((u64)__float_as_uint(s)) << 32) | ic) : (u64)ic;
  keys[idx] = k;
}

struct HdP { int nj; int h3[NJMAX]; int c3Off[NJMAX], kOff[NJMAX];
             int cumC[NJMAX + 1]; };

__global__ void k_head_job(const float* __restrict__ c3b, const float* __restrict__ w41,
                           const float* __restrict__ b41, const float* __restrict__ w42,
                           const float* __restrict__ b42, float* __restrict__ regb,
                           u64* __restrict__ keysb, HdP P) {
  int gid = blockIdx.x * TPB + threadIdx.x;
  if (gid >= P.cumC[P.nj]) return;
  int j = findJob(P.cumC, P.nj, gid);
  int idx = gid - P.cumC[j];
  head_body(c3b + P.c3Off[j], w41, b41, w42, b42,
            regb + 4L * P.kOff[j], keysb + P.kOff[j], P.h3[j] * P.h3[j], idx);
}

// ---------------- bitonic top-K ---------------------------------------------
__device__ __forceinline__ void bitonic2048(u64* s) {
  for (int k = 2; k <= 2048; k <<= 1) {
    for (int j = k >> 1; j > 0; j >>= 1) {
      for (int i = threadIdx.x; i < 2048; i += TPB) {
        int ixj = i ^ j;
        if (ixj > i) {
          u64 a = s[i], b = s[ixj];
          bool desc = ((i & k) == 0);
          if (desc ? (a < b) : (a > b)) { s[i] = b; s[ixj] = a; }
        }
      }
      __syncthreads();
    }
  }
}

__global__ void k_topk(const u64* __restrict__ in, int n, u64* __restrict__ out, int K) {
  __shared__ u64 s[2048];
  int base = blockIdx.x * 2048;
  for (int t = threadIdx.x; t < 2048; t += TPB) {
    int gi = base + t;
    s[t] = (gi < n) ? in[gi] : 0ULL;
  }
  __syncthreads();
  bitonic2048(s);
  for (int t = threadIdx.x; t < K; t += TPB)
    out[(long)blockIdx.x * K + t] = s[t];
}

struct TkP { int nj; int srcSel[NJMAX]; int srcOff[NJMAX]; int n[NJMAX];
             int dstOff[NJMAX]; int cumB[NJMAX + 1]; };

__global__ void k_topk_job(u64* __restrict__ A, u64* __restrict__ B, TkP P) {
  __shared__ u64 s[2048];
  int j = findJob(P.cumB, P.nj, blockIdx.x);
  int lb = blockIdx.x - P.cumB[j];
  const u64* src = (P.srcSel[j] ? B : A) + P.srcOff[j];
  u64* dst = (P.srcSel[j] ? A : B) + P.dstOff[j];
  int n = P.n[j];
  int base = lb * 2048;
  for (int t = threadIdx.x; t < 2048; t += TPB) {
    int gi = base + t;
    s[t] = (gi < n) ? src[gi] : 0ULL;
  }
  __syncthreads();
  bitonic2048(s);
  for (int t = threadIdx.x; t < 512; t += TPB)
    dst[(long)lb * 512 + t] = s[t];
}

struct TkFP { int nj; int srcSel[NJMAX]; int srcOff[NJMAX]; int n[NJMAX]; int sIdx[NJMAX]; };

__global__ void k_topk_fin(const u64* __restrict__ A, const u64* __restrict__ B,
                           u64* __restrict__ selk, TkFP P) {
  __shared__ u64 s[2048];
  int j = blockIdx.x;
  const u64* src = (P.srcSel[j] ? B : A) + P.srcOff[j];
  int n = P.n[j];
  for (int t = threadIdx.x; t < 2048; t += TPB)
    s[t] = (t < n) ? src[t] : 0ULL;
  __syncthreads();
  bitonic2048(s);
  for (int t = threadIdx.x; t < 512; t += TPB)
    selk[(long)P.sIdx[j] * 512 + t] = s[t];
}

// ---------------- gather box rows -------------------------------------------
__device__ __forceinline__ void gather_body(const u64* keys, const float* reg,
                                            float* boxes, int h, int w, float scalef,
                                            int i) {
  float* bx = boxes + (long)i * 12;
  u64 key = keys[i];
  if ((key >> 32) == 0ULL) {
    for (int q = 0; q < 12; ++q) bx[q] = 0.f;
    return;
  }
  u32 cell = 0xFFFFFFFFu - (u32)(key & 0xFFFFFFFFu);
  int x = (int)(cell % (u32)w); u32 t2 = cell / (u32)w;
  int y = (int)(t2 % (u32)h); int b = (int)(t2 / (u32)h);
  float fx = (float)x, fy = (float)y;
  bx[0] = floorf((2.f * fx + 1.f) / scalef);
  bx[1] = floorf((2.f * fy + 1.f) / scalef);
  bx[2] = floorf((2.f * fx + 12.f) / scalef);
  bx[3] = floorf((2.f * fy + 12.f) / scalef);
  bx[4] = __uint_as_float((u32)(key >> 32));
  bx[5] = reg[(long)cell * 4 + 0];
  bx[6] = reg[(long)cell * 4 + 1];
  bx[7] = reg[(long)cell * 4 + 2];
  bx[8] = reg[(long)cell * 4 + 3];
  bx[9] = (float)b;
  bx[10] = 1.f;
  bx[11] = 0.f;
}

struct GtP { int nj; int h3[NJMAX]; float scalef[NJMAX]; int kOff[NJMAX]; int sIdx[NJMAX]; };

__global__ void k_gather_job(const u64* __restrict__ selk, const float* __restrict__ regb,
                             float* __restrict__ boxes, GtP P) {
  int j = blockIdx.x >> 1;
  int i = ((blockIdx.x & 1) << 8) + threadIdx.x;
  gather_body(selk + (long)P.sIdx[j] * 512, regb + 4L * P.kOff[j],
              boxes + (long)P.sIdx[j] * 512 * 12, P.h3[j], P.h3[j], P.scalef[j], i);
}

// ---------------- greedy NMS, 64-wide batched (bit-exact) --------------------
// kp[j] = valid[j] && !exists kept i<j with iou(i,j)>thr  — order-free booleans
// over side-effect-free float comparisons; batch i by 64: phase A = wave-0
// serial greedy inside the batch via shfl, phase B = parallel tail sweep.
__global__ void k_nms(float* __restrict__ boxes, int per, float thr) {
  __shared__ float sx1[1024], sy1[1024], sx2[1024], sy2[1024], sar[1024];
  __shared__ unsigned char kp[1024];
  __shared__ unsigned char kb[64];
  __shared__ int snv;
  float* bs = boxes + (long)blockIdx.x * per * 12;
  int N = per;
  if (threadIdx.x == 0) snv = 0;
  __syncthreads();
  for (int i = threadIdx.x; i < N; i += blockDim.x) {
    const float* b = bs + (long)i * 12;
    float off = b[9] * 100000.0f;
    float a0 = b[0] + off, a1 = b[1] + off, a2 = b[2] + off, a3 = b[3] + off;
    sx1[i] = a0; sy1[i] = a1; sx2[i] = a2; sy2[i] = a3;
    sar[i] = fmaxf(a2 - a0, 0.f) * fmaxf(a3 - a1, 0.f);
    bool v = (b[10] != 0.f);
    kp[i] = v;
    if (v) atomicMax(&snv, i + 1);   // valid entries are a prefix (sorted desc)
  }
  __syncthreads();
  int nv = snv;
  const int wave = threadIdx.x >> 6, lane = threadIdx.x & 63;
  for (int base = 0; base < nv; base += 64) {
    const int lim = (nv - base < 64) ? (nv - base) : 64;
    // phase A: within-batch serial greedy on wave 0
    if (wave == 0) {
      int gi = base + lane;
      bool ok = (lane < lim) && kp[gi];
      float bx1 = 0.f, by1 = 0.f, bx2 = 0.f, by2 = 0.f, ba = 0.f;
      if (lane < lim) { bx1 = sx1[gi]; by1 = sy1[gi]; bx2 = sx2[gi]; by2 = sy2[gi]; ba = sar[gi]; }
      for (int i = 0; i < lim; ++i) {
        int ki = __shfl((int)ok, i);
        float xi1 = __shfl(bx1, i), yi1 = __shfl(by1, i);
        float xi2 = __shfl(bx2, i), yi2 = __shfl(by2, i);
        float ai = __shfl(ba, i);
        if (ki && lane > i && ok) {
          float iw = fmaxf(fminf(xi2, bx2) - fmaxf(xi1, bx1), 0.f);
          float ih = fmaxf(fminf(yi2, by2) - fmaxf(yi1, by1), 0.f);
          float inter = iw * ih;
          float iou = inter / (ai + ba - inter + 1e-9f);
          if (iou > thr) ok = false;
        }
      }
      if (lane < lim) kp[gi] = ok ? 1 : 0;
      kb[lane] = (lane < lim && ok) ? 1 : 0;
    }
    __syncthreads();
    // phase B: apply batch's kept boxes to the tail (j > base+63)
    for (int j = base + 64 + threadIdx.x; j < nv; j += blockDim.x) {
      if (!kp[j]) continue;
      float jx2 = sx2[j], jy2 = sy2[j], jx1 = sx1[j], jy1 = sy1[j], ja = sar[j];
      bool ok = true;
      for (int i = 0; i < lim && ok; ++i) {
        if (!kb[i]) continue;
        int gi = base + i;
        float iw = fmaxf(fminf(sx2[gi], jx2) - fmaxf(sx1[gi], jx1), 0.f);
        float ih = fmaxf(fminf(sy2[gi], jy2) - fmaxf(sy1[gi], jy1), 0.f);
        float inter = iw * ih;
        float iou = inter / (sar[gi] + ja - inter + 1e-9f);
        if (iou > thr) ok = false;
      }
      if (!ok) kp[j] = 0;
    }
    __syncthreads();
  }
  for (int i = threadIdx.x; i < N; i += blockDim.x)
    bs[(long)i * 12 + 11] = kp[i] ? 1.f : 0.f;
}

// ---------------- final stage ------------------------------------------------
__global__ void k_finalkeys(const float* __restrict__ boxes, u64* __restrict__ keys,
                            int total, int padded) {
  int i = blockIdx.x * blockDim.x + threadIdx.x;
  if (i >= padded) return;
  u64 k = 0ULL;
  if (i < total) {
    const float* b = boxes + (long)i * 12;
    u32 ic = 0xFFFFFFFFu - (u32)i;
    k = (b[11] != 0.f) ? ((((u64)__float_as_uint(b[4])) << 32) | ic) : (u64)ic;
  }
  keys[i] = k;
}

__global__ void k_gatherfinal(const u64* __restrict__ keys, const float* __restrict__ boxes,
                              float* __restrict__ sel) {
  int i = blockIdx.x * blockDim.x + threadIdx.x;
  if (i >= 1024) return;
  u64 key = keys[i];
  float* o = sel + (long)i * 12;
  if ((key >> 32) == 0ULL) {
    for (int q = 0; q < 12; ++q) o[q] = 0.f;
    return;
  }
  u32 bi = 0xFFFFFFFFu - (u32)(key & 0xFFFFFFFFu);
  const float* b = boxes + (long)bi * 12;
  for (int q = 0; q < 12; ++q) o[q] = b[q];
  o[10] = 1.f;
  o[11] = 0.f;
}

__global__ void k_refine(const float* __restrict__ sel, float* __restrict__ out, int N) {
  int i = blockIdx.x * blockDim.x + threadIdx.x;
  if (i >= N) return;
  const float* b = sel + (long)i * 12;
  float keep = b[11];
  float x1 = b[0], y1 = b[1], x2 = b[2], y2 = b[3], sc = b[4];
  float rw = x2 - x1, rh = y2 - y1;
  float o0 = x1 + b[5] * rw;
  float o1 = y1 + b[6] * rh;
  float o2 = x2 + b[7] * rw;
  float o3 = y2 + b[8] * rh;
  float hh = o3 - o1, ww = o2 - o0;
  float l = fmaxf(hh, ww);
  float nx1 = o0 + ww * 0.5f - l * 0.5f;
  float ny1 = o1 + hh * 0.5f - l * 0.5f;
  out[(long)i * 5 + 0] = nx1 * keep;
  out[(long)i * 5 + 1] = ny1 * keep;
  out[(long)i * 5 + 2] = (nx1 + l) * keep;
  out[(long)i * 5 + 3] = (ny1 + l) * keep;
  out[(long)i * 5 + 4] = sc * keep;
}

extern "C" void kernel_launch(void* const* d_in, const int* in_sizes, int n_in,
                              void* d_out, int out_size, void* d_ws, size_t ws_size,
                              hipStream_t stream) {
  (void)in_sizes; (void)n_in; (void)out_size;
  const float* images = (const float*)d_in[0];
  const float* c1w = (const float*)d_in[1];
  const float* c1b = (const float*)d_in[2];
  const float* p1  = (const float*)d_in[3];
  const float* c2w = (const float*)d_in[4];
  const float* c2b = (const float*)d_in[5];
  const float* p2  = (const float*)d_in[6];
  const float* c3w = (const float*)d_in[7];
  const float* c3b = (const float*)d_in[8];
  const float* p3  = (const float*)d_in[9];
  const float* w41 = (const float*)d_in[10];
  const float* b41 = (const float*)d_in[11];
  const float* w42 = (const float*)d_in[12];
  const float* b42 = (const float*)d_in[13];
  float* ws = (float*)d_ws;

  double scl[16]; int nsc = 0;
  {
    double m = 12.0 / 20.0;
    double ml = 768.0 * m;
    double si = m;
    while (ml >= 12.0) { scl[nsc++] = si; si *= 0.709; ml *= 0.709; }
  }

  auto cdiv = [](long a, long b) { return (int)((a + b - 1) / b); };

  // per-scale dims + weight-table geometry
  int NH[NSC], PH_[NSC], H2[NSC], H3[NSC], OXB[NSC], TT[NSC], WOFF[NSC];
  float INV[NSC], KSF[NSC];
  {
    int oxb = 0, woff = 0;
    for (int s = 0; s < nsc; ++s) {
      int nh = (int)(768.0 * scl[s] + 1.0);
      NH[s] = nh;
      PH_[s] = ((nh - 2) + 1) / 2;
      H2[s] = PH_[s] - 2;
      H3[s] = H2[s] - 2;
      double inv = 1.0 / (((double)nh) / 768.0);
      INV[s] = (float)inv;
      KSF[s] = (float)(inv > 1.0 ? inv : 1.0);
      TT[s] = (int)(2.0f * KSF[s]) + 2;
      OXB[s] = oxb; oxb += nh;
      WOFF[s] = woff; woff += nh * TT[s];
    }
  }

  // candidate groupings
  static const int GA[11] = {0, 1, 2, 3, 4, 5, 6, 7, 8, 9, 10};
  static const int G1[7] = {0, 5, 6, 7, 8, 9, 10};
  static const int G2[4] = {1, 2, 3, 4};

  struct Layout {
    long HT, IMG, POOL, C2, REG, KEYS, SCR, SEL, BOX, FK, FS, SF, TBL, HD, VD, extent;
    int hdcap, vdcap;
  };

  auto calcLayout = [&](const int* const* gps, const int* gn, int ng,
                        int hdcap, int vdcap, Layout& L) {
    long htA = 0, c3A = 0, imgA = 0, poolA = 0, c2A = 0, cellsA = 0, scrA = 0;
    for (int g = 0; g < ng; ++g) {
      long ht = 0, c3 = 0, im = 0, pl = 0, c2s = 0, ck = 0, sc = 0;
      for (int q = 0; q < gn[g]; ++q) {
        int s = gps[g][q];
        ht += 24L * 768 * NH[s];
        im += 24L * NH[s] * NH[s];
        pl += 80L * PH_[s] * PH_[s];
        c2s += 128L * H2[s] * H2[s];
        c3 += 256L * H3[s] * H3[s];
        long cells = 8L * H3[s] * H3[s];
        ck += cells;
        sc += 512L * ((cells + 2047) / 2048);
      }
      if (ht > htA) htA = ht; if (c3 > c3A) c3A = c3; if (im > imgA) imgA = im;
      if (pl > poolA) poolA = pl; if (c2s > c2A) c2A = c2s;
      if (ck > cellsA) cellsA = ck; if (sc > scrA) scrA = sc;
    }
    long htR = htA > c3A ? htA : c3A;
    auto al = [](long v) { return (v + 15) & ~15L; };
    long off = 0;
    L.HT = off;   off += al(htR);
    L.IMG = off;  off += al(imgA);
    L.POOL = off; off += al(poolA);
    L.C2 = off;   off += al(c2A);
    L.REG = off;  off += al(4 * cellsA);
    L.KEYS = off; off += al(2 * cellsA);
    L.SCR = off;  off += al(2 * scrA + 16384);
    L.SEL = off;  off += al(11264);
    L.BOX = off;  off += al(67584);
    L.FK = off;   off += al(16384);
    L.FS = off;   off += al(2048);
    L.SF = off;   off += al(12288);
    L.TBL = off;  off += al(12288 + 24000);
    L.HD = off;   off += al((long)ng * 5 * hdcap);
    L.VD = off;   off += al((long)ng * 5 * vdcap);
    L.extent = off;
    L.hdcap = hdcap; L.vdcap = vdcap;
  };

  Layout LA, LB;
  {
    const int* gpsA[1] = {GA}; int gnA[1] = {11};
    calcLayout(gpsA, gnA, 1, 8192, 56320, LA);
    const int* gpsB[2] = {G1, G2}; int gnB[2] = {7, 4};
    calcLayout(gpsB, gnB, 2, 2560, 20480, LB);
  }
  bool big = (ws_size >= (size_t)LA.extent * 4);
  const Layout& L = big ? LA : LB;
  const int* GS[2]; int GN[2]; int ngroups;
  if (big) { GS[0] = GA; GN[0] = 11; ngroups = 1; }
  else { GS[0] = G1; GN[0] = 7; GS[1] = G2; GN[1] = 4; ngroups = 2; }

  u64* keys  = (u64*)(ws + L.KEYS);
  u64* scr   = (u64*)(ws + L.SCR);
  u64* selk  = (u64*)(ws + L.SEL);
  u64* fkeys = (u64*)(ws + L.FK);
  u64* fsel  = (u64*)(ws + L.FS);
  float* boxes = ws + L.BOX;
  float* self  = ws + L.SF;
  int*   tX0  = (int*)(ws + L.TBL);
  int*   tCNT = (int*)(ws + L.TBL + 4096);
  float* tWT  = ws + L.TBL + 8192;
  float* tW   = ws + L.TBL + 12288;

  // build resize weight tables (once per launch)
  {
    MkP P; P.ns = nsc;
    for (int s = 0; s < nsc; ++s) {
      P.nw[s] = NH[s]; P.invs[s] = INV[s]; P.ks[s] = KSF[s];
      P.oxB[s] = OXB[s]; P.T[s] = TT[s]; P.wOff[s] = WOFF[s];
    }
    k_mkweights<<<nsc, TPB, 0, stream>>>(tX0, tCNT, tWT, tW, P);
  }

  // per-group geometry
  int imgOff[2][NJMAX], poolOff[2][NJMAX], c2Off[2][NJMAX], c3Off[2][NJMAX],
      htOff[2][NJMAX], kOff[2][NJMAX], cells[2][NJMAX];
  int cumWtot[2], cumRtot[2];
  for (int g = 0; g < ngroups; ++g) {
    long ch = 0, ci = 0, cp = 0, c2 = 0, c3 = 0, ck = 0;
    int cw = 0, cr = 0;
    for (int q = 0; q < GN[g]; ++q) {
      int s = GS[g][q];
      htOff[g][q] = (int)ch;  ch += 24L * 768 * NH[s];
      imgOff[g][q] = (int)ci; ci += 24L * NH[s] * NH[s];
      poolOff[g][q] = (int)cp; cp += 80L * PH_[s] * PH_[s];
      c2Off[g][q] = (int)c2;  c2 += 128L * H2[s] * H2[s];
      c3Off[g][q] = (int)c3;  c3 += 256L * H3[s] * H3[s];
      kOff[g][q] = (int)ck;   cells[g][q] = 8 * H3[s] * H3[s]; ck += cells[g][q];
      cw += 3 * NH[s]; cr += 24 * NH[s];
    }
    cumWtot[g] = cw; cumRtot[g] = cr;
  }

  // build H/V descriptors (geometry-only)
  for (int g = 0; g < ngroups; ++g) {
    DscP P; P.nj = GN[g];
    int cw = 0, cr = 0;
    for (int q = 0; q < GN[g]; ++q) {
      int s = GS[g][q];
      P.N[q] = NH[s]; P.hOff[q] = htOff[g][q]; P.imgOff[q] = imgOff[g][q];
      P.oxB[q] = OXB[s]; P.wOff[q] = WOFF[s];
      P.cumW[q] = cw; cw += 3 * NH[s];
      P.cumR[q] = cr; cr += 24 * NH[s];
    }
    P.cumW[GN[g]] = cw; P.cumR[GN[g]] = cr;
    int* hd = (int*)(ws + L.HD) + (long)g * 5 * L.hdcap;
    int* vd = (int*)(ws + L.VD) + (long)g * 5 * L.vdcap;
    int tot = cw > cr ? cw : cr;
    k_mkdesc<<<cdiv(tot, TPB), TPB, 0, stream>>>(hd, vd, L.hdcap, L.vdcap, P);
  }

  // ---------------- unified job pipeline over groups ----------------
  for (int g = 0; g < ngroups; ++g) {
    const int* gs = GS[g];
    int nj = GN[g];
    int* hd = (int*)(ws + L.HD) + (long)g * 5 * L.hdcap;
    int* vd = (int*)(ws + L.VD) + (long)g * 5 * L.vdcap;
    // H pass (one image read for the whole group)
    {
      dim3 gh(768, 8, 1);
      k_resizeH_d<<<gh, TPB, 0, stream>>>(images, ws + L.HT, tX0, tCNT, tWT, tW,
                                          hd, L.hdcap, cumWtot[g]);
    }
    // V pass: one wave per output row
    k_resizeV_row<<<cdiv(cumRtot[g], 4), TPB, 0, stream>>>(
        ws + L.HT, ws + L.IMG, tX0, tCNT, tWT, tW, vd, L.vdcap, cumRtot[g]);
    // conv1+pool (all 10 co per block)
    {
      C1P P; P.nj = nj; int ct = 0;
      for (int q = 0; q < nj; ++q) {
        int s = gs[q];
        P.nh[q] = NH[s];
        P.imgOff[q] = imgOff[g][q]; P.poolOff[q] = poolOff[g][q];
        int t1x = cdiv(PH_[s], 16);
        P.t1x[q] = t1x;
        P.cumT[q] = ct; ct += t1x * t1x;
      }
      P.cumT[nj] = ct;
      dim3 gg(ct, 1, 8);
      k_conv1pool_job<<<gg, TPB, 0, stream>>>(ws + L.IMG, c1w, c1b, p1, ws + L.POOL, P);
    }
    // conv2 (16 co in 2 groups of 8)
    {
      CvP P; P.nj = nj; int ct = 0;
      for (int q = 0; q < nj; ++q) {
        int s = gs[q];
        P.H[q] = PH_[s];
        P.inOff[q] = poolOff[g][q]; P.outOff[q] = c2Off[g][q];
        int tx = cdiv(H2[s], 64), ty = cdiv(H2[s], 16);
        P.tx[q] = tx;
        P.cumT[q] = ct; ct += tx * ty;
      }
      P.cumT[nj] = ct;
      dim3 gg(ct, 2, 8);
      k_conv3x3c8_job<<<gg, TPB, 0, stream>>>(ws + L.POOL, c2w, c2b, p2, ws + L.C2,
                                              10, 16, P);
    }
    // conv3 (32 co in 4 groups of 8; writes into HT region)
    {
      CvP P; P.nj = nj; int ct = 0;
      for (int q = 0; q < nj; ++q) {
        int s = gs[q];
        P.H[q] = H2[s];
        P.inOff[q] = c2Off[g][q]; P.outOff[q] = c3Off[g][q];
        int tx = cdiv(H3[s], 64), ty = cdiv(H3[s], 16);
        P.tx[q] = tx;
        P.cumT[q] = ct; ct += tx * ty;
      }
      P.cumT[nj] = ct;
      dim3 gg(ct, 4, 8);
      k_conv3x3c8_job<<<gg, TPB, 0, stream>>>(ws + L.C2, c3w, c3b, p3, ws + L.HT,
                                              16, 32, P);
    }
    // heads
    {
      HdP P; P.nj = nj; int cc = 0;
      for (int q = 0; q < nj; ++q) {
        int s = gs[q];
        P.h3[q] = H3[s];
        P.c3Off[q] = c3Off[g][q]; P.kOff[q] = kOff[g][q];
        P.cumC[q] = cc; cc += cells[g][q];
      }
      P.cumC[nj] = cc;
      k_head_job<<<cdiv(cc, TPB), TPB, 0, stream>>>(ws + L.HT, w41, b41, w42, b42,
                                                    ws + L.REG, keys, P);
    }
    // batched top-512 tournament
    {
      int bOff[NJMAX];
      {
        int c = 0;
        for (int q = 0; q < nj; ++q) { bOff[q] = c; c += 512 * cdiv(cells[g][q], 2048); }
      }
      long nCur[NJMAX]; int par[NJMAX];
      for (int q = 0; q < nj; ++q) { nCur[q] = cells[g][q]; par[q] = 0; }
      while (true) {
        TkP P; P.nj = 0; int cum = 0; int act[NJMAX];
        for (int q = 0; q < nj; ++q) {
          if (nCur[q] > 2048) {
            int r = P.nj++;
            act[r] = q;
            int blocks = cdiv(nCur[q], 2048);
            P.srcSel[r] = par[q];
            P.srcOff[r] = par[q] ? bOff[q] : kOff[g][q];
            P.dstOff[r] = par[q] ? kOff[g][q] : bOff[q];
            P.n[r] = (int)nCur[q];
            P.cumB[r] = cum; cum += blocks;
          }
        }
        P.cumB[P.nj] = cum;
        if (P.nj == 0) break;
        k_topk_job<<<cum, TPB, 0, stream>>>(keys, scr, P);
        for (int r = 0; r < P.nj; ++r) {
          int q = act[r];
          nCur[q] = 512L * cdiv(nCur[q], 2048);
          par[q] ^= 1;
        }
      }
      TkFP F; F.nj = nj;
      for (int q = 0; q < nj; ++q) {
        F.srcSel[q] = par[q];
        F.srcOff[q] = par[q] ? bOff[q] : kOff[g][q];
        F.n[q] = (int)nCur[q];
        F.sIdx[q] = gs[q];
      }
      k_topk_fin<<<nj, TPB, 0, stream>>>(keys, scr, selk, F);
    }
    // gather
    {
      GtP P; P.nj = nj;
      for (int q = 0; q < nj; ++q) {
        int s = gs[q];
        P.h3[q] = H3[s]; P.scalef[q] = (float)scl[s]; P.kOff[q] = kOff[g][q];
        P.sIdx[q] = s;
      }
      k_gather_job<<<2 * nj, TPB, 0, stream>>>(selk, ws + L.REG, boxes, P);
    }
  }

  // ---------------- per-scale NMS + final stage ----------------
  k_nms<<<nsc, TPB, 0, stream>>>(boxes, 512, 0.5f);

  int total = nsc * 512;
  k_finalkeys<<<cdiv(8192, TPB), TPB, 0, stream>>>(boxes, fkeys, total, 8192);
  k_topk<<<4, TPB, 0, stream>>>(fkeys, 8192, scr, 1024);
  k_topk<<<2, TPB, 0, stream>>>(scr, 4096, keys, 1024);
  k_topk<<<1, TPB, 0, stream>>>(keys, 2048, fsel, 1024);
  k_gatherfinal<<<4, TPB, 0, stream>>>(fsel, boxes, self);
  k_nms<<<1, TPB, 0, stream>>>(self, 1024, 0.7f);
  k_refine<<<4, TPB, 0, stream>>>(self, (float*)d_out, 1024);
}

// Round 18
// 1015.678 us; speedup vs baseline: 1.2633x; 1.0969x over previous
//
#include <hip/hip_runtime.h>
#include <stdint.h>

typedef unsigned long long u64;
typedef unsigned int u32;

#define TPB 256
#define NJMAX 12
#define NSC 11

__device__ __forceinline__ int findJob(const int* cum, int nj, int v) {
  int j = 0;
  while (j + 1 < nj && v >= cum[j + 1]) ++j;
  return j;
}

// ---------------- resize weight tables (per scale, per output position) -----
// tW layout: TRANSPOSED [k][ox]: tW[wOff + k*nh + ox]  (coalesced lane reads)
struct MkP { int ns; int nw[NSC]; float invs[NSC], ks[NSC];
             int oxB[NSC], T[NSC], wOff[NSC]; };

__global__ void k_mkweights(int* __restrict__ tX0, int* __restrict__ tCNT,
                            float* __restrict__ tWT, float* __restrict__ tW, MkP P) {
  const int s = blockIdx.x;
  const int nw = P.nw[s];
  const float invs = P.invs[s], ks = P.ks[s];
  const int T = P.T[s];
  for (int ox = threadIdx.x; ox < nw; ox += TPB) {
    float sx = ((float)ox + 0.5f) * invs - 0.5f;
    int x0 = (int)ceilf(sx - ks); if (x0 < 0) x0 = 0;
    int x1 = (int)floorf(sx + ks); if (x1 > 767) x1 = 767;
    float wt = 0.f;
    float* wv = tW + P.wOff[s];
    for (int j = x0; j <= x1; ++j) {
      float w = fmaxf(0.f, 1.f - fabsf(sx - (float)j) / ks);
      wt += w;
      wv[(j - x0) * nw + ox] = w;
    }
    for (int k = x1 - x0 + 1; k < T; ++k) wv[k * nw + ox] = 0.f;
    int g = P.oxB[s] + ox;
    tX0[g] = x0; tCNT[g] = x1 - x0 + 1; tWT[g] = wt;
  }
}

// ---------------- descriptor builder (geometry-only, once per group) --------
struct DscP { int nj; int N[NJMAX]; int hOff[NJMAX], imgOff[NJMAX];
              int oxB[NJMAX], wOff[NJMAX];
              int cumW[NJMAX + 1], cumR[NJMAX + 1]; };

__global__ void k_mkdesc(int* __restrict__ hd, int* __restrict__ vd,
                         int hdcap, int vdcap, DscP P) {
  int gid = blockIdx.x * TPB + threadIdx.x;
  int totW = P.cumW[P.nj], totR = P.cumR[P.nj];
  if (gid < totW) {
    int j = findJob(P.cumW, P.nj, gid);
    int local = gid - P.cumW[j];
    int N = P.N[j];
    int ox = local % N, c = local / N;
    hd[gid]             = P.hOff[j] + c * 768 * N + ox;   // A
    hd[hdcap + gid]     = c * 769;                        // R (LDS row base)
    hd[2 * hdcap + gid] = N;                              // stride
    hd[3 * hdcap + gid] = P.oxB[j] + ox;                  // g
    hd[4 * hdcap + gid] = P.wOff[j] + ox;                 // W
  }
  if (gid < totR) {
    int j = findJob(P.cumR, P.nj, gid);
    int local = gid - P.cumR[j];
    int N = P.N[j];
    int oy = local % N, q = local / N;   // q = b*3+c in 0..23
    vd[gid]             = P.hOff[j] + q * 768 * N;        // S (src col base)
    vd[vdcap + gid]     = P.imgOff[j] + (q * N + oy) * N; // O (out row base)
    vd[2 * vdcap + gid] = P.oxB[j] + oy;                  // g
    vd[3 * vdcap + gid] = P.wOff[j] + oy;                 // W
    vd[4 * vdcap + gid] = N;                              // stride
  }
}

// ---------------- H pass: descriptor-driven, row-resident -------------------
__global__ void k_resizeH_d(const float* __restrict__ img, float* __restrict__ base,
                            const int* __restrict__ tX0, const int* __restrict__ tCNT,
                            const float* __restrict__ tWT, const float* __restrict__ tW,
                            const int* __restrict__ hd, int hdcap, int total) {
  __shared__ float row[3][769];
  const int y = blockIdx.x, b = blockIdx.y;
  const float* src = img + ((long)b * 768 + y) * 768 * 3;
  for (int t = threadIdx.x; t < 2304; t += TPB) {
    int x = t / 3, c = t - 3 * x;
    row[c][x] = src[t];
  }
  __syncthreads();
  const float* rowF = &row[0][0];
  const long yb = (long)y + 2304L * b;
  for (int t = threadIdx.x; t < total; t += TPB) {
    int A = hd[t];
    int R = hd[hdcap + t];
    int N = hd[2 * hdcap + t];
    int g = hd[3 * hdcap + t];
    int W = hd[4 * hdcap + t];
    int x0 = tX0[g], cnt = tCNT[g];
    float wt = tWT[g];
    const float* wv = tW + W;
    const float* rp = rowF + R + x0;
    float acc = 0.f;
    int k = 0;
    for (; k + 3 < cnt; k += 4) {
      float v0 = rp[k],     w0 = wv[k * N];
      float v1 = rp[k + 1], w1 = wv[(k + 1) * N];
      float v2 = rp[k + 2], w2 = wv[(k + 2) * N];
      float v3 = rp[k + 3], w3 = wv[(k + 3) * N];
      acc += v0 * w0; acc += v1 * w1; acc += v2 * w2; acc += v3 * w3;
    }
    for (; k < cnt; ++k) acc += rp[k] * wv[k * N];
    base[(long)A + (long)N * yb] = acc / wt;
  }
}

// ---------------- V pass: one 64-lane wave per output row -------------------
__global__ void k_resizeV_row(const float* __restrict__ basep, float* __restrict__ img,
                              const int* __restrict__ tX0, const int* __restrict__ tCNT,
                              const float* __restrict__ tWT, const float* __restrict__ tW,
                              const int* __restrict__ vd, int vdcap, int nRows) {
  int row = blockIdx.x * 4 + (threadIdx.x >> 6);
  if (row >= nRows) return;
  int lane = threadIdx.x & 63;
  int S = vd[row];
  int O = vd[vdcap + row];
  int g = vd[2 * vdcap + row];
  int W = vd[3 * vdcap + row];
  int N = vd[4 * vdcap + row];
  int y0 = tX0[g], cnt = tCNT[g];
  float wt = tWT[g];
  const float* wv = tW + W;
  const float* col0 = basep + S + (long)y0 * N;
  for (int ox = lane; ox < N; ox += 64) {
    const float* col = col0 + ox;
    float acc = 0.f;
    int k = 0;
    for (; k + 3 < cnt; k += 4) {
      float v0 = col[k * N],       w0 = wv[k * N];
      float v1 = col[(k + 1) * N], w1 = wv[(k + 1) * N];
      float v2 = col[(k + 2) * N], w2 = wv[(k + 2) * N];
      float v3 = col[(k + 3) * N], w3 = wv[(k + 3) * N];
      acc += v0 * w0; acc += v1 * w1; acc += v2 * w2; acc += v3 * w3;
    }
    for (; k < cnt; ++k) acc += col[k * N] * wv[k * N];
    img[(long)O + ox] = (acc / wt - 127.5f) * 0.0078125f;
  }
}

// ---------------- fused conv1 + PReLU + 2x2 ceil-maxpool (all 10 co) --------
__device__ __forceinline__ void conv1pool_body(
    const float* in, const float* w, const float* bias, const float* pr,
    float* out, int H, int W, int b, int px, int py) {
  const int h1 = H - 2, w1 = W - 2;
  const int PH = (h1 + 1) >> 1, PW = (w1 + 1) >> 1;
  if (px >= PW || py >= PH) return;
  const int x0 = px * 2, y0 = py * 2;
  float a00[10], a01[10], a10[10], a11[10];
#pragma unroll
  for (int co = 0; co < 10; ++co) { a00[co] = 0.f; a01[co] = 0.f; a10[co] = 0.f; a11[co] = 0.f; }
  const long HW = (long)H * W;
  const float* pp = in + ((long)b * 3 * H + y0) * W + x0;
  for (int ci = 0; ci < 3; ++ci, pp += HW) {
    const float* r = pp;
    float r00 = r[0], r01 = r[1], r02 = r[2], r03 = r[3]; r += W;
    float r10 = r[0], r11 = r[1], r12 = r[2], r13 = r[3]; r += W;
    float r20 = r[0], r21 = r[1], r22 = r[2], r23 = r[3]; r += W;
    float r30 = r[0], r31 = r[1], r32 = r[2], r33 = r[3];
#pragma unroll
    for (int co = 0; co < 10; ++co) {
      const float* wc = w + ((long)co * 3 + ci) * 9;
      float w0 = wc[0], w1_ = wc[1], w2 = wc[2];
      float w3 = wc[3], w4 = wc[4], w5 = wc[5];
      float w6 = wc[6], w7 = wc[7], w8 = wc[8];
      a00[co] += r00 * w0 + r01 * w1_ + r02 * w2;
      a00[co] += r10 * w3 + r11 * w4 + r12 * w5;
      a00[co] += r20 * w6 + r21 * w7 + r22 * w8;
      a01[co] += r01 * w0 + r02 * w1_ + r03 * w2;
      a01[co] += r11 * w3 + r12 * w4 + r13 * w5;
      a01[co] += r21 * w6 + r22 * w7 + r23 * w8;
      a10[co] += r10 * w0 + r11 * w1_ + r12 * w2;
      a10[co] += r20 * w3 + r21 * w4 + r22 * w5;
      a10[co] += r30 * w6 + r31 * w7 + r32 * w8;
      a11[co] += r11 * w0 + r12 * w1_ + r13 * w2;
      a11[co] += r21 * w3 + r22 * w4 + r23 * w5;
      a11[co] += r31 * w6 + r32 * w7 + r33 * w8;
    }
  }
  const bool vx = (x0 + 1 < w1), vy = (y0 + 1 < h1);
#pragma unroll
  for (int co = 0; co < 10; ++co) {
    const float bb = bias[co], al = pr[co];
    float v = a00[co] + bb; v = v > 0.f ? v : al * v;
    float m = v;
    if (vx) { v = a01[co] + bb; v = v > 0.f ? v : al * v; m = fmaxf(m, v); }
    if (vy) { v = a10[co] + bb; v = v > 0.f ? v : al * v; m = fmaxf(m, v); }
    if (vx && vy) { v = a11[co] + bb; v = v > 0.f ? v : al * v; m = fmaxf(m, v); }
    out[(((long)b * 10 + co) * PH + py) * PW + px] = m;
  }
}

struct C1P { int nj; int nh[NJMAX]; int imgOff[NJMAX], poolOff[NJMAX];
             int t1x[NJMAX]; int cumT[NJMAX + 1]; };

__global__ void k_conv1pool_job(const float* __restrict__ imgb, const float* __restrict__ w,
                                const float* __restrict__ bias, const float* __restrict__ pr,
                                float* __restrict__ poolb, C1P P) {
  int j = findJob(P.cumT, P.nj, blockIdx.x);
  int local = blockIdx.x - P.cumT[j];
  int t1x = P.t1x[j];
  int tX = local % t1x, tY = local / t1x;
  conv1pool_body(imgb + P.imgOff[j], w, bias, pr, poolb + P.poolOff[j],
                 P.nh[j], P.nh[j], blockIdx.z,
                 tX * 16 + (threadIdx.x & 15), tY * 16 + (threadIdx.x >> 4));
}

// ---------------- co-blocked (8) tiled 3x3 conv + PReLU ---------------------
__device__ __forceinline__ void conv3x3c8_body(
    const float* in, const float* w, const float* bias, const float* pr,
    float* out, int Cin, int Cout, int H, int W, int cog, int b, int x0, int y) {
  const int OH = H - 2, OW = W - 2;
  if (y >= OH || x0 >= OW) return;
  float acc[8][4];
#pragma unroll
  for (int k = 0; k < 8; ++k) { acc[k][0] = 0.f; acc[k][1] = 0.f; acc[k][2] = 0.f; acc[k][3] = 0.f; }
  const float* wp = w + (long)cog * Cin * 9;
  const long HW = (long)H * W;
  const float* pp = in + ((long)b * Cin * H + y) * W + x0;
  for (int ci = 0; ci < Cin; ++ci, pp += HW) {
    const float* r = pp;
    float q00 = r[0], q01 = r[1], q02 = r[2], q03 = r[3], q04 = r[4], q05 = r[5]; r += W;
    float q10 = r[0], q11 = r[1], q12 = r[2], q13 = r[3], q14 = r[4], q15 = r[5]; r += W;
    float q20 = r[0], q21 = r[1], q22 = r[2], q23 = r[3], q24 = r[4], q25 = r[5];
#pragma unroll
    for (int k = 0; k < 8; ++k) {
      const float* wc = wp + ((long)k * Cin + ci) * 9;
      float w0 = wc[0], w1 = wc[1], w2 = wc[2];
      float w3 = wc[3], w4 = wc[4], w5 = wc[5];
      float w6 = wc[6], w7 = wc[7], w8 = wc[8];
      acc[k][0] += q00 * w0 + q01 * w1 + q02 * w2;
      acc[k][1] += q01 * w0 + q02 * w1 + q03 * w2;
      acc[k][2] += q02 * w0 + q03 * w1 + q04 * w2;
      acc[k][3] += q03 * w0 + q04 * w1 + q05 * w2;
      acc[k][0] += q10 * w3 + q11 * w4 + q12 * w5;
      acc[k][1] += q11 * w3 + q12 * w4 + q13 * w5;
      acc[k][2] += q12 * w3 + q13 * w4 + q14 * w5;
      acc[k][3] += q13 * w3 + q14 * w4 + q15 * w5;
      acc[k][0] += q20 * w6 + q21 * w7 + q22 * w8;
      acc[k][1] += q21 * w6 + q22 * w7 + q23 * w8;
      acc[k][2] += q22 * w6 + q23 * w7 + q24 * w8;
      acc[k][3] += q23 * w6 + q24 * w7 + q25 * w8;
    }
  }
  const int rem = OW - x0;
#pragma unroll
  for (int k = 0; k < 8; ++k) {
    const int co = cog + k;
    const float bb = bias[co], al = pr[co];
    float* op = out + (((long)b * Cout + co) * OH + y) * OW + x0;
    float v0 = acc[k][0] + bb; v0 = v0 > 0.f ? v0 : al * v0;
    op[0] = v0;
    if (rem > 1) { float v = acc[k][1] + bb; v = v > 0.f ? v : al * v; op[1] = v; }
    if (rem > 2) { float v = acc[k][2] + bb; v = v > 0.f ? v : al * v; op[2] = v; }
    if (rem > 3) { float v = acc[k][3] + bb; v = v > 0.f ? v : al * v; op[3] = v; }
  }
}

struct CvP { int nj; int H[NJMAX]; int inOff[NJMAX], outOff[NJMAX];
             int tx[NJMAX]; int cumT[NJMAX + 1]; };

__global__ void k_conv3x3c8_job(const float* __restrict__ inb, const float* __restrict__ w,
                                const float* __restrict__ bias, const float* __restrict__ pr,
                                float* __restrict__ outb, int Cin, int Cout, CvP P) {
  int j = findJob(P.cumT, P.nj, blockIdx.x);
  int local = blockIdx.x - P.cumT[j];
  int tx0 = P.tx[j];
  int tX = local % tx0, tY = local / tx0;
  conv3x3c8_body(inb + P.inOff[j], w, bias, pr, outb + P.outOff[j], Cin, Cout,
                 P.H[j], P.H[j], blockIdx.y * 8, blockIdx.z,
                 tX * 64 + (threadIdx.x & 15) * 4, tY * 16 + (threadIdx.x >> 4));
}

// ---------------- 1x1 heads -------------------------------------------------
__device__ __forceinline__ void head_body(const float* x3, const float* w41,
                                          const float* b41, const float* w42,
                                          const float* b42, float* reg, u64* keys,
                                          int plane, long idx) {
  int b = (int)(idx / plane); int rem = (int)(idx % plane);
  const float* p = x3 + (long)b * 32 * plane + rem;
  float l0 = 0.f, l1 = 0.f, r0 = 0.f, r1 = 0.f, r2 = 0.f, r3 = 0.f;
  for (int c = 0; c < 32; ++c) {
    float v = p[(long)c * plane];
    l0 += v * w41[c];      l1 += v * w41[32 + c];
    r0 += v * w42[c];      r1 += v * w42[32 + c];
    r2 += v * w42[64 + c]; r3 += v * w42[96 + c];
  }
  l0 += b41[0]; l1 += b41[1];
  r0 += b42[0]; r1 += b42[1]; r2 += b42[2]; r3 += b42[3];
  float mx = fmaxf(l0, l1);
  float e0 = expf(l0 - mx), e1 = expf(l1 - mx);
  float s = e1 / (e0 + e1);
  reg[idx * 4 + 0] = r0; reg[idx * 4 + 1] = r1;
  reg[idx * 4 + 2] = r2; reg[idx * 4 + 3] = r3;
  u32 ic = 0xFFFFFFFFu - (u32)idx;
  u64 k = (s >= 0.6f) ? ((((u64)__float_as_uint(s)) << 32) | ic) : (u64)ic;
  keys[idx] = k;
}

struct HdP { int nj; int h3[NJMAX]; int c3Off[NJMAX], kOff[NJMAX];
             int cumC[NJMAX + 1]; };

__global__ void k_head_job(const float* __restrict__ c3b, const float* __restrict__ w41,
                           const float* __restrict__ b41, const float* __restrict__ w42,
                           const float* __restrict__ b42, float* __restrict__ regb,
                           u64* __restrict__ keysb, HdP P) {
  int gid = blockIdx.x * TPB + threadIdx.x;
  if (gid >= P.cumC[P.nj]) return;
  int j = findJob(P.cumC, P.nj, gid);
  int idx = gid - P.cumC[j];
  head_body(c3b + P.c3Off[j], w41, b41, w42, b42,
            regb + 4L * P.kOff[j], keysb + P.kOff[j], P.h3[j] * P.h3[j], idx);
}

// ---------------- bitonic top-K ---------------------------------------------
__device__ __forceinline__ void bitonic2048(u64* s) {
  for (int k = 2; k <= 2048; k <<= 1) {
    for (int j = k >> 1; j > 0; j >>= 1) {
      for (int i = threadIdx.x; i < 2048; i += TPB) {
        int ixj = i ^ j;
        if (ixj > i) {
          u64 a = s[i], b = s[ixj];
          bool desc = ((i & k) == 0);
          if (desc ? (a < b) : (a > b)) { s[i] = b; s[ixj] = a; }
        }
      }
      __syncthreads();
    }
  }
}

struct TkP { int nj; int srcSel[NJMAX]; int srcOff[NJMAX]; int n[NJMAX];
             int dstOff[NJMAX]; int cumB[NJMAX + 1]; };

__global__ void k_topk_job(u64* __restrict__ A, u64* __restrict__ B, TkP P) {
  __shared__ u64 s[2048];
  int j = findJob(P.cumB, P.nj, blockIdx.x);
  int lb = blockIdx.x - P.cumB[j];
  const u64* src = (P.srcSel[j] ? B : A) + P.srcOff[j];
  u64* dst = (P.srcSel[j] ? A : B) + P.dstOff[j];
  int n = P.n[j];
  int base = lb * 2048;
  for (int t = threadIdx.x; t < 2048; t += TPB) {
    int gi = base + t;
    s[t] = (gi < n) ? src[gi] : 0ULL;
  }
  __syncthreads();
  bitonic2048(s);
  for (int t = threadIdx.x; t < 512; t += TPB)
    dst[(long)lb * 512 + t] = s[t];
}

struct TkFP { int nj; int srcSel[NJMAX]; int srcOff[NJMAX]; int n[NJMAX]; int sIdx[NJMAX]; };

__global__ void k_topk_fin(const u64* __restrict__ A, const u64* __restrict__ B,
                           u64* __restrict__ selk, TkFP P) {
  __shared__ u64 s[2048];
  int j = blockIdx.x;
  const u64* src = (P.srcSel[j] ? B : A) + P.srcOff[j];
  int n = P.n[j];
  for (int t = threadIdx.x; t < 2048; t += TPB)
    s[t] = (t < n) ? src[t] : 0ULL;
  __syncthreads();
  bitonic2048(s);
  for (int t = threadIdx.x; t < 512; t += TPB)
    selk[(long)P.sIdx[j] * 512 + t] = s[t];
}

// ---------------- gather box rows -------------------------------------------
__device__ __forceinline__ void gather_body(const u64* keys, const float* reg,
                                            float* boxes, int h, int w, float scalef,
                                            int i) {
  float* bx = boxes + (long)i * 12;
  u64 key = keys[i];
  if ((key >> 32) == 0ULL) {
    for (int q = 0; q < 12; ++q) bx[q] = 0.f;
    return;
  }
  u32 cell = 0xFFFFFFFFu - (u32)(key & 0xFFFFFFFFu);
  int x = (int)(cell % (u32)w); u32 t2 = cell / (u32)w;
  int y = (int)(t2 % (u32)h); int b = (int)(t2 / (u32)h);
  float fx = (float)x, fy = (float)y;
  bx[0] = floorf((2.f * fx + 1.f) / scalef);
  bx[1] = floorf((2.f * fy + 1.f) / scalef);
  bx[2] = floorf((2.f * fx + 12.f) / scalef);
  bx[3] = floorf((2.f * fy + 12.f) / scalef);
  bx[4] = __uint_as_float((u32)(key >> 32));
  bx[5] = reg[(long)cell * 4 + 0];
  bx[6] = reg[(long)cell * 4 + 1];
  bx[7] = reg[(long)cell * 4 + 2];
  bx[8] = reg[(long)cell * 4 + 3];
  bx[9] = (float)b;
  bx[10] = 1.f;
  bx[11] = 0.f;
}

struct GtP { int nj; int h3[NJMAX]; float scalef[NJMAX]; int kOff[NJMAX]; int sIdx[NJMAX]; };

__global__ void k_gather_job(const u64* __restrict__ selk, const float* __restrict__ regb,
                             float* __restrict__ boxes, GtP P) {
  int j = blockIdx.x >> 1;
  int i = ((blockIdx.x & 1) << 8) + threadIdx.x;
  gather_body(selk + (long)P.sIdx[j] * 512, regb + 4L * P.kOff[j],
              boxes + (long)P.sIdx[j] * 512 * 12, P.h3[j], P.h3[j], P.scalef[j], i);
}

// ---------------- greedy NMS, 64-wide batched (bit-exact) --------------------
__global__ void k_nms(float* __restrict__ boxes, int per, float thr) {
  __shared__ float sx1[1024], sy1[1024], sx2[1024], sy2[1024], sar[1024];
  __shared__ unsigned char kp[1024];
  __shared__ unsigned char kb[64];
  __shared__ int snv;
  float* bs = boxes + (long)blockIdx.x * per * 12;
  int N = per;
  if (threadIdx.x == 0) snv = 0;
  __syncthreads();
  for (int i = threadIdx.x; i < N; i += blockDim.x) {
    const float* b = bs + (long)i * 12;
    float off = b[9] * 100000.0f;
    float a0 = b[0] + off, a1 = b[1] + off, a2 = b[2] + off, a3 = b[3] + off;
    sx1[i] = a0; sy1[i] = a1; sx2[i] = a2; sy2[i] = a3;
    sar[i] = fmaxf(a2 - a0, 0.f) * fmaxf(a3 - a1, 0.f);
    bool v = (b[10] != 0.f);
    kp[i] = v;
    if (v) atomicMax(&snv, i + 1);
  }
  __syncthreads();
  int nv = snv;
  const int wave = threadIdx.x >> 6, lane = threadIdx.x & 63;
  for (int base = 0; base < nv; base += 64) {
    const int lim = (nv - base < 64) ? (nv - base) : 64;
    if (wave == 0) {
      int gi = base + lane;
      bool ok = (lane < lim) && kp[gi];
      float bx1 = 0.f, by1 = 0.f, bx2 = 0.f, by2 = 0.f, ba = 0.f;
      if (lane < lim) { bx1 = sx1[gi]; by1 = sy1[gi]; bx2 = sx2[gi]; by2 = sy2[gi]; ba = sar[gi]; }
      for (int i = 0; i < lim; ++i) {
        int ki = __shfl((int)ok, i);
        float xi1 = __shfl(bx1, i), yi1 = __shfl(by1, i);
        float xi2 = __shfl(bx2, i), yi2 = __shfl(by2, i);
        float ai = __shfl(ba, i);
        if (ki && lane > i && ok) {
          float iw = fmaxf(fminf(xi2, bx2) - fmaxf(xi1, bx1), 0.f);
          float ih = fmaxf(fminf(yi2, by2) - fmaxf(yi1, by1), 0.f);
          float inter = iw * ih;
          float iou = inter / (ai + ba - inter + 1e-9f);
          if (iou > thr) ok = false;
        }
      }
      if (lane < lim) kp[gi] = ok ? 1 : 0;
      kb[lane] = (lane < lim && ok) ? 1 : 0;
    }
    __syncthreads();
    for (int j = base + 64 + threadIdx.x; j < nv; j += blockDim.x) {
      if (!kp[j]) continue;
      float jx2 = sx2[j], jy2 = sy2[j], jx1 = sx1[j], jy1 = sy1[j], ja = sar[j];
      bool ok = true;
      for (int i = 0; i < lim && ok; ++i) {
        if (!kb[i]) continue;
        int gi = base + i;
        float iw = fmaxf(fminf(sx2[gi], jx2) - fmaxf(sx1[gi], jx1), 0.f);
        float ih = fmaxf(fminf(sy2[gi], jy2) - fmaxf(sy1[gi], jy1), 0.f);
        float inter = iw * ih;
        float iou = inter / (sar[gi] + ja - inter + 1e-9f);
        if (iou > thr) ok = false;
      }
      if (!ok) kp[j] = 0;
    }
    __syncthreads();
  }
  for (int i = threadIdx.x; i < N; i += blockDim.x)
    bs[(long)i * 12 + 11] = kp[i] ? 1.f : 0.f;
}

// ---------------- fused final stage: keys+sort+gather+NMS+refine, 1 block ----
__global__ void k_final(const float* __restrict__ boxes, int total, float thr,
                        float* __restrict__ selfb, float* __restrict__ out) {
  __shared__ u64 s[8192];
  __shared__ unsigned char kb[64];
  __shared__ int snv;
  float* fb = (float*)s;
  const int tid = threadIdx.x;   // 1024 threads
  // 1) build keys (identical to k_finalkeys)
  for (int i = tid; i < 8192; i += 1024) {
    u64 k = 0ULL;
    if (i < total) {
      const float* b = boxes + (long)i * 12;
      u32 ic = 0xFFFFFFFFu - (u32)i;
      k = (b[11] != 0.f) ? ((((u64)__float_as_uint(b[4])) << 32) | ic) : (u64)ic;
    }
    s[i] = k;
  }
  if (tid == 0) snv = 0;
  __syncthreads();
  // 2) full bitonic sort descending (unique keys -> exact top-1024, same order
  //    as the 3-round tournament it replaces)
  for (int k = 2; k <= 8192; k <<= 1) {
    for (int j = k >> 1; j > 0; j >>= 1) {
      for (int i = tid; i < 8192; i += 1024) {
        int ixj = i ^ j;
        if (ixj > i) {
          u64 a = s[i], b = s[ixj];
          bool desc = ((i & k) == 0);
          if (desc ? (a < b) : (a > b)) { s[i] = b; s[ixj] = a; }
        }
      }
      __syncthreads();
    }
  }
  // 3) consume top-1024 keys, then alias sort buffer as NMS arrays
  u64 myKey = s[tid];
  __syncthreads();
  float* sx1 = fb;
  float* sy1 = fb + 1024;
  float* sx2 = fb + 2048;
  float* sy2 = fb + 3072;
  float* sar = fb + 4096;
  unsigned char* kp = (unsigned char*)(fb + 5120);
  {
    int i = tid;
    float* o = selfb + (long)i * 12;
    if ((myKey >> 32) == 0ULL) {
      for (int q = 0; q < 12; ++q) o[q] = 0.f;
      sx1[i] = 0.f; sy1[i] = 0.f; sx2[i] = 0.f; sy2[i] = 0.f; sar[i] = 0.f;
      kp[i] = 0;
    } else {
      u32 bi = 0xFFFFFFFFu - (u32)(myKey & 0xFFFFFFFFu);
      const float* b = boxes + (long)bi * 12;
      float r0 = b[0], r1 = b[1], r2 = b[2], r3 = b[3], r4 = b[4];
      float r5 = b[5], r6 = b[6], r7 = b[7], r8 = b[8], r9 = b[9];
      o[0] = r0; o[1] = r1; o[2] = r2; o[3] = r3; o[4] = r4;
      o[5] = r5; o[6] = r6; o[7] = r7; o[8] = r8; o[9] = r9;
      o[10] = 1.f; o[11] = 0.f;
      float off = r9 * 100000.0f;
      float a0 = r0 + off, a1 = r1 + off, a2 = r2 + off, a3 = r3 + off;
      sx1[i] = a0; sy1[i] = a1; sx2[i] = a2; sy2[i] = a3;
      sar[i] = fmaxf(a2 - a0, 0.f) * fmaxf(a3 - a1, 0.f);
      kp[i] = 1;
      atomicMax(&snv, i + 1);
    }
  }
  __syncthreads();
  // 4) batched greedy NMS (same as k_nms)
  int nv = snv;
  const int wave = tid >> 6, lane = tid & 63;
  for (int base = 0; base < nv; base += 64) {
    const int lim = (nv - base < 64) ? (nv - base) : 64;
    if (wave == 0) {
      int gi = base + lane;
      bool ok = (lane < lim) && kp[gi];
      float bx1 = 0.f, by1 = 0.f, bx2 = 0.f, by2 = 0.f, ba = 0.f;
      if (lane < lim) { bx1 = sx1[gi]; by1 = sy1[gi]; bx2 = sx2[gi]; by2 = sy2[gi]; ba = sar[gi]; }
      for (int i = 0; i < lim; ++i) {
        int ki = __shfl((int)ok, i);
        float xi1 = __shfl(bx1, i), yi1 = __shfl(by1, i);
        float xi2 = __shfl(bx2, i), yi2 = __shfl(by2, i);
        float ai = __shfl(ba, i);
        if (ki && lane > i && ok) {
          float iw = fmaxf(fminf(xi2, bx2) - fmaxf(xi1, bx1), 0.f);
          float ih = fmaxf(fminf(yi2, by2) - fmaxf(yi1, by1), 0.f);
          float inter = iw * ih;
          float iou = inter / (ai + ba - inter + 1e-9f);
          if (iou > thr) ok = false;
        }
      }
      if (lane < lim) kp[gi] = ok ? 1 : 0;
      kb[lane] = (lane < lim && ok) ? 1 : 0;
    }
    __syncthreads();
    for (int j = base + 64 + tid; j < nv; j += blockDim.x) {
      if (!kp[j]) continue;
      float jx2 = sx2[j], jy2 = sy2[j], jx1 = sx1[j], jy1 = sy1[j], ja = sar[j];
      bool ok = true;
      for (int i = 0; i < lim && ok; ++i) {
        if (!kb[i]) continue;
        int gi = base + i;
        float iw = fmaxf(fminf(sx2[gi], jx2) - fmaxf(sx1[gi], jx1), 0.f);
        float ih = fmaxf(fminf(sy2[gi], jy2) - fmaxf(sy1[gi], jy1), 0.f);
        float inter = iw * ih;
        float iou = inter / (sar[gi] + ja - inter + 1e-9f);
        if (iou > thr) ok = false;
      }
      if (!ok) kp[j] = 0;
    }
    __syncthreads();
  }
  // 5) refine (keep = kp, same math as k_refine)
  {
    int i = tid;
    const float* b = selfb + (long)i * 12;
    float keep = kp[i] ? 1.f : 0.f;
    float x1 = b[0], y1 = b[1], x2 = b[2], y2 = b[3], sc = b[4];
    float rw = x2 - x1, rh = y2 - y1;
    float o0 = x1 + b[5] * rw;
    float o1 = y1 + b[6] * rh;
    float o2 = x2 + b[7] * rw;
    float o3 = y2 + b[8] * rh;
    float hh = o3 - o1, ww = o2 - o0;
    float l = fmaxf(hh, ww);
    float nx1 = o0 + ww * 0.5f - l * 0.5f;
    float ny1 = o1 + hh * 0.5f - l * 0.5f;
    out[(long)i * 5 + 0] = nx1 * keep;
    out[(long)i * 5 + 1] = ny1 * keep;
    out[(long)i * 5 + 2] = (nx1 + l) * keep;
    out[(long)i * 5 + 3] = (ny1 + l) * keep;
    out[(long)i * 5 + 4] = sc * keep;
  }
}

extern "C" void kernel_launch(void* const* d_in, const int* in_sizes, int n_in,
                              void* d_out, int out_size, void* d_ws, size_t ws_size,
                              hipStream_t stream) {
  (void)in_sizes; (void)n_in; (void)out_size;
  const float* images = (const float*)d_in[0];
  const float* c1w = (const float*)d_in[1];
  const float* c1b = (const float*)d_in[2];
  const float* p1  = (const float*)d_in[3];
  const float* c2w = (const float*)d_in[4];
  const float* c2b = (const float*)d_in[5];
  const float* p2  = (const float*)d_in[6];
  const float* c3w = (const float*)d_in[7];
  const float* c3b = (const float*)d_in[8];
  const float* p3  = (const float*)d_in[9];
  const float* w41 = (const float*)d_in[10];
  const float* b41 = (const float*)d_in[11];
  const float* w42 = (const float*)d_in[12];
  const float* b42 = (const float*)d_in[13];
  float* ws = (float*)d_ws;

  double scl[16]; int nsc = 0;
  {
    double m = 12.0 / 20.0;
    double ml = 768.0 * m;
    double si = m;
    while (ml >= 12.0) { scl[nsc++] = si; si *= 0.709; ml *= 0.709; }
  }

  auto cdiv = [](long a, long b) { return (int)((a + b - 1) / b); };

  // per-scale dims + weight-table geometry
  int NH[NSC], PH_[NSC], H2[NSC], H3[NSC], OXB[NSC], TT[NSC], WOFF[NSC];
  float INV[NSC], KSF[NSC];
  {
    int oxb = 0, woff = 0;
    for (int s = 0; s < nsc; ++s) {
      int nh = (int)(768.0 * scl[s] + 1.0);
      NH[s] = nh;
      PH_[s] = ((nh - 2) + 1) / 2;
      H2[s] = PH_[s] - 2;
      H3[s] = H2[s] - 2;
      double inv = 1.0 / (((double)nh) / 768.0);
      INV[s] = (float)inv;
      KSF[s] = (float)(inv > 1.0 ? inv : 1.0);
      TT[s] = (int)(2.0f * KSF[s]) + 2;
      OXB[s] = oxb; oxb += nh;
      WOFF[s] = woff; woff += nh * TT[s];
    }
  }

  // candidate groupings
  static const int GA[11] = {0, 1, 2, 3, 4, 5, 6, 7, 8, 9, 10};
  static const int G1[7] = {0, 5, 6, 7, 8, 9, 10};
  static const int G2[4] = {1, 2, 3, 4};

  struct Layout {
    long HT, IMG, POOL, C2, REG, KEYS, SCR, SEL, BOX, FK, FS, SF, TBL, HD, VD, extent;
    int hdcap, vdcap;
  };

  auto calcLayout = [&](const int* const* gps, const int* gn, int ng,
                        int hdcap, int vdcap, Layout& L) {
    long htA = 0, c3A = 0, imgA = 0, poolA = 0, c2A = 0, cellsA = 0, scrA = 0;
    for (int g = 0; g < ng; ++g) {
      long ht = 0, c3 = 0, im = 0, pl = 0, c2s = 0, ck = 0, sc = 0;
      for (int q = 0; q < gn[g]; ++q) {
        int s = gps[g][q];
        ht += 24L * 768 * NH[s];
        im += 24L * NH[s] * NH[s];
        pl += 80L * PH_[s] * PH_[s];
        c2s += 128L * H2[s] * H2[s];
        c3 += 256L * H3[s] * H3[s];
        long cells = 8L * H3[s] * H3[s];
        ck += cells;
        sc += 512L * ((cells + 2047) / 2048);
      }
      if (ht > htA) htA = ht; if (c3 > c3A) c3A = c3; if (im > imgA) imgA = im;
      if (pl > poolA) poolA = pl; if (c2s > c2A) c2A = c2s;
      if (ck > cellsA) cellsA = ck; if (sc > scrA) scrA = sc;
    }
    long htR = htA > c3A ? htA : c3A;
    auto al = [](long v) { return (v + 15) & ~15L; };
    long off = 0;
    L.HT = off;   off += al(htR);
    L.IMG = off;  off += al(imgA);
    L.POOL = off; off += al(poolA);
    L.C2 = off;   off += al(c2A);
    L.REG = off;  off += al(4 * cellsA);
    L.KEYS = off; off += al(2 * cellsA);
    L.SCR = off;  off += al(2 * scrA + 16384);
    L.SEL = off;  off += al(11264);
    L.BOX = off;  off += al(67584);
    L.FK = off;   off += al(16384);
    L.FS = off;   off += al(2048);
    L.SF = off;   off += al(12288);
    L.TBL = off;  off += al(12288 + 24000);
    L.HD = off;   off += al((long)ng * 5 * hdcap);
    L.VD = off;   off += al((long)ng * 5 * vdcap);
    L.extent = off;
    L.hdcap = hdcap; L.vdcap = vdcap;
  };

  Layout LA, LB;
  {
    const int* gpsA[1] = {GA}; int gnA[1] = {11};
    calcLayout(gpsA, gnA, 1, 8192, 56320, LA);
    const int* gpsB[2] = {G1, G2}; int gnB[2] = {7, 4};
    calcLayout(gpsB, gnB, 2, 2560, 20480, LB);
  }
  bool big = (ws_size >= (size_t)LA.extent * 4);
  const Layout& L = big ? LA : LB;
  const int* GS[2]; int GN[2]; int ngroups;
  if (big) { GS[0] = GA; GN[0] = 11; ngroups = 1; }
  else { GS[0] = G1; GN[0] = 7; GS[1] = G2; GN[1] = 4; ngroups = 2; }

  u64* keys  = (u64*)(ws + L.KEYS);
  u64* scr   = (u64*)(ws + L.SCR);
  u64* selk  = (u64*)(ws + L.SEL);
  float* boxes = ws + L.BOX;
  float* self  = ws + L.SF;
  int*   tX0  = (int*)(ws + L.TBL);
  int*   tCNT = (int*)(ws + L.TBL + 4096);
  float* tWT  = ws + L.TBL + 8192;
  float* tW   = ws + L.TBL + 12288;

  // build resize weight tables (once per launch)
  {
    MkP P; P.ns = nsc;
    for (int s = 0; s < nsc; ++s) {
      P.nw[s] = NH[s]; P.invs[s] = INV[s]; P.ks[s] = KSF[s];
      P.oxB[s] = OXB[s]; P.T[s] = TT[s]; P.wOff[s] = WOFF[s];
    }
    k_mkweights<<<nsc, TPB, 0, stream>>>(tX0, tCNT, tWT, tW, P);
  }

  // per-group geometry
  int imgOff[2][NJMAX], poolOff[2][NJMAX], c2Off[2][NJMAX], c3Off[2][NJMAX],
      htOff[2][NJMAX], kOff[2][NJMAX], cells[2][NJMAX];
  int cumWtot[2], cumRtot[2];
  for (int g = 0; g < ngroups; ++g) {
    long ch = 0, ci = 0, cp = 0, c2 = 0, c3 = 0, ck = 0;
    int cw = 0, cr = 0;
    for (int q = 0; q < GN[g]; ++q) {
      int s = GS[g][q];
      htOff[g][q] = (int)ch;  ch += 24L * 768 * NH[s];
      imgOff[g][q] = (int)ci; ci += 24L * NH[s] * NH[s];
      poolOff[g][q] = (int)cp; cp += 80L * PH_[s] * PH_[s];
      c2Off[g][q] = (int)c2;  c2 += 128L * H2[s] * H2[s];
      c3Off[g][q] = (int)c3;  c3 += 256L * H3[s] * H3[s];
      kOff[g][q] = (int)ck;   cells[g][q] = 8 * H3[s] * H3[s]; ck += cells[g][q];
      cw += 3 * NH[s]; cr += 24 * NH[s];
    }
    cumWtot[g] = cw; cumRtot[g] = cr;
  }

  // build H/V descriptors (geometry-only)
  for (int g = 0; g < ngroups; ++g) {
    DscP P; P.nj = GN[g];
    int cw = 0, cr = 0;
    for (int q = 0; q < GN[g]; ++q) {
      int s = GS[g][q];
      P.N[q] = NH[s]; P.hOff[q] = htOff[g][q]; P.imgOff[q] = imgOff[g][q];
      P.oxB[q] = OXB[s]; P.wOff[q] = WOFF[s];
      P.cumW[q] = cw; cw += 3 * NH[s];
      P.cumR[q] = cr; cr += 24 * NH[s];
    }
    P.cumW[GN[g]] = cw; P.cumR[GN[g]] = cr;
    int* hd = (int*)(ws + L.HD) + (long)g * 5 * L.hdcap;
    int* vd = (int*)(ws + L.VD) + (long)g * 5 * L.vdcap;
    int tot = cw > cr ? cw : cr;
    k_mkdesc<<<cdiv(tot, TPB), TPB, 0, stream>>>(hd, vd, L.hdcap, L.vdcap, P);
  }

  // ---------------- unified job pipeline over groups ----------------
  for (int g = 0; g < ngroups; ++g) {
    const int* gs = GS[g];
    int nj = GN[g];
    int* hd = (int*)(ws + L.HD) + (long)g * 5 * L.hdcap;
    int* vd = (int*)(ws + L.VD) + (long)g * 5 * L.vdcap;
    {
      dim3 gh(768, 8, 1);
      k_resizeH_d<<<gh, TPB, 0, stream>>>(images, ws + L.HT, tX0, tCNT, tWT, tW,
                                          hd, L.hdcap, cumWtot[g]);
    }
    k_resizeV_row<<<cdiv(cumRtot[g], 4), TPB, 0, stream>>>(
        ws + L.HT, ws + L.IMG, tX0, tCNT, tWT, tW, vd, L.vdcap, cumRtot[g]);
    {
      C1P P; P.nj = nj; int ct = 0;
      for (int q = 0; q < nj; ++q) {
        int s = gs[q];
        P.nh[q] = NH[s];
        P.imgOff[q] = imgOff[g][q]; P.poolOff[q] = poolOff[g][q];
        int t1x = cdiv(PH_[s], 16);
        P.t1x[q] = t1x;
        P.cumT[q] = ct; ct += t1x * t1x;
      }
      P.cumT[nj] = ct;
      dim3 gg(ct, 1, 8);
      k_conv1pool_job<<<gg, TPB, 0, stream>>>(ws + L.IMG, c1w, c1b, p1, ws + L.POOL, P);
    }
    {
      CvP P; P.nj = nj; int ct = 0;
      for (int q = 0; q < nj; ++q) {
        int s = gs[q];
        P.H[q] = PH_[s];
        P.inOff[q] = poolOff[g][q]; P.outOff[q] = c2Off[g][q];
        int tx = cdiv(H2[s], 64), ty = cdiv(H2[s], 16);
        P.tx[q] = tx;
        P.cumT[q] = ct; ct += tx * ty;
      }
      P.cumT[nj] = ct;
      dim3 gg(ct, 2, 8);
      k_conv3x3c8_job<<<gg, TPB, 0, stream>>>(ws + L.POOL, c2w, c2b, p2, ws + L.C2,
                                              10, 16, P);
    }
    {
      CvP P; P.nj = nj; int ct = 0;
      for (int q = 0; q < nj; ++q) {
        int s = gs[q];
        P.H[q] = H2[s];
        P.inOff[q] = c2Off[g][q]; P.outOff[q] = c3Off[g][q];
        int tx = cdiv(H3[s], 64), ty = cdiv(H3[s], 16);
        P.tx[q] = tx;
        P.cumT[q] = ct; ct += tx * ty;
      }
      P.cumT[nj] = ct;
      dim3 gg(ct, 4, 8);
      k_conv3x3c8_job<<<gg, TPB, 0, stream>>>(ws + L.C2, c3w, c3b, p3, ws + L.HT,
                                              16, 32, P);
    }
    {
      HdP P; P.nj = nj; int cc = 0;
      for (int q = 0; q < nj; ++q) {
        int s = gs[q];
        P.h3[q] = H3[s];
        P.c3Off[q] = c3Off[g][q]; P.kOff[q] = kOff[g][q];
        P.cumC[q] = cc; cc += cells[g][q];
      }
      P.cumC[nj] = cc;
      k_head_job<<<cdiv(cc, TPB), TPB, 0, stream>>>(ws + L.HT, w41, b41, w42, b42,
                                                    ws + L.REG, keys, P);
    }
    {
      int bOff[NJMAX];
      {
        int c = 0;
        for (int q = 0; q < nj; ++q) { bOff[q] = c; c += 512 * cdiv(cells[g][q], 2048); }
      }
      long nCur[NJMAX]; int par[NJMAX];
      for (int q = 0; q < nj; ++q) { nCur[q] = cells[g][q]; par[q] = 0; }
      while (true) {
        TkP P; P.nj = 0; int cum = 0; int act[NJMAX];
        for (int q = 0; q < nj; ++q) {
          if (nCur[q] > 2048) {
            int r = P.nj++;
            act[r] = q;
            int blocks = cdiv(nCur[q], 2048);
            P.srcSel[r] = par[q];
            P.srcOff[r] = par[q] ? bOff[q] : kOff[g][q];
            P.dstOff[r] = par[q] ? kOff[g][q] : bOff[q];
            P.n[r] = (int)nCur[q];
            P.cumB[r] = cum; cum += blocks;
          }
        }
        P.cumB[P.nj] = cum;
        if (P.nj == 0) break;
        k_topk_job<<<cum, TPB, 0, stream>>>(keys, scr, P);
        for (int r = 0; r < P.nj; ++r) {
          int q = act[r];
          nCur[q] = 512L * cdiv(nCur[q], 2048);
          par[q] ^= 1;
        }
      }
      TkFP F; F.nj = nj;
      for (int q = 0; q < nj; ++q) {
        F.srcSel[q] = par[q];
        F.srcOff[q] = par[q] ? bOff[q] : kOff[g][q];
        F.n[q] = (int)nCur[q];
        F.sIdx[q] = gs[q];
      }
      k_topk_fin<<<nj, TPB, 0, stream>>>(keys, scr, selk, F);
    }
    {
      GtP P; P.nj = nj;
      for (int q = 0; q < nj; ++q) {
        int s = gs[q];
        P.h3[q] = H3[s]; P.scalef[q] = (float)scl[s]; P.kOff[q] = kOff[g][q];
        P.sIdx[q] = s;
      }
      k_gather_job<<<2 * nj, TPB, 0, stream>>>(selk, ws + L.REG, boxes, P);
    }
  }

  // ---------------- per-scale NMS + fused final stage ----------------
  k_nms<<<nsc, TPB, 0, stream>>>(boxes, 512, 0.5f);

  int total = nsc * 512;
  k_final<<<1, 1024, 0, stream>>>(boxes, total, 0.7f, self, (float*)d_out);
}

// Round 19
// 998.508 us; speedup vs baseline: 1.2850x; 1.0172x over previous
//
#include <hip/hip_runtime.h>
#include <stdint.h>

typedef unsigned long long u64;
typedef unsigned int u32;

#define TPB 256
#define NJMAX 12
#define NSC 11

__device__ __forceinline__ int findJob(const int* cum, int nj, int v) {
  int j = 0;
  while (j + 1 < nj && v >= cum[j + 1]) ++j;
  return j;
}

// ---------------- resize weight tables (per scale, per output position) -----
// tW layout: TRANSPOSED [k][ox]: tW[wOff + k*nh + ox]  (coalesced lane reads)
struct MkP { int ns; int nw[NSC]; float invs[NSC], ks[NSC];
             int oxB[NSC], T[NSC], wOff[NSC]; };

__global__ void k_mkweights(int* __restrict__ tX0, int* __restrict__ tCNT,
                            float* __restrict__ tWT, float* __restrict__ tW, MkP P) {
  const int s = blockIdx.x;
  const int nw = P.nw[s];
  const float invs = P.invs[s], ks = P.ks[s];
  const int T = P.T[s];
  for (int ox = threadIdx.x; ox < nw; ox += TPB) {
    float sx = ((float)ox + 0.5f) * invs - 0.5f;
    int x0 = (int)ceilf(sx - ks); if (x0 < 0) x0 = 0;
    int x1 = (int)floorf(sx + ks); if (x1 > 767) x1 = 767;
    float wt = 0.f;
    float* wv = tW + P.wOff[s];
    for (int j = x0; j <= x1; ++j) {
      float w = fmaxf(0.f, 1.f - fabsf(sx - (float)j) / ks);
      wt += w;
      wv[(j - x0) * nw + ox] = w;
    }
    for (int k = x1 - x0 + 1; k < T; ++k) wv[k * nw + ox] = 0.f;
    int g = P.oxB[s] + ox;
    tX0[g] = x0; tCNT[g] = x1 - x0 + 1; tWT[g] = wt;
  }
}

// ---------------- descriptor builder (geometry-only, once per group) --------
struct DscP { int nj; int N[NJMAX]; int hOff[NJMAX], imgOff[NJMAX];
              int oxB[NJMAX], wOff[NJMAX];
              int cumW[NJMAX + 1], cumR[NJMAX + 1]; };

__global__ void k_mkdesc(int* __restrict__ hd, int* __restrict__ vd,
                         int hdcap, int vdcap, DscP P) {
  int gid = blockIdx.x * TPB + threadIdx.x;
  int totW = P.cumW[P.nj], totR = P.cumR[P.nj];
  if (gid < totW) {
    int j = findJob(P.cumW, P.nj, gid);
    int local = gid - P.cumW[j];
    int N = P.N[j];
    int ox = local % N, c = local / N;
    hd[gid]             = P.hOff[j] + c * 768 * N + ox;   // A
    hd[hdcap + gid]     = c * 769;                        // R (LDS row base)
    hd[2 * hdcap + gid] = N;                              // stride
    hd[3 * hdcap + gid] = P.oxB[j] + ox;                  // g
    hd[4 * hdcap + gid] = P.wOff[j] + ox;                 // W
  }
  if (gid < totR) {
    int j = findJob(P.cumR, P.nj, gid);
    int local = gid - P.cumR[j];
    int N = P.N[j];
    int oy = local % N, q = local / N;   // q = b*3+c in 0..23
    vd[gid]             = P.hOff[j] + q * 768 * N;        // S (src col base)
    vd[vdcap + gid]     = P.imgOff[j] + (q * N + oy) * N; // O (out row base)
    vd[2 * vdcap + gid] = P.oxB[j] + oy;                  // g
    vd[3 * vdcap + gid] = P.wOff[j] + oy;                 // W
    vd[4 * vdcap + gid] = N;                              // stride
  }
}

// ---------------- H pass: descriptor-driven, row-resident -------------------
__global__ void k_resizeH_d(const float* __restrict__ img, float* __restrict__ base,
                            const int* __restrict__ tX0, const int* __restrict__ tCNT,
                            const float* __restrict__ tWT, const float* __restrict__ tW,
                            const int* __restrict__ hd, int hdcap, int total) {
  __shared__ float row[3][769];
  const int y = blockIdx.x, b = blockIdx.y;
  const float* src = img + ((long)b * 768 + y) * 768 * 3;
  for (int t = threadIdx.x; t < 2304; t += TPB) {
    int x = t / 3, c = t - 3 * x;
    row[c][x] = src[t];
  }
  __syncthreads();
  const float* rowF = &row[0][0];
  const long yb = (long)y + 2304L * b;
  for (int t = threadIdx.x; t < total; t += TPB) {
    int A = hd[t];
    int R = hd[hdcap + t];
    int N = hd[2 * hdcap + t];
    int g = hd[3 * hdcap + t];
    int W = hd[4 * hdcap + t];
    int x0 = tX0[g], cnt = tCNT[g];
    float wt = tWT[g];
    const float* wv = tW + W;
    const float* rp = rowF + R + x0;
    float acc = 0.f;
    int k = 0;
    for (; k + 3 < cnt; k += 4) {
      float v0 = rp[k],     w0 = wv[(long)k * N];
      float v1 = rp[k + 1], w1 = wv[(long)(k + 1) * N];
      float v2 = rp[k + 2], w2 = wv[(long)(k + 2) * N];
      float v3 = rp[k + 3], w3 = wv[(long)(k + 3) * N];
      acc += v0 * w0; acc += v1 * w1; acc += v2 * w2; acc += v3 * w3;
    }
    for (; k < cnt; ++k) acc += rp[k] * wv[(long)k * N];
    base[(long)A + (long)N * yb] = acc / wt;
  }
}

// ---------------- V pass: one 64-lane wave per output row -------------------
__global__ void k_resizeV_row(const float* __restrict__ basep, float* __restrict__ img,
                              const int* __restrict__ tX0, const int* __restrict__ tCNT,
                              const float* __restrict__ tWT, const float* __restrict__ tW,
                              const int* __restrict__ vd, int vdcap, int nRows) {
  int row = blockIdx.x * 4 + (threadIdx.x >> 6);
  if (row >= nRows) return;
  int lane = threadIdx.x & 63;
  int S = vd[row];
  int O = vd[vdcap + row];
  int g = vd[2 * vdcap + row];
  int W = vd[3 * vdcap + row];
  int N = vd[4 * vdcap + row];
  int y0 = tX0[g], cnt = tCNT[g];
  float wt = tWT[g];
  const float* wv = tW + W;
  const float* col0 = basep + S + (long)y0 * N;
  for (int ox = lane; ox < N; ox += 64) {
    const float* col = col0 + ox;
    float acc = 0.f;
    int k = 0;
    for (; k + 3 < cnt; k += 4) {
      float v0 = col[(long)k * N],       w0 = wv[(long)k * N];
      float v1 = col[(long)(k + 1) * N], w1 = wv[(long)(k + 1) * N];
      float v2 = col[(long)(k + 2) * N], w2 = wv[(long)(k + 2) * N];
      float v3 = col[(long)(k + 3) * N], w3 = wv[(long)(k + 3) * N];
      acc += v0 * w0; acc += v1 * w1; acc += v2 * w2; acc += v3 * w3;
    }
    for (; k < cnt; ++k) acc += col[(long)k * N] * wv[(long)k * N];
    img[(long)O + ox] = (acc / wt - 127.5f) * 0.0078125f;
  }
}

// ---------------- fused conv1 + PReLU + 2x2 ceil-maxpool (all 10 co) --------
__device__ __forceinline__ void conv1pool_body(
    const float* in, const float* w, const float* bias, const float* pr,
    float* out, int H, int W, int b, int px, int py) {
  const int h1 = H - 2, w1 = W - 2;
  const int PH = (h1 + 1) >> 1, PW = (w1 + 1) >> 1;
  if (px >= PW || py >= PH) return;
  const int x0 = px * 2, y0 = py * 2;
  float a00[10], a01[10], a10[10], a11[10];
#pragma unroll
  for (int co = 0; co < 10; ++co) { a00[co] = 0.f; a01[co] = 0.f; a10[co] = 0.f; a11[co] = 0.f; }
  const long HW = (long)H * W;
  const float* pp = in + ((long)b * 3 * H + y0) * W + x0;
  for (int ci = 0; ci < 3; ++ci, pp += HW) {
    const float* r = pp;
    float r00 = r[0], r01 = r[1], r02 = r[2], r03 = r[3]; r += W;
    float r10 = r[0], r11 = r[1], r12 = r[2], r13 = r[3]; r += W;
    float r20 = r[0], r21 = r[1], r22 = r[2], r23 = r[3]; r += W;
    float r30 = r[0], r31 = r[1], r32 = r[2], r33 = r[3];
#pragma unroll
    for (int co = 0; co < 10; ++co) {
      const float* wc = w + ((long)co * 3 + ci) * 9;
      float w0 = wc[0], w1_ = wc[1], w2 = wc[2];
      float w3 = wc[3], w4 = wc[4], w5 = wc[5];
      float w6 = wc[6], w7 = wc[7], w8 = wc[8];
      a00[co] += r00 * w0 + r01 * w1_ + r02 * w2;
      a00[co] += r10 * w3 + r11 * w4 + r12 * w5;
      a00[co] += r20 * w6 + r21 * w7 + r22 * w8;
      a01[co] += r01 * w0 + r02 * w1_ + r03 * w2;
      a01[co] += r11 * w3 + r12 * w4 + r13 * w5;
      a01[co] += r21 * w6 + r22 * w7 + r23 * w8;
      a10[co] += r10 * w0 + r11 * w1_ + r12 * w2;
      a10[co] += r20 * w3 + r21 * w4 + r22 * w5;
      a10[co] += r30 * w6 + r31 * w7 + r32 * w8;
      a11[co] += r11 * w0 + r12 * w1_ + r13 * w2;
      a11[co] += r21 * w3 + r22 * w4 + r23 * w5;
      a11[co] += r31 * w6 + r32 * w7 + r33 * w8;
    }
  }
  const bool vx = (x0 + 1 < w1), vy = (y0 + 1 < h1);
#pragma unroll
  for (int co = 0; co < 10; ++co) {
    const float bb = bias[co], al = pr[co];
    float v = a00[co] + bb; v = v > 0.f ? v : al * v;
    float m = v;
    if (vx) { v = a01[co] + bb; v = v > 0.f ? v : al * v; m = fmaxf(m, v); }
    if (vy) { v = a10[co] + bb; v = v > 0.f ? v : al * v; m = fmaxf(m, v); }
    if (vx && vy) { v = a11[co] + bb; v = v > 0.f ? v : al * v; m = fmaxf(m, v); }
    out[(((long)b * 10 + co) * PH + py) * PW + px] = m;
  }
}

struct C1P { int nj; int nh[NJMAX]; int imgOff[NJMAX], poolOff[NJMAX];
             int t1x[NJMAX]; int cumT[NJMAX + 1]; };

__global__ void k_conv1pool_job(const float* __restrict__ imgb, const float* __restrict__ w,
                                const float* __restrict__ bias, const float* __restrict__ pr,
                                float* __restrict__ poolb, C1P P) {
  int j = findJob(P.cumT, P.nj, blockIdx.x);
  int local = blockIdx.x - P.cumT[j];
  int t1x = P.t1x[j];
  int tX = local % t1x, tY = local / t1x;
  conv1pool_body(imgb + P.imgOff[j], w, bias, pr, poolb + P.poolOff[j],
                 P.nh[j], P.nh[j], blockIdx.z,
                 tX * 16 + (threadIdx.x & 15), tY * 16 + (threadIdx.x >> 4));
}

// ---------------- co-blocked (8) tiled 3x3 conv + PReLU ---------------------
__device__ __forceinline__ void conv3x3c8_body(
    const float* in, const float* w, const float* bias, const float* pr,
    float* out, int Cin, int Cout, int H, int W, int cog, int b, int x0, int y) {
  const int OH = H - 2, OW = W - 2;
  if (y >= OH || x0 >= OW) return;
  float acc[8][4];
#pragma unroll
  for (int k = 0; k < 8; ++k) { acc[k][0] = 0.f; acc[k][1] = 0.f; acc[k][2] = 0.f; acc[k][3] = 0.f; }
  const float* wp = w + (long)cog * Cin * 9;
  const long HW = (long)H * W;
  const float* pp = in + ((long)b * Cin * H + y) * W + x0;
  for (int ci = 0; ci < Cin; ++ci, pp += HW) {
    const float* r = pp;
    float q00 = r[0], q01 = r[1], q02 = r[2], q03 = r[3], q04 = r[4], q05 = r[5]; r += W;
    float q10 = r[0], q11 = r[1], q12 = r[2], q13 = r[3], q14 = r[4], q15 = r[5]; r += W;
    float q20 = r[0], q21 = r[1], q22 = r[2], q23 = r[3], q24 = r[4], q25 = r[5];
#pragma unroll
    for (int k = 0; k < 8; ++k) {
      const float* wc = wp + ((long)k * Cin + ci) * 9;
      float w0 = wc[0], w1 = wc[1], w2 = wc[2];
      float w3 = wc[3], w4 = wc[4], w5 = wc[5];
      float w6 = wc[6], w7 = wc[7], w8 = wc[8];
      acc[k][0] += q00 * w0 + q01 * w1 + q02 * w2;
      acc[k][1] += q01 * w0 + q02 * w1 + q03 * w2;
      acc[k][2] += q02 * w0 + q03 * w1 + q04 * w2;
      acc[k][3] += q03 * w0 + q04 * w1 + q05 * w2;
      acc[k][0] += q10 * w3 + q11 * w4 + q12 * w5;
      acc[k][1] += q11 * w3 + q12 * w4 + q13 * w5;
      acc[k][2] += q12 * w3 + q13 * w4 + q14 * w5;
      acc[k][3] += q13 * w3 + q14 * w4 + q15 * w5;
      acc[k][0] += q20 * w6 + q21 * w7 + q22 * w8;
      acc[k][1] += q21 * w6 + q22 * w7 + q23 * w8;
      acc[k][2] += q22 * w6 + q23 * w7 + q24 * w8;
      acc[k][3] += q23 * w6 + q24 * w7 + q25 * w8;
    }
  }
  const int rem = OW - x0;
#pragma unroll
  for (int k = 0; k < 8; ++k) {
    const int co = cog + k;
    const float bb = bias[co], al = pr[co];
    float* op = out + (((long)b * Cout + co) * OH + y) * OW + x0;
    float v0 = acc[k][0] + bb; v0 = v0 > 0.f ? v0 : al * v0;
    op[0] = v0;
    if (rem > 1) { float v = acc[k][1] + bb; v = v > 0.f ? v : al * v; op[1] = v; }
    if (rem > 2) { float v = acc[k][2] + bb; v = v > 0.f ? v : al * v; op[2] = v; }
    if (rem > 3) { float v = acc[k][3] + bb; v = v > 0.f ? v : al * v; op[3] = v; }
  }
}

struct CvP { int nj; int H[NJMAX]; int inOff[NJMAX], outOff[NJMAX];
             int tx[NJMAX]; int cumT[NJMAX + 1]; };

__global__ void k_conv3x3c8_job(const float* __restrict__ inb, const float* __restrict__ w,
                                const float* __restrict__ bias, const float* __restrict__ pr,
                                float* __restrict__ outb, int Cin, int Cout, CvP P) {
  int j = findJob(P.cumT, P.nj, blockIdx.x);
  int local = blockIdx.x - P.cumT[j];
  int tx0 = P.tx[j];
  int tX = local % tx0, tY = local / tx0;
  conv3x3c8_body(inb + P.inOff[j], w, bias, pr, outb + P.outOff[j], Cin, Cout,
                 P.H[j], P.H[j], blockIdx.y * 8, blockIdx.z,
                 tX * 64 + (threadIdx.x & 15) * 4, tY * 16 + (threadIdx.x >> 4));
}

// ---------------- 1x1 heads -------------------------------------------------
__device__ __forceinline__ void head_body(const float* x3, const float* w41,
                                          const float* b41, const float* w42,
                                          const float* b42, float* reg, u64* keys,
                                          int plane, long idx) {
  int b = (int)(idx / plane); int rem = (int)(idx % plane);
  const float* p = x3 + (long)b * 32 * plane + rem;
  float l0 = 0.f, l1 = 0.f, r0 = 0.f, r1 = 0.f, r2 = 0.f, r3 = 0.f;
  for (int c = 0; c < 32; ++c) {
    float v = p[(long)c * plane];
    l0 += v * w41[c];      l1 += v * w41[32 + c];
    r0 += v * w42[c];      r1 += v * w42[32 + c];
    r2 += v * w42[64 + c]; r3 += v * w42[96 + c];
  }
  l0 += b41[0]; l1 += b41[1];
  r0 += b42[0]; r1 += b42[1]; r2 += b42[2]; r3 += b42[3];
  float mx = fmaxf(l0, l1);
  float e0 = expf(l0 - mx), e1 = expf(l1 - mx);
  float s = e1 / (e0 + e1);
  reg[idx * 4 + 0] = r0; reg[idx * 4 + 1] = r1;
  reg[idx * 4 + 2] = r2; reg[idx * 4 + 3] = r3;
  u32 ic = 0xFFFFFFFFu - (u32)idx;
  u64 k = (s >= 0.6f) ? ((((u64)__float_as_uint(s)) << 32) | ic) : (u64)ic;
  keys[idx] = k;
}

struct HdP { int nj; int h3[NJMAX]; int c3Off[NJMAX], kOff[NJMAX];
             int cumC[NJMAX + 1]; };

__global__ void k_head_job(const float* __restrict__ c3b, const float* __restrict__ w41,
                           const float* __restrict__ b41, const float* __restrict__ w42,
                           const float* __restrict__ b42, float* __restrict__ regb,
                           u64* __restrict__ keysb, HdP P) {
  int gid = blockIdx.x * TPB + threadIdx.x;
  if (gid >= P.cumC[P.nj]) return;
  int j = findJob(P.cumC, P.nj, gid);
  int idx = gid - P.cumC[j];
  head_body(c3b + P.c3Off[j], w41, b41, w42, b42,
            regb + 4L * P.kOff[j], keysb + P.kOff[j], P.h3[j] * P.h3[j], idx);
}

// ---------------- bitonic top-K ---------------------------------------------
__device__ __forceinline__ void bitonic2048(u64* s) {
  for (int k = 2; k <= 2048; k <<= 1) {
    for (int j = k >> 1; j > 0; j >>= 1) {
      for (int i = threadIdx.x; i < 2048; i += TPB) {
        int ixj = i ^ j;
        if (ixj > i) {
          u64 a = s[i], b = s[ixj];
          bool desc = ((i & k) == 0);
          if (desc ? (a < b) : (a > b)) { s[i] = b; s[ixj] = a; }
        }
      }
      __syncthreads();
    }
  }
}

struct TkP { int nj; int srcSel[NJMAX]; int srcOff[NJMAX]; int n[NJMAX];
             int dstOff[NJMAX]; int cumB[NJMAX + 1]; };

__global__ void k_topk_job(u64* __restrict__ A, u64* __restrict__ B, TkP P) {
  __shared__ u64 s[2048];
  int j = findJob(P.cumB, P.nj, blockIdx.x);
  int lb = blockIdx.x - P.cumB[j];
  const u64* src = (P.srcSel[j] ? B : A) + P.srcOff[j];
  u64* dst = (P.srcSel[j] ? A : B) + P.dstOff[j];
  int n = P.n[j];
  int base = lb * 2048;
  for (int t = threadIdx.x; t < 2048; t += TPB) {
    int gi = base + t;
    s[t] = (gi < n) ? src[gi] : 0ULL;
  }
  __syncthreads();
  bitonic2048(s);
  for (int t = threadIdx.x; t < 512; t += TPB)
    dst[(long)lb * 512 + t] = s[t];
}

struct TkFP { int nj; int srcSel[NJMAX]; int srcOff[NJMAX]; int n[NJMAX]; int sIdx[NJMAX]; };

__global__ void k_topk_fin(const u64* __restrict__ A, const u64* __restrict__ B,
                           u64* __restrict__ selk, TkFP P) {
  __shared__ u64 s[2048];
  int j = blockIdx.x;
  const u64* src = (P.srcSel[j] ? B : A) + P.srcOff[j];
  int n = P.n[j];
  for (int t = threadIdx.x; t < 2048; t += TPB)
    s[t] = (t < n) ? src[t] : 0ULL;
  __syncthreads();
  bitonic2048(s);
  for (int t = threadIdx.x; t < 512; t += TPB)
    selk[(long)P.sIdx[j] * 512 + t] = s[t];
}

// ---------------- gather box rows -------------------------------------------
__device__ __forceinline__ void gather_body(const u64* keys, const float* reg,
                                            float* boxes, int h, int w, float scalef,
                                            int i) {
  float* bx = boxes + (long)i * 12;
  u64 key = keys[i];
  if ((key >> 32) == 0ULL) {
    for (int q = 0; q < 12; ++q) bx[q] = 0.f;
    return;
  }
  u32 cell = 0xFFFFFFFFu - (u32)(key & 0xFFFFFFFFu);
  int x = (int)(cell % (u32)w); u32 t2 = cell / (u32)w;
  int y = (int)(t2 % (u32)h); int b = (int)(t2 / (u32)h);
  float fx = (float)x, fy = (float)y;
  bx[0] = floorf((2.f * fx + 1.f) / scalef);
  bx[1] = floorf((2.f * fy + 1.f) / scalef);
  bx[2] = floorf((2.f * fx + 12.f) / scalef);
  bx[3] = floorf((2.f * fy + 12.f) / scalef);
  bx[4] = __uint_as_float((u32)(key >> 32));
  bx[5] = reg[(long)cell * 4 + 0];
  bx[6] = reg[(long)cell * 4 + 1];
  bx[7] = reg[(long)cell * 4 + 2];
  bx[8] = reg[(long)cell * 4 + 3];
  bx[9] = (float)b;
  bx[10] = 1.f;
  bx[11] = 0.f;
}

struct GtP { int nj; int h3[NJMAX]; float scalef[NJMAX]; int kOff[NJMAX]; int sIdx[NJMAX]; };

__global__ void k_gather_job(const u64* __restrict__ selk, const float* __restrict__ regb,
                             float* __restrict__ boxes, GtP P) {
  int j = blockIdx.x >> 1;
  int i = ((blockIdx.x & 1) << 8) + threadIdx.x;
  gather_body(selk + (long)P.sIdx[j] * 512, regb + 4L * P.kOff[j],
              boxes + (long)P.sIdx[j] * 512 * 12, P.h3[j], P.h3[j], P.scalef[j], i);
}

// ---------------- greedy NMS, 64-wide batched (bit-exact) --------------------
__global__ void k_nms(float* __restrict__ boxes, int per, float thr) {
  __shared__ float sx1[1024], sy1[1024], sx2[1024], sy2[1024], sar[1024];
  __shared__ unsigned char kp[1024];
  __shared__ unsigned char kb[64];
  __shared__ int snv;
  float* bs = boxes + (long)blockIdx.x * per * 12;
  int N = per;
  if (threadIdx.x == 0) snv = 0;
  __syncthreads();
  for (int i = threadIdx.x; i < N; i += blockDim.x) {
    const float* b = bs + (long)i * 12;
    float off = b[9] * 100000.0f;
    float a0 = b[0] + off, a1 = b[1] + off, a2 = b[2] + off, a3 = b[3] + off;
    sx1[i] = a0; sy1[i] = a1; sx2[i] = a2; sy2[i] = a3;
    sar[i] = fmaxf(a2 - a0, 0.f) * fmaxf(a3 - a1, 0.f);
    bool v = (b[10] != 0.f);
    kp[i] = v;
    if (v) atomicMax(&snv, i + 1);
  }
  __syncthreads();
  int nv = snv;
  const int wave = threadIdx.x >> 6, lane = threadIdx.x & 63;
  for (int base = 0; base < nv; base += 64) {
    const int lim = (nv - base < 64) ? (nv - base) : 64;
    if (wave == 0) {
      int gi = base + lane;
      bool ok = (lane < lim) && kp[gi];
      float bx1 = 0.f, by1 = 0.f, bx2 = 0.f, by2 = 0.f, ba = 0.f;
      if (lane < lim) { bx1 = sx1[gi]; by1 = sy1[gi]; bx2 = sx2[gi]; by2 = sy2[gi]; ba = sar[gi]; }
      for (int i = 0; i < lim; ++i) {
        int ki = __shfl((int)ok, i);
        float xi1 = __shfl(bx1, i), yi1 = __shfl(by1, i);
        float xi2 = __shfl(bx2, i), yi2 = __shfl(by2, i);
        float ai = __shfl(ba, i);
        if (ki && lane > i && ok) {
          float iw = fmaxf(fminf(xi2, bx2) - fmaxf(xi1, bx1), 0.f);
          float ih = fmaxf(fminf(yi2, by2) - fmaxf(yi1, by1), 0.f);
          float inter = iw * ih;
          float iou = inter / (ai + ba - inter + 1e-9f);
          if (iou > thr) ok = false;
        }
      }
      if (lane < lim) kp[gi] = ok ? 1 : 0;
      kb[lane] = (lane < lim && ok) ? 1 : 0;
    }
    __syncthreads();
    for (int j = base + 64 + threadIdx.x; j < nv; j += blockDim.x) {
      if (!kp[j]) continue;
      float jx2 = sx2[j], jy2 = sy2[j], jx1 = sx1[j], jy1 = sy1[j], ja = sar[j];
      bool ok = true;
      for (int i = 0; i < lim && ok; ++i) {
        if (!kb[i]) continue;
        int gi = base + i;
        float iw = fmaxf(fminf(sx2[gi], jx2) - fmaxf(sx1[gi], jx1), 0.f);
        float ih = fmaxf(fminf(sy2[gi], jy2) - fmaxf(sy1[gi], jy1), 0.f);
        float inter = iw * ih;
        float iou = inter / (sar[gi] + ja - inter + 1e-9f);
        if (iou > thr) ok = false;
      }
      if (!ok) kp[j] = 0;
    }
    __syncthreads();
  }
  for (int i = threadIdx.x; i < N; i += blockDim.x)
    bs[(long)i * 12 + 11] = kp[i] ? 1.f : 0.f;
}

// ---------------- fused final stage: keys+sort+gather+NMS+refine, 1 block ----
__global__ void k_final(const float* __restrict__ boxes, int total, float thr,
                        float* __restrict__ selfb, float* __restrict__ out) {
  __shared__ u64 s[8192];
  __shared__ unsigned char kb[64];
  __shared__ int snv;
  float* fb = (float*)s;
  const int tid = threadIdx.x;   // 1024 threads
  // 1) build keys (identical to k_finalkeys)
  for (int i = tid; i < 8192; i += 1024) {
    u64 k = 0ULL;
    if (i < total) {
      const float* b = boxes + (long)i * 12;
      u32 ic = 0xFFFFFFFFu - (u32)i;
      k = (b[11] != 0.f) ? ((((u64)__float_as_uint(b[4])) << 32) | ic) : (u64)ic;
    }
    s[i] = k;
  }
  if (tid == 0) snv = 0;
  __syncthreads();
  // 2) full bitonic sort descending
  for (int k = 2; k <= 8192; k <<= 1) {
    for (int j = k >> 1; j > 0; j >>= 1) {
      for (int i = tid; i < 8192; i += 1024) {
        int ixj = i ^ j;
        if (ixj > i) {
          u64 a = s[i], b = s[ixj];
          bool desc = ((i & k) == 0);
          if (desc ? (a < b) : (a > b)) { s[i] = b; s[ixj] = a; }
        }
      }
      __syncthreads();
    }
  }
  // 3) consume top-1024 keys, then alias sort buffer as NMS arrays
  u64 myKey = s[tid];
  __syncthreads();
  float* sx1 = fb;
  float* sy1 = fb + 1024;
  float* sx2 = fb + 2048;
  float* sy2 = fb + 3072;
  float* sar = fb + 4096;
  unsigned char* kp = (unsigned char*)(fb + 5120);
  {
    int i = tid;
    float* o = selfb + (long)i * 12;
    if ((myKey >> 32) == 0ULL) {
      for (int q = 0; q < 12; ++q) o[q] = 0.f;
      sx1[i] = 0.f; sy1[i] = 0.f; sx2[i] = 0.f; sy2[i] = 0.f; sar[i] = 0.f;
      kp[i] = 0;
    } else {
      u32 bi = 0xFFFFFFFFu - (u32)(myKey & 0xFFFFFFFFu);
      const float* b = boxes + (long)bi * 12;
      float r0 = b[0], r1 = b[1], r2 = b[2], r3 = b[3], r4 = b[4];
      float r5 = b[5], r6 = b[6], r7 = b[7], r8 = b[8], r9 = b[9];
      o[0] = r0; o[1] = r1; o[2] = r2; o[3] = r3; o[4] = r4;
      o[5] = r5; o[6] = r6; o[7] = r7; o[8] = r8; o[9] = r9;
      o[10] = 1.f; o[11] = 0.f;
      float off = r9 * 100000.0f;
      float a0 = r0 + off, a1 = r1 + off, a2 = r2 + off, a3 = r3 + off;
      sx1[i] = a0; sy1[i] = a1; sx2[i] = a2; sy2[i] = a3;
      sar[i] = fmaxf(a2 - a0, 0.f) * fmaxf(a3 - a1, 0.f);
      kp[i] = 1;
      atomicMax(&snv, i + 1);
    }
  }
  __syncthreads();
  // 4) batched greedy NMS
  int nv = snv;
  const int wave = tid >> 6, lane = tid & 63;
  for (int base = 0; base < nv; base += 64) {
    const int lim = (nv - base < 64) ? (nv - base) : 64;
    if (wave == 0) {
      int gi = base + lane;
      bool ok = (lane < lim) && kp[gi];
      float bx1 = 0.f, by1 = 0.f, bx2 = 0.f, by2 = 0.f, ba = 0.f;
      if (lane < lim) { bx1 = sx1[gi]; by1 = sy1[gi]; bx2 = sx2[gi]; by2 = sy2[gi]; ba = sar[gi]; }
      for (int i = 0; i < lim; ++i) {
        int ki = __shfl((int)ok, i);
        float xi1 = __shfl(bx1, i), yi1 = __shfl(by1, i);
        float xi2 = __shfl(bx2, i), yi2 = __shfl(by2, i);
        float ai = __shfl(ba, i);
        if (ki && lane > i && ok) {
          float iw = fmaxf(fminf(xi2, bx2) - fmaxf(xi1, bx1), 0.f);
          float ih = fmaxf(fminf(yi2, by2) - fmaxf(yi1, by1), 0.f);
          float inter = iw * ih;
          float iou = inter / (ai + ba - inter + 1e-9f);
          if (iou > thr) ok = false;
        }
      }
      if (lane < lim) kp[gi] = ok ? 1 : 0;
      kb[lane] = (lane < lim && ok) ? 1 : 0;
    }
    __syncthreads();
    for (int j = base + 64 + tid; j < nv; j += blockDim.x) {
      if (!kp[j]) continue;
      float jx2 = sx2[j], jy2 = sy2[j], jx1 = sx1[j], jy1 = sy1[j], ja = sar[j];
      bool ok = true;
      for (int i = 0; i < lim && ok; ++i) {
        if (!kb[i]) continue;
        int gi = base + i;
        float iw = fmaxf(fminf(sx2[gi], jx2) - fmaxf(sx1[gi], jx1), 0.f);
        float ih = fmaxf(fminf(sy2[gi], jy2) - fmaxf(sy1[gi], jy1), 0.f);
        float inter = iw * ih;
        float iou = inter / (sar[gi] + ja - inter + 1e-9f);
        if (iou > thr) ok = false;
      }
      if (!ok) kp[j] = 0;
    }
    __syncthreads();
  }
  // 5) refine (keep = kp, same math as k_refine)
  {
    int i = tid;
    const float* b = selfb + (long)i * 12;
    float keep = kp[i] ? 1.f : 0.f;
    float x1 = b[0], y1 = b[1], x2 = b[2], y2 = b[3], sc = b[4];
    float rw = x2 - x1, rh = y2 - y1;
    float o0 = x1 + b[5] * rw;
    float o1 = y1 + b[6] * rh;
    float o2 = x2 + b[7] * rw;
    float o3 = y2 + b[8] * rh;
    float hh = o3 - o1, ww = o2 - o0;
    float l = fmaxf(hh, ww);
    float nx1 = o0 + ww * 0.5f - l * 0.5f;
    float ny1 = o1 + hh * 0.5f - l * 0.5f;
    out[(long)i * 5 + 0] = nx1 * keep;
    out[(long)i * 5 + 1] = ny1 * keep;
    out[(long)i * 5 + 2] = (nx1 + l) * keep;
    out[(long)i * 5 + 3] = (ny1 + l) * keep;
    out[(long)i * 5 + 4] = sc * keep;
  }
}

extern "C" void kernel_launch(void* const* d_in, const int* in_sizes, int n_in,
                              void* d_out, int out_size, void* d_ws, size_t ws_size,
                              hipStream_t stream) {
  (void)in_sizes; (void)n_in; (void)out_size;
  const float* images = (const float*)d_in[0];
  const float* c1w = (const float*)d_in[1];
  const float* c1b = (const float*)d_in[2];
  const float* p1  = (const float*)d_in[3];
  const float* c2w = (const float*)d_in[4];
  const float* c2b = (const float*)d_in[5];
  const float* p2  = (const float*)d_in[6];
  const float* c3w = (const float*)d_in[7];
  const float* c3b = (const float*)d_in[8];
  const float* p3  = (const float*)d_in[9];
  const float* w41 = (const float*)d_in[10];
  const float* b41 = (const float*)d_in[11];
  const float* w42 = (const float*)d_in[12];
  const float* b42 = (const float*)d_in[13];
  float* ws = (float*)d_ws;

  double scl[16]; int nsc = 0;
  {
    double m = 12.0 / 20.0;
    double ml = 768.0 * m;
    double si = m;
    while (ml >= 12.0) { scl[nsc++] = si; si *= 0.709; ml *= 0.709; }
  }

  auto cdiv = [](long a, long b) { return (int)((a + b - 1) / b); };

  // per-scale dims + weight-table geometry
  int NH[NSC], PH_[NSC], H2[NSC], H3[NSC], OXB[NSC], TT[NSC], WOFF[NSC];
  float INV[NSC], KSF[NSC];
  {
    int oxb = 0, woff = 0;
    for (int s = 0; s < nsc; ++s) {
      int nh = (int)(768.0 * scl[s] + 1.0);
      NH[s] = nh;
      PH_[s] = ((nh - 2) + 1) / 2;
      H2[s] = PH_[s] - 2;
      H3[s] = H2[s] - 2;
      double inv = 1.0 / (((double)nh) / 768.0);
      INV[s] = (float)inv;
      KSF[s] = (float)(inv > 1.0 ? inv : 1.0);
      TT[s] = (int)(2.0f * KSF[s]) + 2;
      OXB[s] = oxb; oxb += nh;
      WOFF[s] = woff; woff += nh * TT[s];
    }
  }

  // candidate groupings
  static const int GA[11] = {0, 1, 2, 3, 4, 5, 6, 7, 8, 9, 10};
  static const int G1[7] = {0, 5, 6, 7, 8, 9, 10};
  static const int G2[4] = {1, 2, 3, 4};

  struct Layout {
    long HT, IMG, POOL, C2, REG, KEYS, SCR, SEL, BOX, FK, FS, SF, TBL, HD, VD, extent;
    int hdcap, vdcap;
  };

  auto calcLayout = [&](const int* const* gps, const int* gn, int ng,
                        int hdcap, int vdcap, Layout& L) {
    long htA = 0, c3A = 0, imgA = 0, poolA = 0, c2A = 0, cellsA = 0, scrA = 0;
    for (int g = 0; g < ng; ++g) {
      long ht = 0, c3 = 0, im = 0, pl = 0, c2s = 0, ck = 0, sc = 0;
      for (int q = 0; q < gn[g]; ++q) {
        int s = gps[g][q];
        ht += 24L * 768 * NH[s];
        im += 24L * NH[s] * NH[s];
        pl += 80L * PH_[s] * PH_[s];
        c2s += 128L * H2[s] * H2[s];
        c3 += 256L * H3[s] * H3[s];
        long cells = 8L * H3[s] * H3[s];
        ck += cells;
        sc += 512L * ((cells + 2047) / 2048);
      }
      if (ht > htA) htA = ht; if (c3 > c3A) c3A = c3; if (im > imgA) imgA = im;
      if (pl > poolA) poolA = pl; if (c2s > c2A) c2A = c2s;
      if (ck > cellsA) cellsA = ck; if (sc > scrA) scrA = sc;
    }
    long htR = htA > c3A ? htA : c3A;
    auto al = [](long v) { return (v + 15) & ~15L; };
    long off = 0;
    L.HT = off;   off += al(htR);
    L.IMG = off;  off += al(imgA);
    L.POOL = off; off += al(poolA);
    L.C2 = off;   off += al(c2A);
    L.REG = off;  off += al(4 * cellsA);
    L.KEYS = off; off += al(2 * cellsA);
    L.SCR = off;  off += al(2 * scrA + 16384);
    L.SEL = off;  off += al(11264);
    L.BOX = off;  off += al(67584);
    L.FK = off;   off += al(16384);
    L.FS = off;   off += al(2048);
    L.SF = off;   off += al(12288);
    L.TBL = off;  off += al(12288 + 24000);
    L.HD = off;   off += al((long)ng * 5 * hdcap);
    L.VD = off;   off += al((long)ng * 5 * vdcap);
    L.extent = off;
    L.hdcap = hdcap; L.vdcap = vdcap;
  };

  Layout LA, LB;
  {
    const int* gpsA[1] = {GA}; int gnA[1] = {11};
    calcLayout(gpsA, gnA, 1, 8192, 56320, LA);
    const int* gpsB[2] = {G1, G2}; int gnB[2] = {7, 4};
    calcLayout(gpsB, gnB, 2, 2560, 20480, LB);
  }
  bool big = (ws_size >= (size_t)LA.extent * 4);
  const Layout& L = big ? LA : LB;
  const int* GS[2]; int GN[2]; int ngroups;
  if (big) { GS[0] = GA; GN[0] = 11; ngroups = 1; }
  else { GS[0] = G1; GN[0] = 7; GS[1] = G2; GN[1] = 4; ngroups = 2; }

  u64* keys  = (u64*)(ws + L.KEYS);
  u64* scr   = (u64*)(ws + L.SCR);
  u64* selk  = (u64*)(ws + L.SEL);
  float* boxes = ws + L.BOX;
  float* self  = ws + L.SF;
  int*   tX0  = (int*)(ws + L.TBL);
  int*   tCNT = (int*)(ws + L.TBL + 4096);
  float* tWT  = ws + L.TBL + 8192;
  float* tW   = ws + L.TBL + 12288;

  // build resize weight tables (once per launch)
  {
    MkP P; P.ns = nsc;
    for (int s = 0; s < nsc; ++s) {
      P.nw[s] = NH[s]; P.invs[s] = INV[s]; P.ks[s] = KSF[s];
      P.oxB[s] = OXB[s]; P.T[s] = TT[s]; P.wOff[s] = WOFF[s];
    }
    k_mkweights<<<nsc, TPB, 0, stream>>>(tX0, tCNT, tWT, tW, P);
  }

  // per-group geometry
  int imgOff[2][NJMAX], poolOff[2][NJMAX], c2Off[2][NJMAX], c3Off[2][NJMAX],
      htOff[2][NJMAX], kOff[2][NJMAX], cells[2][NJMAX];
  int cumWtot[2], cumRtot[2];
  for (int g = 0; g < ngroups; ++g) {
    long ch = 0, ci = 0, cp = 0, c2 = 0, c3 = 0, ck = 0;
    int cw = 0, cr = 0;
    for (int q = 0; q < GN[g]; ++q) {
      int s = GS[g][q];
      htOff[g][q] = (int)ch;  ch += 24L * 768 * NH[s];
      imgOff[g][q] = (int)ci; ci += 24L * NH[s] * NH[s];
      poolOff[g][q] = (int)cp; cp += 80L * PH_[s] * PH_[s];
      c2Off[g][q] = (int)c2;  c2 += 128L * H2[s] * H2[s];
      c3Off[g][q] = (int)c3;  c3 += 256L * H3[s] * H3[s];
      kOff[g][q] = (int)ck;   cells[g][q] = 8 * H3[s] * H3[s]; ck += cells[g][q];
      cw += 3 * NH[s]; cr += 24 * NH[s];
    }
    cumWtot[g] = cw; cumRtot[g] = cr;
  }

  // build H/V descriptors (geometry-only)
  for (int g = 0; g < ngroups; ++g) {
    DscP P; P.nj = GN[g];
    int cw = 0, cr = 0;
    for (int q = 0; q < GN[g]; ++q) {
      int s = GS[g][q];
      P.N[q] = NH[s]; P.hOff[q] = htOff[g][q]; P.imgOff[q] = imgOff[g][q];
      P.oxB[q] = OXB[s]; P.wOff[q] = WOFF[s];
      P.cumW[q] = cw; cw += 3 * NH[s];
      P.cumR[q] = cr; cr += 24 * NH[s];
    }
    P.cumW[GN[g]] = cw; P.cumR[GN[g]] = cr;
    int* hd = (int*)(ws + L.HD) + (long)g * 5 * L.hdcap;
    int* vd = (int*)(ws + L.VD) + (long)g * 5 * L.vdcap;
    int tot = cw > cr ? cw : cr;
    k_mkdesc<<<cdiv(tot, TPB), TPB, 0, stream>>>(hd, vd, L.hdcap, L.vdcap, P);
  }

  // ---------------- unified job pipeline over groups ----------------
  for (int g = 0; g < ngroups; ++g) {
    const int* gs = GS[g];
    int nj = GN[g];
    int* hd = (int*)(ws + L.HD) + (long)g * 5 * L.hdcap;
    int* vd = (int*)(ws + L.VD) + (long)g * 5 * L.vdcap;
    {
      dim3 gh(768, 8, 1);
      k_resizeH_d<<<gh, TPB, 0, stream>>>(images, ws + L.HT, tX0, tCNT, tWT, tW,
                                          hd, L.hdcap, cumWtot[g]);
    }
    k_resizeV_row<<<cdiv(cumRtot[g], 4), TPB, 0, stream>>>(
        ws + L.HT, ws + L.IMG, tX0, tCNT, tWT, tW, vd, L.vdcap, cumRtot[g]);
    {
      C1P P; P.nj = nj; int ct = 0;
      for (int q = 0; q < nj; ++q) {
        int s = gs[q];
        P.nh[q] = NH[s];
        P.imgOff[q] = imgOff[g][q]; P.poolOff[q] = poolOff[g][q];
        int t1x = cdiv(PH_[s], 16);
        P.t1x[q] = t1x;
        P.cumT[q] = ct; ct += t1x * t1x;
      }
      P.cumT[nj] = ct;
      dim3 gg(ct, 1, 8);
      k_conv1pool_job<<<gg, TPB, 0, stream>>>(ws + L.IMG, c1w, c1b, p1, ws + L.POOL, P);
    }
    {
      CvP P; P.nj = nj; int ct = 0;
      for (int q = 0; q < nj; ++q) {
        int s = gs[q];
        P.H[q] = PH_[s];
        P.inOff[q] = poolOff[g][q]; P.outOff[q] = c2Off[g][q];
        int tx = cdiv(H2[s], 64), ty = cdiv(H2[s], 16);
        P.tx[q] = tx;
        P.cumT[q] = ct; ct += tx * ty;
      }
      P.cumT[nj] = ct;
      dim3 gg(ct, 2, 8);
      k_conv3x3c8_job<<<gg, TPB, 0, stream>>>(ws + L.POOL, c2w, c2b, p2, ws + L.C2,
                                              10, 16, P);
    }
    {
      CvP P; P.nj = nj; int ct = 0;
      for (int q = 0; q < nj; ++q) {
        int s = gs[q];
        P.H[q] = H2[s];
        P.inOff[q] = c2Off[g][q]; P.outOff[q] = c3Off[g][q];
        int tx = cdiv(H3[s], 64), ty = cdiv(H3[s], 16);
        P.tx[q] = tx;
        P.cumT[q] = ct; ct += tx * ty;
      }
      P.cumT[nj] = ct;
      dim3 gg(ct, 4, 8);
      k_conv3x3c8_job<<<gg, TPB, 0, stream>>>(ws + L.C2, c3w, c3b, p3, ws + L.HT,
                                              16, 32, P);
    }
    {
      HdP P; P.nj = nj; int cc = 0;
      for (int q = 0; q < nj; ++q) {
        int s = gs[q];
        P.h3[q] = H3[s];
        P.c3Off[q] = c3Off[g][q]; P.kOff[q] = kOff[g][q];
        P.cumC[q] = cc; cc += cells[g][q];
      }
      P.cumC[nj] = cc;
      k_head_job<<<cdiv(cc, TPB), TPB, 0, stream>>>(ws + L.HT, w41, b41, w42, b42,
                                                    ws + L.REG, keys, P);
    }
    {
      int bOff[NJMAX];
      {
        int c = 0;
        for (int q = 0; q < nj; ++q) { bOff[q] = c; c += 512 * cdiv(cells[g][q], 2048); }
      }
      long nCur[NJMAX]; int par[NJMAX];
      for (int q = 0; q < nj; ++q) { nCur[q] = cells[g][q]; par[q] = 0; }
      while (true) {
        TkP P; P.nj = 0; int cum = 0; int act[NJMAX];
        for (int q = 0; q < nj; ++q) {
          if (nCur[q] > 2048) {
            int r = P.nj++;
            act[r] = q;
            int blocks = cdiv(nCur[q], 2048);
            P.srcSel[r] = par[q];
            P.srcOff[r] = par[q] ? bOff[q] : kOff[g][q];
            P.dstOff[r] = par[q] ? kOff[g][q] : bOff[q];
            P.n[r] = (int)nCur[q];
            P.cumB[r] = cum; cum += blocks;
          }
        }
        P.cumB[P.nj] = cum;
        if (P.nj == 0) break;
        k_topk_job<<<cum, TPB, 0, stream>>>(keys, scr, P);
        for (int r = 0; r < P.nj; ++r) {
          int q = act[r];
          nCur[q] = 512L * cdiv(nCur[q], 2048);
          par[q] ^= 1;
        }
      }
      TkFP F; F.nj = nj;
      for (int q = 0; q < nj; ++q) {
        F.srcSel[q] = par[q];
        F.srcOff[q] = par[q] ? bOff[q] : kOff[g][q];
        F.n[q] = (int)nCur[q];
        F.sIdx[q] = gs[q];
      }
      k_topk_fin<<<nj, TPB, 0, stream>>>(keys, scr, selk, F);
    }
    {
      GtP P; P.nj = nj;
      for (int q = 0; q < nj; ++q) {
        int s = gs[q];
        P.h3[q] = H3[s]; P.scalef[q] = (float)scl[s]; P.kOff[q] = kOff[g][q];
        P.sIdx[q] = s;
      }
      k_gather_job<<<2 * nj, TPB, 0, stream>>>(selk, ws + L.REG, boxes, P);
    }
  }

  // ---------------- per-scale NMS + fused final stage ----------------
  k_nms<<<nsc, TPB, 0, stream>>>(boxes, 512, 0.5f);

  int total = nsc * 512;
  k_final<<<1, 1024, 0, stream>>>(boxes, total, 0.7f, self, (float*)d_out);
}

// Round 20
// 944.251 us; speedup vs baseline: 1.3588x; 1.0575x over previous
//
#include <hip/hip_runtime.h>
#include <stdint.h>

typedef unsigned long long u64;
typedef unsigned int u32;

#define TPB 256
#define NJMAX 12
#define NSC 11

__device__ __forceinline__ int findJob(const int* cum, int nj, int v) {
  int j = 0;
  while (j + 1 < nj && v >= cum[j + 1]) ++j;
  return j;
}

// ---------------- resize weight tables (per scale, per output position) -----
struct MkP { int ns; int nw[NSC]; float invs[NSC], ks[NSC];
             int oxB[NSC], T[NSC], wOff[NSC]; };

__global__ void k_mkweights(int* __restrict__ tX0, int* __restrict__ tCNT,
                            float* __restrict__ tWT, float* __restrict__ tW, MkP P) {
  const int s = blockIdx.x;
  const int nw = P.nw[s];
  const float invs = P.invs[s], ks = P.ks[s];
  const int T = P.T[s];
  for (int ox = threadIdx.x; ox < nw; ox += TPB) {
    float sx = ((float)ox + 0.5f) * invs - 0.5f;
    int x0 = (int)ceilf(sx - ks); if (x0 < 0) x0 = 0;
    int x1 = (int)floorf(sx + ks); if (x1 > 767) x1 = 767;
    float wt = 0.f;
    float* wv = tW + P.wOff[s];
    for (int j = x0; j <= x1; ++j) {
      float w = fmaxf(0.f, 1.f - fabsf(sx - (float)j) / ks);
      wt += w;
      wv[(j - x0) * nw + ox] = w;
    }
    for (int k = x1 - x0 + 1; k < T; ++k) wv[k * nw + ox] = 0.f;
    int g = P.oxB[s] + ox;
    tX0[g] = x0; tCNT[g] = x1 - x0 + 1; tWT[g] = wt;
  }
}

// ---------------- descriptor builder (geometry-only, once per group) --------
struct DscP { int nj; int N[NJMAX]; int hOff[NJMAX], imgOff[NJMAX];
              int oxB[NJMAX], wOff[NJMAX];
              int cumW[NJMAX + 1], cumR[NJMAX + 1]; };

__global__ void k_mkdesc(int* __restrict__ hd, int* __restrict__ vd,
                         int hdcap, int vdcap, DscP P) {
  int gid = blockIdx.x * TPB + threadIdx.x;
  int totW = P.cumW[P.nj], totR = P.cumR[P.nj];
  if (gid < totW) {
    int j = findJob(P.cumW, P.nj, gid);
    int local = gid - P.cumW[j];
    int N = P.N[j];
    int ox = local % N, c = local / N;
    hd[gid]             = P.hOff[j] + c * 768 * N + ox;   // A
    hd[hdcap + gid]     = c * 769;                        // R (LDS row base)
    hd[2 * hdcap + gid] = N;                              // stride
    hd[3 * hdcap + gid] = P.oxB[j] + ox;                  // g
    hd[4 * hdcap + gid] = P.wOff[j] + ox;                 // W
  }
  if (gid < totR) {
    int j = findJob(P.cumR, P.nj, gid);
    int local = gid - P.cumR[j];
    int N = P.N[j];
    int oy = local % N, q = local / N;   // q = b*3+c in 0..23
    vd[gid]             = P.hOff[j] + q * 768 * N;        // S (src col base)
    vd[vdcap + gid]     = P.imgOff[j] + (q * N + oy) * N; // O (out row base)
    vd[2 * vdcap + gid] = P.oxB[j] + oy;                  // g
    vd[3 * vdcap + gid] = P.wOff[j] + oy;                 // W
    vd[4 * vdcap + gid] = N;                              // stride
  }
}

// ---------------- H pass: descriptor-driven, row-resident -------------------
__global__ void k_resizeH_d(const float* __restrict__ img, float* __restrict__ base,
                            const int* __restrict__ tX0, const int* __restrict__ tCNT,
                            const float* __restrict__ tWT, const float* __restrict__ tW,
                            const int* __restrict__ hd, int hdcap, int total) {
  __shared__ float row[3][769];
  const int y = blockIdx.x, b = blockIdx.y;
  const float* src = img + ((long)b * 768 + y) * 768 * 3;
  for (int t = threadIdx.x; t < 2304; t += TPB) {
    int x = t / 3, c = t - 3 * x;
    row[c][x] = src[t];
  }
  __syncthreads();
  const float* rowF = &row[0][0];
  const long yb = (long)y + 2304L * b;
  for (int t = threadIdx.x; t < total; t += TPB) {
    int A = hd[t];
    int R = hd[hdcap + t];
    int N = hd[2 * hdcap + t];
    int g = hd[3 * hdcap + t];
    int W = hd[4 * hdcap + t];
    int x0 = tX0[g], cnt = tCNT[g];
    float wt = tWT[g];
    const float* wv = tW + W;
    const float* rp = rowF + R + x0;
    float acc = 0.f;
    int k = 0;
    for (; k + 3 < cnt; k += 4) {
      float v0 = rp[k],     w0 = wv[(long)k * N];
      float v1 = rp[k + 1], w1 = wv[(long)(k + 1) * N];
      float v2 = rp[k + 2], w2 = wv[(long)(k + 2) * N];
      float v3 = rp[k + 3], w3 = wv[(long)(k + 3) * N];
      acc += v0 * w0; acc += v1 * w1; acc += v2 * w2; acc += v3 * w3;
    }
    for (; k < cnt; ++k) acc += rp[k] * wv[(long)k * N];
    base[(long)A + (long)N * yb] = acc / wt;
  }
}

// ---------------- V pass: one 64-lane wave per output row -------------------
__global__ void k_resizeV_row(const float* __restrict__ basep, float* __restrict__ img,
                              const int* __restrict__ tX0, const int* __restrict__ tCNT,
                              const float* __restrict__ tWT, const float* __restrict__ tW,
                              const int* __restrict__ vd, int vdcap, int nRows) {
  int row = blockIdx.x * 4 + (threadIdx.x >> 6);
  if (row >= nRows) return;
  int lane = threadIdx.x & 63;
  int S = vd[row];
  int O = vd[vdcap + row];
  int g = vd[2 * vdcap + row];
  int W = vd[3 * vdcap + row];
  int N = vd[4 * vdcap + row];
  int y0 = tX0[g], cnt = tCNT[g];
  float wt = tWT[g];
  const float* wv = tW + W;
  const float* col0 = basep + S + (long)y0 * N;
  for (int ox = lane; ox < N; ox += 64) {
    const float* col = col0 + ox;
    float acc = 0.f;
    int k = 0;
    for (; k + 3 < cnt; k += 4) {
      float v0 = col[(long)k * N],       w0 = wv[(long)k * N];
      float v1 = col[(long)(k + 1) * N], w1 = wv[(long)(k + 1) * N];
      float v2 = col[(long)(k + 2) * N], w2 = wv[(long)(k + 2) * N];
      float v3 = col[(long)(k + 3) * N], w3 = wv[(long)(k + 3) * N];
      acc += v0 * w0; acc += v1 * w1; acc += v2 * w2; acc += v3 * w3;
    }
    for (; k < cnt; ++k) acc += col[(long)k * N] * wv[(long)k * N];
    img[(long)O + ox] = (acc / wt - 127.5f) * 0.0078125f;
  }
}

// ---------------- fused conv1 + PReLU + 2x2 ceil-maxpool (all 10 co) --------
__device__ __forceinline__ void conv1pool_body(
    const float* in, const float* w, const float* bias, const float* pr,
    float* out, int H, int W, int b, int px, int py) {
  const int h1 = H - 2, w1 = W - 2;
  const int PH = (h1 + 1) >> 1, PW = (w1 + 1) >> 1;
  if (px >= PW || py >= PH) return;
  const int x0 = px * 2, y0 = py * 2;
  float a00[10], a01[10], a10[10], a11[10];
#pragma unroll
  for (int co = 0; co < 10; ++co) { a00[co] = 0.f; a01[co] = 0.f; a10[co] = 0.f; a11[co] = 0.f; }
  const long HW = (long)H * W;
  const float* pp = in + ((long)b * 3 * H + y0) * W + x0;
  for (int ci = 0; ci < 3; ++ci, pp += HW) {
    const float* r = pp;
    float r00 = r[0], r01 = r[1], r02 = r[2], r03 = r[3]; r += W;
    float r10 = r[0], r11 = r[1], r12 = r[2], r13 = r[3]; r += W;
    float r20 = r[0], r21 = r[1], r22 = r[2], r23 = r[3]; r += W;
    float r30 = r[0], r31 = r[1], r32 = r[2], r33 = r[3];
#pragma unroll
    for (int co = 0; co < 10; ++co) {
      const float* wc = w + ((long)co * 3 + ci) * 9;
      float w0 = wc[0], w1_ = wc[1], w2 = wc[2];
      float w3 = wc[3], w4 = wc[4], w5 = wc[5];
      float w6 = wc[6], w7 = wc[7], w8 = wc[8];
      a00[co] += r00 * w0 + r01 * w1_ + r02 * w2;
      a00[co] += r10 * w3 + r11 * w4 + r12 * w5;
      a00[co] += r20 * w6 + r21 * w7 + r22 * w8;
      a01[co] += r01 * w0 + r02 * w1_ + r03 * w2;
      a01[co] += r11 * w3 + r12 * w4 + r13 * w5;
      a01[co] += r21 * w6 + r22 * w7 + r23 * w8;
      a10[co] += r10 * w0 + r11 * w1_ + r12 * w2;
      a10[co] += r20 * w3 + r21 * w4 + r22 * w5;
      a10[co] += r30 * w6 + r31 * w7 + r32 * w8;
      a11[co] += r11 * w0 + r12 * w1_ + r13 * w2;
      a11[co] += r21 * w3 + r22 * w4 + r23 * w5;
      a11[co] += r31 * w6 + r32 * w7 + r33 * w8;
    }
  }
  const bool vx = (x0 + 1 < w1), vy = (y0 + 1 < h1);
#pragma unroll
  for (int co = 0; co < 10; ++co) {
    const float bb = bias[co], al = pr[co];
    float v = a00[co] + bb; v = v > 0.f ? v : al * v;
    float m = v;
    if (vx) { v = a01[co] + bb; v = v > 0.f ? v : al * v; m = fmaxf(m, v); }
    if (vy) { v = a10[co] + bb; v = v > 0.f ? v : al * v; m = fmaxf(m, v); }
    if (vx && vy) { v = a11[co] + bb; v = v > 0.f ? v : al * v; m = fmaxf(m, v); }
    out[(((long)b * 10 + co) * PH + py) * PW + px] = m;
  }
}

struct C1P { int nj; int nh[NJMAX]; int imgOff[NJMAX], poolOff[NJMAX];
             int t1x[NJMAX]; int cumT[NJMAX + 1]; };

__global__ void k_conv1pool_job(const float* __restrict__ imgb, const float* __restrict__ w,
                                const float* __restrict__ bias, const float* __restrict__ pr,
                                float* __restrict__ poolb, C1P P) {
  int j = findJob(P.cumT, P.nj, blockIdx.x);
  int local = blockIdx.x - P.cumT[j];
  int t1x = P.t1x[j];
  int tX = local % t1x, tY = local / t1x;
  conv1pool_body(imgb + P.imgOff[j], w, bias, pr, poolb + P.poolOff[j],
                 P.nh[j], P.nh[j], blockIdx.z,
                 tX * 16 + (threadIdx.x & 15), tY * 16 + (threadIdx.x >> 4));
}

// ---------------- co-blocked (8) tiled 3x3 conv + PReLU ---------------------
__device__ __forceinline__ void conv3x3c8_body(
    const float* in, const float* w, const float* bias, const float* pr,
    float* out, int Cin, int Cout, int H, int W, int cog, int b, int x0, int y) {
  const int OH = H - 2, OW = W - 2;
  if (y >= OH || x0 >= OW) return;
  float acc[8][4];
#pragma unroll
  for (int k = 0; k < 8; ++k) { acc[k][0] = 0.f; acc[k][1] = 0.f; acc[k][2] = 0.f; acc[k][3] = 0.f; }
  const float* wp = w + (long)cog * Cin * 9;
  const long HW = (long)H * W;
  const float* pp = in + ((long)b * Cin * H + y) * W + x0;
  for (int ci = 0; ci < Cin; ++ci, pp += HW) {
    const float* r = pp;
    float q00 = r[0], q01 = r[1], q02 = r[2], q03 = r[3], q04 = r[4], q05 = r[5]; r += W;
    float q10 = r[0], q11 = r[1], q12 = r[2], q13 = r[3], q14 = r[4], q15 = r[5]; r += W;
    float q20 = r[0], q21 = r[1], q22 = r[2], q23 = r[3], q24 = r[4], q25 = r[5];
#pragma unroll
    for (int k = 0; k < 8; ++k) {
      const float* wc = wp + ((long)k * Cin + ci) * 9;
      float w0 = wc[0], w1 = wc[1], w2 = wc[2];
      float w3 = wc[3], w4 = wc[4], w5 = wc[5];
      float w6 = wc[6], w7 = wc[7], w8 = wc[8];
      acc[k][0] += q00 * w0 + q01 * w1 + q02 * w2;
      acc[k][1] += q01 * w0 + q02 * w1 + q03 * w2;
      acc[k][2] += q02 * w0 + q03 * w1 + q04 * w2;
      acc[k][3] += q03 * w0 + q04 * w1 + q05 * w2;
      acc[k][0] += q10 * w3 + q11 * w4 + q12 * w5;
      acc[k][1] += q11 * w3 + q12 * w4 + q13 * w5;
      acc[k][2] += q12 * w3 + q13 * w4 + q14 * w5;
      acc[k][3] += q13 * w3 + q14 * w4 + q15 * w5;
      acc[k][0] += q20 * w6 + q21 * w7 + q22 * w8;
      acc[k][1] += q21 * w6 + q22 * w7 + q23 * w8;
      acc[k][2] += q22 * w6 + q23 * w7 + q24 * w8;
      acc[k][3] += q23 * w6 + q24 * w7 + q25 * w8;
    }
  }
  const int rem = OW - x0;
#pragma unroll
  for (int k = 0; k < 8; ++k) {
    const int co = cog + k;
    const float bb = bias[co], al = pr[co];
    float* op = out + (((long)b * Cout + co) * OH + y) * OW + x0;
    float v0 = acc[k][0] + bb; v0 = v0 > 0.f ? v0 : al * v0;
    op[0] = v0;
    if (rem > 1) { float v = acc[k][1] + bb; v = v > 0.f ? v : al * v; op[1] = v; }
    if (rem > 2) { float v = acc[k][2] + bb; v = v > 0.f ? v : al * v; op[2] = v; }
    if (rem > 3) { float v = acc[k][3] + bb; v = v > 0.f ? v : al * v; op[3] = v; }
  }
}

struct CvP { int nj; int H[NJMAX]; int inOff[NJMAX], outOff[NJMAX];
             int tx[NJMAX]; int cumT[NJMAX + 1]; };

__global__ void k_conv3x3c8_job(const float* __restrict__ inb, const float* __restrict__ w,
                                const float* __restrict__ bias, const float* __restrict__ pr,
                                float* __restrict__ outb, int Cin, int Cout, CvP P) {
  int j = findJob(P.cumT, P.nj, blockIdx.x);
  int local = blockIdx.x - P.cumT[j];
  int tx0 = P.tx[j];
  int tX = local % tx0, tY = local / tx0;
  conv3x3c8_body(inb + P.inOff[j], w, bias, pr, outb + P.outOff[j], Cin, Cout,
                 P.H[j], P.H[j], blockIdx.y * 8, blockIdx.z,
                 tX * 64 + (threadIdx.x & 15) * 4, tY * 16 + (threadIdx.x >> 4));
}

// ---------------- 1x1 heads -------------------------------------------------
__device__ __forceinline__ void head_body(const float* x3, const float* w41,
                                          const float* b41, const float* w42,
                                          const float* b42, float* reg, u64* keys,
                                          int plane, long idx) {
  int b = (int)(idx / plane); int rem = (int)(idx % plane);
  const float* p = x3 + (long)b * 32 * plane + rem;
  float l0 = 0.f, l1 = 0.f, r0 = 0.f, r1 = 0.f, r2 = 0.f, r3 = 0.f;
  for (int c = 0; c < 32; ++c) {
    float v = p[(long)c * plane];
    l0 += v * w41[c];      l1 += v * w41[32 + c];
    r0 += v * w42[c];      r1 += v * w42[32 + c];
    r2 += v * w42[64 + c]; r3 += v * w42[96 + c];
  }
  l0 += b41[0]; l1 += b41[1];
  r0 += b42[0]; r1 += b42[1]; r2 += b42[2]; r3 += b42[3];
  float mx = fmaxf(l0, l1);
  float e0 = expf(l0 - mx), e1 = expf(l1 - mx);
  float s = e1 / (e0 + e1);
  reg[idx * 4 + 0] = r0; reg[idx * 4 + 1] = r1;
  reg[idx * 4 + 2] = r2; reg[idx * 4 + 3] = r3;
  u32 ic = 0xFFFFFFFFu - (u32)idx;
  u64 k = (s >= 0.6f) ? ((((u64)__float_as_uint(s)) << 32) | ic) : (u64)ic;
  keys[idx] = k;
}

struct HdP { int nj; int h3[NJMAX]; int c3Off[NJMAX], kOff[NJMAX];
             int cumC[NJMAX + 1]; };

__global__ void k_head_job(const float* __restrict__ c3b, const float* __restrict__ w41,
                           const float* __restrict__ b41, const float* __restrict__ w42,
                           const float* __restrict__ b42, float* __restrict__ regb,
                           u64* __restrict__ keysb, HdP P) {
  int gid = blockIdx.x * TPB + threadIdx.x;
  if (gid >= P.cumC[P.nj]) return;
  int j = findJob(P.cumC, P.nj, gid);
  int idx = gid - P.cumC[j];
  head_body(c3b + P.c3Off[j], w41, b41, w42, b42,
            regb + 4L * P.kOff[j], keysb + P.kOff[j], P.h3[j] * P.h3[j], idx);
}

// ---------------- bitonic sorters -------------------------------------------
__device__ __forceinline__ void bitonic2048(u64* s) {
  for (int k = 2; k <= 2048; k <<= 1) {
    for (int j = k >> 1; j > 0; j >>= 1) {
      for (int i = threadIdx.x; i < 2048; i += TPB) {
        int ixj = i ^ j;
        if (ixj > i) {
          u64 a = s[i], b = s[ixj];
          bool desc = ((i & k) == 0);
          if (desc ? (a < b) : (a > b)) { s[i] = b; s[ixj] = a; }
        }
      }
      __syncthreads();
    }
  }
}

// 8192-chunk tournament round: sort chunk, keep top-512 (1024 threads)
struct TkP { int nj; int srcSel[NJMAX]; int srcOff[NJMAX]; int n[NJMAX];
             int dstOff[NJMAX]; int cumB[NJMAX + 1]; };

__global__ __launch_bounds__(1024) void k_topk_job8(u64* __restrict__ A,
                                                    u64* __restrict__ B, TkP P) {
  __shared__ u64 s[8192];
  int j = findJob(P.cumB, P.nj, blockIdx.x);
  int lb = blockIdx.x - P.cumB[j];
  const u64* src = (P.srcSel[j] ? B : A) + P.srcOff[j];
  u64* dst = (P.srcSel[j] ? A : B) + P.dstOff[j];
  int n = P.n[j];
  int base = lb * 8192;
  for (int t = threadIdx.x; t < 8192; t += 1024) {
    int gi = base + t;
    s[t] = (gi < n) ? src[gi] : 0ULL;
  }
  __syncthreads();
  for (int k = 2; k <= 8192; k <<= 1) {
    for (int jj = k >> 1; jj > 0; jj >>= 1) {
      for (int i = threadIdx.x; i < 8192; i += 1024) {
        int ixj = i ^ jj;
        if (ixj > i) {
          u64 a = s[i], b = s[ixj];
          bool desc = ((i & k) == 0);
          if (desc ? (a < b) : (a > b)) { s[i] = b; s[ixj] = a; }
        }
      }
      __syncthreads();
    }
  }
  for (int t = threadIdx.x; t < 512; t += 1024)
    dst[(long)lb * 512 + t] = s[t];
}

// ---------------- fused tail: final sort + gather + per-scale NMS -----------
struct TlP { int nj; int srcSel[NJMAX]; int srcOff[NJMAX]; int n[NJMAX];
             int sIdx[NJMAX]; int h3[NJMAX]; float scalef[NJMAX]; int kOff[NJMAX]; };

__global__ void k_tail(const u64* __restrict__ A, const u64* __restrict__ B,
                       const float* __restrict__ regb, float* __restrict__ boxes,
                       float thr, TlP P) {
  __shared__ u64 s[2048];
  __shared__ float sx1[512], sy1[512], sx2[512], sy2[512], sar[512];
  __shared__ unsigned char kp[512];
  __shared__ unsigned char kb[64];
  __shared__ int snv;
  const int j = blockIdx.x;
  const u64* src = (P.srcSel[j] ? B : A) + P.srcOff[j];
  int n = P.n[j];
  for (int t = threadIdx.x; t < 2048; t += TPB)
    s[t] = (t < n) ? src[t] : 0ULL;
  if (threadIdx.x == 0) snv = 0;
  __syncthreads();
  bitonic2048(s);
  // gather top-512 boxes + build NMS arrays (math identical to gather_body/k_nms)
  float* bset = boxes + (long)P.sIdx[j] * 512 * 12;
  const int h = P.h3[j];
  const float scalef = P.scalef[j];
  const float* reg = regb + 4L * P.kOff[j];
  for (int i = threadIdx.x; i < 512; i += TPB) {
    u64 key = s[i];
    float* bx = bset + (long)i * 12;
    if ((key >> 32) == 0ULL) {
      for (int q = 0; q < 12; ++q) bx[q] = 0.f;
      sx1[i] = 0.f; sy1[i] = 0.f; sx2[i] = 0.f; sy2[i] = 0.f; sar[i] = 0.f;
      kp[i] = 0;
    } else {
      u32 cell = 0xFFFFFFFFu - (u32)(key & 0xFFFFFFFFu);
      int x = (int)(cell % (u32)h); u32 t2 = cell / (u32)h;
      int y = (int)(t2 % (u32)h); int b = (int)(t2 / (u32)h);
      float fx = (float)x, fy = (float)y;
      float b0 = floorf((2.f * fx + 1.f) / scalef);
      float b1 = floorf((2.f * fy + 1.f) / scalef);
      float b2 = floorf((2.f * fx + 12.f) / scalef);
      float b3 = floorf((2.f * fy + 12.f) / scalef);
      float b4 = __uint_as_float((u32)(key >> 32));
      float b9 = (float)b;
      bx[0] = b0; bx[1] = b1; bx[2] = b2; bx[3] = b3; bx[4] = b4;
      bx[5] = reg[(long)cell * 4 + 0];
      bx[6] = reg[(long)cell * 4 + 1];
      bx[7] = reg[(long)cell * 4 + 2];
      bx[8] = reg[(long)cell * 4 + 3];
      bx[9] = b9; bx[10] = 1.f; bx[11] = 0.f;
      float off = b9 * 100000.0f;
      float a0 = b0 + off, a1 = b1 + off, a2 = b2 + off, a3 = b3 + off;
      sx1[i] = a0; sy1[i] = a1; sx2[i] = a2; sy2[i] = a3;
      sar[i] = fmaxf(a2 - a0, 0.f) * fmaxf(a3 - a1, 0.f);
      kp[i] = 1;
      atomicMax(&snv, i + 1);   // valid keys sort before invalid -> prefix
    }
  }
  __syncthreads();
  // batched greedy NMS (identical structure to proven k_nms)
  int nv = snv;
  const int wave = threadIdx.x >> 6, lane = threadIdx.x & 63;
  for (int base = 0; base < nv; base += 64) {
    const int lim = (nv - base < 64) ? (nv - base) : 64;
    if (wave == 0) {
      int gi = base + lane;
      bool ok = (lane < lim) && kp[gi];
      float bx1 = 0.f, by1 = 0.f, bx2 = 0.f, by2 = 0.f, ba = 0.f;
      if (lane < lim) { bx1 = sx1[gi]; by1 = sy1[gi]; bx2 = sx2[gi]; by2 = sy2[gi]; ba = sar[gi]; }
      for (int i = 0; i < lim; ++i) {
        int ki = __shfl((int)ok, i);
        float xi1 = __shfl(bx1, i), yi1 = __shfl(by1, i);
        float xi2 = __shfl(bx2, i), yi2 = __shfl(by2, i);
        float ai = __shfl(ba, i);
        if (ki && lane > i && ok) {
          float iw = fmaxf(fminf(xi2, bx2) - fmaxf(xi1, bx1), 0.f);
          float ih = fmaxf(fminf(yi2, by2) - fmaxf(yi1, by1), 0.f);
          float inter = iw * ih;
          float iou = inter / (ai + ba - inter + 1e-9f);
          if (iou > thr) ok = false;
        }
      }
      if (lane < lim) kp[gi] = ok ? 1 : 0;
      kb[lane] = (lane < lim && ok) ? 1 : 0;
    }
    __syncthreads();
    for (int jj = base + 64 + threadIdx.x; jj < nv; jj += blockDim.x) {
      if (!kp[jj]) continue;
      float jx2 = sx2[jj], jy2 = sy2[jj], jx1 = sx1[jj], jy1 = sy1[jj], ja = sar[jj];
      bool ok = true;
      for (int i = 0; i < lim && ok; ++i) {
        if (!kb[i]) continue;
        int gi = base + i;
        float iw = fmaxf(fminf(sx2[gi], jx2) - fmaxf(sx1[gi], jx1), 0.f);
        float ih = fmaxf(fminf(sy2[gi], jy2) - fmaxf(sy1[gi], jy1), 0.f);
        float inter = iw * ih;
        float iou = inter / (sar[gi] + ja - inter + 1e-9f);
        if (iou > thr) ok = false;
      }
      if (!ok) kp[jj] = 0;
    }
    __syncthreads();
  }
  for (int i = threadIdx.x; i < 512; i += TPB)
    bset[(long)i * 12 + 11] = kp[i] ? 1.f : 0.f;
}

// ---------------- fused final stage: keys+sort+gather+NMS+refine, 1 block ----
__global__ void k_final(const float* __restrict__ boxes, int total, float thr,
                        float* __restrict__ selfb, float* __restrict__ out) {
  __shared__ u64 s[8192];
  __shared__ unsigned char kb[64];
  __shared__ int snv;
  float* fb = (float*)s;
  const int tid = threadIdx.x;   // 1024 threads
  for (int i = tid; i < 8192; i += 1024) {
    u64 k = 0ULL;
    if (i < total) {
      const float* b = boxes + (long)i * 12;
      u32 ic = 0xFFFFFFFFu - (u32)i;
      k = (b[11] != 0.f) ? ((((u64)__float_as_uint(b[4])) << 32) | ic) : (u64)ic;
    }
    s[i] = k;
  }
  if (tid == 0) snv = 0;
  __syncthreads();
  for (int k = 2; k <= 8192; k <<= 1) {
    for (int j = k >> 1; j > 0; j >>= 1) {
      for (int i = tid; i < 8192; i += 1024) {
        int ixj = i ^ j;
        if (ixj > i) {
          u64 a = s[i], b = s[ixj];
          bool desc = ((i & k) == 0);
          if (desc ? (a < b) : (a > b)) { s[i] = b; s[ixj] = a; }
        }
      }
      __syncthreads();
    }
  }
  u64 myKey = s[tid];
  __syncthreads();
  float* sx1 = fb;
  float* sy1 = fb + 1024;
  float* sx2 = fb + 2048;
  float* sy2 = fb + 3072;
  float* sar = fb + 4096;
  unsigned char* kp = (unsigned char*)(fb + 5120);
  {
    int i = tid;
    float* o = selfb + (long)i * 12;
    if ((myKey >> 32) == 0ULL) {
      for (int q = 0; q < 12; ++q) o[q] = 0.f;
      sx1[i] = 0.f; sy1[i] = 0.f; sx2[i] = 0.f; sy2[i] = 0.f; sar[i] = 0.f;
      kp[i] = 0;
    } else {
      u32 bi = 0xFFFFFFFFu - (u32)(myKey & 0xFFFFFFFFu);
      const float* b = boxes + (long)bi * 12;
      float r0 = b[0], r1 = b[1], r2 = b[2], r3 = b[3], r4 = b[4];
      float r5 = b[5], r6 = b[6], r7 = b[7], r8 = b[8], r9 = b[9];
      o[0] = r0; o[1] = r1; o[2] = r2; o[3] = r3; o[4] = r4;
      o[5] = r5; o[6] = r6; o[7] = r7; o[8] = r8; o[9] = r9;
      o[10] = 1.f; o[11] = 0.f;
      float off = r9 * 100000.0f;
      float a0 = r0 + off, a1 = r1 + off, a2 = r2 + off, a3 = r3 + off;
      sx1[i] = a0; sy1[i] = a1; sx2[i] = a2; sy2[i] = a3;
      sar[i] = fmaxf(a2 - a0, 0.f) * fmaxf(a3 - a1, 0.f);
      kp[i] = 1;
      atomicMax(&snv, i + 1);
    }
  }
  __syncthreads();
  int nv = snv;
  const int wave = tid >> 6, lane = tid & 63;
  for (int base = 0; base < nv; base += 64) {
    const int lim = (nv - base < 64) ? (nv - base) : 64;
    if (wave == 0) {
      int gi = base + lane;
      bool ok = (lane < lim) && kp[gi];
      float bx1 = 0.f, by1 = 0.f, bx2 = 0.f, by2 = 0.f, ba = 0.f;
      if (lane < lim) { bx1 = sx1[gi]; by1 = sy1[gi]; bx2 = sx2[gi]; by2 = sy2[gi]; ba = sar[gi]; }
      for (int i = 0; i < lim; ++i) {
        int ki = __shfl((int)ok, i);
        float xi1 = __shfl(bx1, i), yi1 = __shfl(by1, i);
        float xi2 = __shfl(bx2, i), yi2 = __shfl(by2, i);
        float ai = __shfl(ba, i);
        if (ki && lane > i && ok) {
          float iw = fmaxf(fminf(xi2, bx2) - fmaxf(xi1, bx1), 0.f);
          float ih = fmaxf(fminf(yi2, by2) - fmaxf(yi1, by1), 0.f);
          float inter = iw * ih;
          float iou = inter / (ai + ba - inter + 1e-9f);
          if (iou > thr) ok = false;
        }
      }
      if (lane < lim) kp[gi] = ok ? 1 : 0;
      kb[lane] = (lane < lim && ok) ? 1 : 0;
    }
    __syncthreads();
    for (int j = base + 64 + tid; j < nv; j += blockDim.x) {
      if (!kp[j]) continue;
      float jx2 = sx2[j], jy2 = sy2[j], jx1 = sx1[j], jy1 = sy1[j], ja = sar[j];
      bool ok = true;
      for (int i = 0; i < lim && ok; ++i) {
        if (!kb[i]) continue;
        int gi = base + i;
        float iw = fmaxf(fminf(sx2[gi], jx2) - fmaxf(sx1[gi], jx1), 0.f);
        float ih = fmaxf(fminf(sy2[gi], jy2) - fmaxf(sy1[gi], jy1), 0.f);
        float inter = iw * ih;
        float iou = inter / (sar[gi] + ja - inter + 1e-9f);
        if (iou > thr) ok = false;
      }
      if (!ok) kp[j] = 0;
    }
    __syncthreads();
  }
  {
    int i = tid;
    const float* b = selfb + (long)i * 12;
    float keep = kp[i] ? 1.f : 0.f;
    float x1 = b[0], y1 = b[1], x2 = b[2], y2 = b[3], sc = b[4];
    float rw = x2 - x1, rh = y2 - y1;
    float o0 = x1 + b[5] * rw;
    float o1 = y1 + b[6] * rh;
    float o2 = x2 + b[7] * rw;
    float o3 = y2 + b[8] * rh;
    float hh = o3 - o1, ww = o2 - o0;
    float l = fmaxf(hh, ww);
    float nx1 = o0 + ww * 0.5f - l * 0.5f;
    float ny1 = o1 + hh * 0.5f - l * 0.5f;
    out[(long)i * 5 + 0] = nx1 * keep;
    out[(long)i * 5 + 1] = ny1 * keep;
    out[(long)i * 5 + 2] = (nx1 + l) * keep;
    out[(long)i * 5 + 3] = (ny1 + l) * keep;
    out[(long)i * 5 + 4] = sc * keep;
  }
}

extern "C" void kernel_launch(void* const* d_in, const int* in_sizes, int n_in,
                              void* d_out, int out_size, void* d_ws, size_t ws_size,
                              hipStream_t stream) {
  (void)in_sizes; (void)n_in; (void)out_size;
  const float* images = (const float*)d_in[0];
  const float* c1w = (const float*)d_in[1];
  const float* c1b = (const float*)d_in[2];
  const float* p1  = (const float*)d_in[3];
  const float* c2w = (const float*)d_in[4];
  const float* c2b = (const float*)d_in[5];
  const float* p2  = (const float*)d_in[6];
  const float* c3w = (const float*)d_in[7];
  const float* c3b = (const float*)d_in[8];
  const float* p3  = (const float*)d_in[9];
  const float* w41 = (const float*)d_in[10];
  const float* b41 = (const float*)d_in[11];
  const float* w42 = (const float*)d_in[12];
  const float* b42 = (const float*)d_in[13];
  float* ws = (float*)d_ws;

  double scl[16]; int nsc = 0;
  {
    double m = 12.0 / 20.0;
    double ml = 768.0 * m;
    double si = m;
    while (ml >= 12.0) { scl[nsc++] = si; si *= 0.709; ml *= 0.709; }
  }

  auto cdiv = [](long a, long b) { return (int)((a + b - 1) / b); };

  int NH[NSC], PH_[NSC], H2[NSC], H3[NSC], OXB[NSC], TT[NSC], WOFF[NSC];
  float INV[NSC], KSF[NSC];
  {
    int oxb = 0, woff = 0;
    for (int s = 0; s < nsc; ++s) {
      int nh = (int)(768.0 * scl[s] + 1.0);
      NH[s] = nh;
      PH_[s] = ((nh - 2) + 1) / 2;
      H2[s] = PH_[s] - 2;
      H3[s] = H2[s] - 2;
      double inv = 1.0 / (((double)nh) / 768.0);
      INV[s] = (float)inv;
      KSF[s] = (float)(inv > 1.0 ? inv : 1.0);
      TT[s] = (int)(2.0f * KSF[s]) + 2;
      OXB[s] = oxb; oxb += nh;
      WOFF[s] = woff; woff += nh * TT[s];
    }
  }

  static const int GA[11] = {0, 1, 2, 3, 4, 5, 6, 7, 8, 9, 10};
  static const int G1[7] = {0, 5, 6, 7, 8, 9, 10};
  static const int G2[4] = {1, 2, 3, 4};

  struct Layout {
    long HT, IMG, POOL, C2, REG, KEYS, SCR, SEL, BOX, FK, FS, SF, TBL, HD, VD, extent;
    int hdcap, vdcap;
  };

  auto calcLayout = [&](const int* const* gps, const int* gn, int ng,
                        int hdcap, int vdcap, Layout& L) {
    long htA = 0, c3A = 0, imgA = 0, poolA = 0, c2A = 0, cellsA = 0, scrA = 0;
    for (int g = 0; g < ng; ++g) {
      long ht = 0, c3 = 0, im = 0, pl = 0, c2s = 0, ck = 0, sc = 0;
      for (int q = 0; q < gn[g]; ++q) {
        int s = gps[g][q];
        ht += 24L * 768 * NH[s];
        im += 24L * NH[s] * NH[s];
        pl += 80L * PH_[s] * PH_[s];
        c2s += 128L * H2[s] * H2[s];
        c3 += 256L * H3[s] * H3[s];
        long cells = 8L * H3[s] * H3[s];
        ck += cells;
        sc += 512L * ((cells + 2047) / 2048);
      }
      if (ht > htA) htA = ht; if (c3 > c3A) c3A = c3; if (im > imgA) imgA = im;
      if (pl > poolA) poolA = pl; if (c2s > c2A) c2A = c2s;
      if (ck > cellsA) cellsA = ck; if (sc > scrA) scrA = sc;
    }
    long htR = htA > c3A ? htA : c3A;
    auto al = [](long v) { return (v + 15) & ~15L; };
    long off = 0;
    L.HT = off;   off += al(htR);
    L.IMG = off;  off += al(imgA);
    L.POOL = off; off += al(poolA);
    L.C2 = off;   off += al(c2A);
    L.REG = off;  off += al(4 * cellsA);
    L.KEYS = off; off += al(2 * cellsA);
    L.SCR = off;  off += al(2 * scrA + 16384);
    L.SEL = off;  off += al(11264);
    L.BOX = off;  off += al(67584);
    L.FK = off;   off += al(16384);
    L.FS = off;   off += al(2048);
    L.SF = off;   off += al(12288);
    L.TBL = off;  off += al(12288 + 24000);
    L.HD = off;   off += al((long)ng * 5 * hdcap);
    L.VD = off;   off += al((long)ng * 5 * vdcap);
    L.extent = off;
    L.hdcap = hdcap; L.vdcap = vdcap;
  };

  Layout LA, LB;
  {
    const int* gpsA[1] = {GA}; int gnA[1] = {11};
    calcLayout(gpsA, gnA, 1, 8192, 56320, LA);
    const int* gpsB[2] = {G1, G2}; int gnB[2] = {7, 4};
    calcLayout(gpsB, gnB, 2, 2560, 20480, LB);
  }
  bool big = (ws_size >= (size_t)LA.extent * 4);
  const Layout& L = big ? LA : LB;
  const int* GS[2]; int GN[2]; int ngroups;
  if (big) { GS[0] = GA; GN[0] = 11; ngroups = 1; }
  else { GS[0] = G1; GN[0] = 7; GS[1] = G2; GN[1] = 4; ngroups = 2; }

  u64* keys  = (u64*)(ws + L.KEYS);
  u64* scr   = (u64*)(ws + L.SCR);
  float* boxes = ws + L.BOX;
  float* self  = ws + L.SF;
  int*   tX0  = (int*)(ws + L.TBL);
  int*   tCNT = (int*)(ws + L.TBL + 4096);
  float* tWT  = ws + L.TBL + 8192;
  float* tW   = ws + L.TBL + 12288;

  // build resize weight tables (once per launch)
  {
    MkP P; P.ns = nsc;
    for (int s = 0; s < nsc; ++s) {
      P.nw[s] = NH[s]; P.invs[s] = INV[s]; P.ks[s] = KSF[s];
      P.oxB[s] = OXB[s]; P.T[s] = TT[s]; P.wOff[s] = WOFF[s];
    }
    k_mkweights<<<nsc, TPB, 0, stream>>>(tX0, tCNT, tWT, tW, P);
  }

  // per-group geometry
  int imgOff[2][NJMAX], poolOff[2][NJMAX], c2Off[2][NJMAX], c3Off[2][NJMAX],
      htOff[2][NJMAX], kOff[2][NJMAX], cells[2][NJMAX];
  int cumWtot[2], cumRtot[2];
  for (int g = 0; g < ngroups; ++g) {
    long ch = 0, ci = 0, cp = 0, c2 = 0, c3 = 0, ck = 0;
    int cw = 0, cr = 0;
    for (int q = 0; q < GN[g]; ++q) {
      int s = GS[g][q];
      htOff[g][q] = (int)ch;  ch += 24L * 768 * NH[s];
      imgOff[g][q] = (int)ci; ci += 24L * NH[s] * NH[s];
      poolOff[g][q] = (int)cp; cp += 80L * PH_[s] * PH_[s];
      c2Off[g][q] = (int)c2;  c2 += 128L * H2[s] * H2[s];
      c3Off[g][q] = (int)c3;  c3 += 256L * H3[s] * H3[s];
      kOff[g][q] = (int)ck;   cells[g][q] = 8 * H3[s] * H3[s]; ck += cells[g][q];
      cw += 3 * NH[s]; cr += 24 * NH[s];
    }
    cumWtot[g] = cw; cumRtot[g] = cr;
  }

  // build H/V descriptors (geometry-only)
  for (int g = 0; g < ngroups; ++g) {
    DscP P; P.nj = GN[g];
    int cw = 0, cr = 0;
    for (int q = 0; q < GN[g]; ++q) {
      int s = GS[g][q];
      P.N[q] = NH[s]; P.hOff[q] = htOff[g][q]; P.imgOff[q] = imgOff[g][q];
      P.oxB[q] = OXB[s]; P.wOff[q] = WOFF[s];
      P.cumW[q] = cw; cw += 3 * NH[s];
      P.cumR[q] = cr; cr += 24 * NH[s];
    }
    P.cumW[GN[g]] = cw; P.cumR[GN[g]] = cr;
    int* hd = (int*)(ws + L.HD) + (long)g * 5 * L.hdcap;
    int* vd = (int*)(ws + L.VD) + (long)g * 5 * L.vdcap;
    int tot = cw > cr ? cw : cr;
    k_mkdesc<<<cdiv(tot, TPB), TPB, 0, stream>>>(hd, vd, L.hdcap, L.vdcap, P);
  }

  // ---------------- unified job pipeline over groups ----------------
  for (int g = 0; g < ngroups; ++g) {
    const int* gs = GS[g];
    int nj = GN[g];
    int* hd = (int*)(ws + L.HD) + (long)g * 5 * L.hdcap;
    int* vd = (int*)(ws + L.VD) + (long)g * 5 * L.vdcap;
    {
      dim3 gh(768, 8, 1);
      k_resizeH_d<<<gh, TPB, 0, stream>>>(images, ws + L.HT, tX0, tCNT, tWT, tW,
                                          hd, L.hdcap, cumWtot[g]);
    }
    k_resizeV_row<<<cdiv(cumRtot[g], 4), TPB, 0, stream>>>(
        ws + L.HT, ws + L.IMG, tX0, tCNT, tWT, tW, vd, L.vdcap, cumRtot[g]);
    {
      C1P P; P.nj = nj; int ct = 0;
      for (int q = 0; q < nj; ++q) {
        int s = gs[q];
        P.nh[q] = NH[s];
        P.imgOff[q] = imgOff[g][q]; P.poolOff[q] = poolOff[g][q];
        int t1x = cdiv(PH_[s], 16);
        P.t1x[q] = t1x;
        P.cumT[q] = ct; ct += t1x * t1x;
      }
      P.cumT[nj] = ct;
      dim3 gg(ct, 1, 8);
      k_conv1pool_job<<<gg, TPB, 0, stream>>>(ws + L.IMG, c1w, c1b, p1, ws + L.POOL, P);
    }
    {
      CvP P; P.nj = nj; int ct = 0;
      for (int q = 0; q < nj; ++q) {
        int s = gs[q];
        P.H[q] = PH_[s];
        P.inOff[q] = poolOff[g][q]; P.outOff[q] = c2Off[g][q];
        int tx = cdiv(H2[s], 64), ty = cdiv(H2[s], 16);
        P.tx[q] = tx;
        P.cumT[q] = ct; ct += tx * ty;
      }
      P.cumT[nj] = ct;
      dim3 gg(ct, 2, 8);
      k_conv3x3c8_job<<<gg, TPB, 0, stream>>>(ws + L.POOL, c2w, c2b, p2, ws + L.C2,
                                              10, 16, P);
    }
    {
      CvP P; P.nj = nj; int ct = 0;
      for (int q = 0; q < nj; ++q) {
        int s = gs[q];
        P.H[q] = H2[s];
        P.inOff[q] = c2Off[g][q]; P.outOff[q] = c3Off[g][q];
        int tx = cdiv(H3[s], 64), ty = cdiv(H3[s], 16);
        P.tx[q] = tx;
        P.cumT[q] = ct; ct += tx * ty;
      }
      P.cumT[nj] = ct;
      dim3 gg(ct, 4, 8);
      k_conv3x3c8_job<<<gg, TPB, 0, stream>>>(ws + L.C2, c3w, c3b, p3, ws + L.HT,
                                              16, 32, P);
    }
    {
      HdP P; P.nj = nj; int cc = 0;
      for (int q = 0; q < nj; ++q) {
        int s = gs[q];
        P.h3[q] = H3[s];
        P.c3Off[q] = c3Off[g][q]; P.kOff[q] = kOff[g][q];
        P.cumC[q] = cc; cc += cells[g][q];
      }
      P.cumC[nj] = cc;
      k_head_job<<<cdiv(cc, TPB), TPB, 0, stream>>>(ws + L.HT, w41, b41, w42, b42,
                                                    ws + L.REG, keys, P);
    }
    // batched top-512 tournament (8192-chunk rounds) + fused tail
    {
      int bOff[NJMAX];
      {
        int c = 0;
        for (int q = 0; q < nj; ++q) { bOff[q] = c; c += 512 * cdiv(cells[g][q], 8192); }
      }
      long nCur[NJMAX]; int par[NJMAX];
      for (int q = 0; q < nj; ++q) { nCur[q] = cells[g][q]; par[q] = 0; }
      while (true) {
        TkP P; P.nj = 0; int cum = 0; int act[NJMAX];
        for (int q = 0; q < nj; ++q) {
          if (nCur[q] > 2048) {
            int r = P.nj++;
            act[r] = q;
            int blocks = cdiv(nCur[q], 8192);
            P.srcSel[r] = par[q];
            P.srcOff[r] = par[q] ? bOff[q] : kOff[g][q];
            P.dstOff[r] = par[q] ? kOff[g][q] : bOff[q];
            P.n[r] = (int)nCur[q];
            P.cumB[r] = cum; cum += blocks;
          }
        }
        P.cumB[P.nj] = cum;
        if (P.nj == 0) break;
        k_topk_job8<<<cum, 1024, 0, stream>>>(keys, scr, P);
        for (int r = 0; r < P.nj; ++r) {
          int q = act[r];
          nCur[q] = 512L * cdiv(nCur[q], 8192);
          par[q] ^= 1;
        }
      }
      TlP F; F.nj = nj;
      for (int q = 0; q < nj; ++q) {
        int s = gs[q];
        F.srcSel[q] = par[q];
        F.srcOff[q] = par[q] ? bOff[q] : kOff[g][q];
        F.n[q] = (int)nCur[q];
        F.sIdx[q] = s;
        F.h3[q] = H3[s];
        F.scalef[q] = (float)scl[s];
        F.kOff[q] = kOff[g][q];
      }
      k_tail<<<nj, TPB, 0, stream>>>(keys, scr, ws + L.REG, boxes, 0.5f, F);
    }
  }

  // ---------------- fused final stage ----------------
  int total = nsc * 512;
  k_final<<<1, 1024, 0, stream>>>(boxes, total, 0.7f, self, (float*)d_out);
}